// Round 2
// baseline (1462.134 us; speedup 1.0000x reference)
//
#include <hip/hip_runtime.h>
#include <math.h>

#define NN 50000
#define NE 800000
#define IN_DIM 128
#define HIDF 64
#define NH 8
#define HF 512   /* NH*HIDF */
#define OUT_DIM 64

// ============================ utility ============================

__global__ __launch_bounds__(256) void zeroIntKernel(int* __restrict__ a, int n) {
  int i = blockIdx.x * 256 + threadIdx.x;
  if (i < n) a[i] = 0;
}

// ============================ CSR build ============================

__global__ __launch_bounds__(256) void histKernel(const int* __restrict__ dst,
                                                  int* __restrict__ deg, int e) {
  int i = blockIdx.x * 256 + threadIdx.x;
  if (i < e) atomicAdd(&deg[dst[i]], 1);
}

__global__ __launch_bounds__(256) void scanBlockKernel(const int* __restrict__ deg,
                                                       int* __restrict__ row_ptr,
                                                       int* __restrict__ bsums, int n) {
  __shared__ int sd[256];
  int i = blockIdx.x * 256 + threadIdx.x;
  int v = (i < n) ? deg[i] : 0;
  sd[threadIdx.x] = v;
  __syncthreads();
  for (int off = 1; off < 256; off <<= 1) {
    int t = (threadIdx.x >= off) ? sd[threadIdx.x - off] : 0;
    __syncthreads();
    sd[threadIdx.x] += t;
    __syncthreads();
  }
  if (i < n) row_ptr[i + 1] = sd[threadIdx.x];  // inclusive -> row_ptr[i+1]
  if (threadIdx.x == 255) bsums[blockIdx.x] = sd[255];
  if (i == 0) row_ptr[0] = 0;
}

__global__ __launch_bounds__(256) void scanTopKernel(int* __restrict__ bsums, int nb) {
  __shared__ int sd[256];
  int v = (threadIdx.x < nb) ? bsums[threadIdx.x] : 0;
  sd[threadIdx.x] = v;
  __syncthreads();
  for (int off = 1; off < 256; off <<= 1) {
    int t = (threadIdx.x >= off) ? sd[threadIdx.x - off] : 0;
    __syncthreads();
    sd[threadIdx.x] += t;
    __syncthreads();
  }
  if (threadIdx.x < nb) bsums[threadIdx.x] = sd[threadIdx.x] - v;  // exclusive
}

// row_ptr[i+1] += bsums[block]; cursor[i] = row_ptr[i] (final, for scatter)
__global__ __launch_bounds__(256) void scanAddKernel(int* __restrict__ row_ptr,
                                                     const int* __restrict__ bsums,
                                                     int* __restrict__ cursor, int n) {
  int i = blockIdx.x * 256 + threadIdx.x;
  if (i < n) {
    int v = row_ptr[i + 1] + bsums[blockIdx.x];
    row_ptr[i + 1] = v;
    // cursor[i] needs final row_ptr[i]: for i in this block, row_ptr[i] final value
    // is (i % 256 == 0) ? (bsums of prev block chain) : computed similarly.
    // Simpler: recompute below in a second tiny kernel.
  }
}

__global__ __launch_bounds__(256) void copyIntKernel(const int* __restrict__ a,
                                                     int* __restrict__ b, int n) {
  int i = blockIdx.x * 256 + threadIdx.x;
  if (i < n) b[i] = a[i];
}

__global__ __launch_bounds__(256) void fillKernel(const int* __restrict__ src,
                                                  const int* __restrict__ dst,
                                                  int* __restrict__ cursor,
                                                  int* __restrict__ srcs, int e) {
  int i = blockIdx.x * 256 + threadIdx.x;
  if (i < e) {
    int d = dst[i];
    int pos = atomicAdd(&cursor[d], 1);
    srcs[pos] = src[i];
  }
}

// ============================ GEMM: feat = X @ W^T ============================
// X [n, KIN], W [512, KIN] row-major, out [n, 512]. Block: 256 thr, 32 rows, all 512 cols.
template <int KIN>
__global__ __launch_bounds__(256) void gemmKernel(const float* __restrict__ X,
                                                  const float* __restrict__ W,
                                                  float* __restrict__ out, int n) {
  __shared__ float xt[32 * KIN];
  int tid = threadIdx.x;
  int n0 = blockIdx.x * 32;
  for (int i = tid; i < 32 * KIN; i += 256) {
    int r = i / KIN, k = i % KIN;
    xt[i] = (n0 + r < n) ? X[(size_t)(n0 + r) * KIN + k] : 0.f;
  }
  __syncthreads();
  int j0 = tid * 2;
  float acc0[32], acc1[32];
#pragma unroll
  for (int r = 0; r < 32; ++r) { acc0[r] = 0.f; acc1[r] = 0.f; }
  const float4* w0p = (const float4*)(W + (size_t)j0 * KIN);
  const float4* w1p = (const float4*)(W + (size_t)(j0 + 1) * KIN);
  for (int k4 = 0; k4 < KIN / 4; ++k4) {
    float4 w0 = w0p[k4];
    float4 w1 = w1p[k4];
#pragma unroll
    for (int r = 0; r < 32; ++r) {
      float4 xv = *(const float4*)&xt[r * KIN + k4 * 4];
      acc0[r] += xv.x * w0.x + xv.y * w0.y + xv.z * w0.z + xv.w * w0.w;
      acc1[r] += xv.x * w1.x + xv.y * w1.y + xv.z * w1.z + xv.w * w1.w;
    }
  }
#pragma unroll
  for (int r = 0; r < 32; ++r) {
    int nn = n0 + r;
    if (nn < n) *(float2*)&out[(size_t)nn * HF + j0] = make_float2(acc0[r], acc1[r]);
  }
}

// ============================ el/er ============================
__global__ __launch_bounds__(256) void elerKernel(const float* __restrict__ feat,
                                                  const float* __restrict__ al,
                                                  const float* __restrict__ ar,
                                                  float* __restrict__ el,
                                                  float* __restrict__ er, int n) {
  int node = blockIdx.x * 4 + (threadIdx.x >> 6);
  int lane = threadIdx.x & 63;
  if (node >= n) return;
  const float* f = feat + (size_t)node * HF;
#pragma unroll
  for (int h = 0; h < NH; ++h) {
    float v = f[h * 64 + lane];
    float pl = v * al[h * 64 + lane];
    float pr = v * ar[h * 64 + lane];
#pragma unroll
    for (int m = 32; m >= 1; m >>= 1) {
      pl += __shfl_xor(pl, m);
      pr += __shfl_xor(pr, m);
    }
    if (lane == 0) {
      el[(size_t)node * NH + h] = pl;
      er[(size_t)node * NH + h] = pr;
    }
  }
}

// ============================ edge softmax (per-dst, CSR) ============================
// wave per dst node; lane = e_sub*8 + h
__global__ __launch_bounds__(256) void alphaKernel(const float* __restrict__ el,
                                                   const float* __restrict__ er,
                                                   const int* __restrict__ row_ptr,
                                                   const int* __restrict__ srcs,
                                                   float* __restrict__ alpha, int n) {
  int node = blockIdx.x * 4 + (threadIdx.x >> 6);
  int lane = threadIdx.x & 63;
  if (node >= n) return;
  int s0 = row_ptr[node], s1 = row_ptr[node + 1];
  int deg = s1 - s0;
  if (deg <= 0) return;
  int h = lane & 7;
  int esub = lane >> 3;
  float erv = er[(size_t)node * NH + h];
  // pass 1: per-(dst,h) max of leaky(el+er)
  float m = -INFINITY;
  for (int c = 0; c * 8 < deg; ++c) {
    int idx = s0 + c * 8 + esub;
    float ev = -INFINITY;
    if (idx < s1) {
      int s = srcs[idx];
      float e = el[(size_t)s * NH + h] + erv;
      ev = (e > 0.f) ? e : 0.2f * e;
    }
    ev = fmaxf(ev, __shfl_xor(ev, 8));
    ev = fmaxf(ev, __shfl_xor(ev, 16));
    ev = fmaxf(ev, __shfl_xor(ev, 32));
    m = fmaxf(m, ev);
  }
  // pass 2: exp + sum (store exp)
  float ssum = 0.f;
  for (int c = 0; c * 8 < deg; ++c) {
    int idx = s0 + c * 8 + esub;
    float a = 0.f;
    if (idx < s1) {
      int s = srcs[idx];
      float e = el[(size_t)s * NH + h] + erv;
      e = (e > 0.f) ? e : 0.2f * e;
      a = expf(e - m);
      alpha[(size_t)idx * NH + h] = a;
    }
    float t = a;
    t += __shfl_xor(t, 8);
    t += __shfl_xor(t, 16);
    t += __shfl_xor(t, 32);
    ssum += t;
  }
  float inv = 1.0f / ssum;
  // pass 3: normalize
  for (int c = 0; c * 8 < deg; ++c) {
    int idx = s0 + c * 8 + esub;
    if (idx < s1) alpha[(size_t)idx * NH + h] *= inv;
  }
}

// ============================ aggregate + head-sum + bias + leaky ============================
__global__ __launch_bounds__(256) void aggKernel(const float* __restrict__ feat,
                                                 const float* __restrict__ alpha,
                                                 const int* __restrict__ row_ptr,
                                                 const int* __restrict__ srcs,
                                                 const float* __restrict__ b,
                                                 float* __restrict__ xout, int n) {
  int node = blockIdx.x * 4 + (threadIdx.x >> 6);
  int lane = threadIdx.x & 63;
  if (node >= n) return;
  int s0 = row_ptr[node], s1 = row_ptr[node + 1];
  float acc = 0.f;
  for (int p = s0; p < s1; ++p) {
    int s = srcs[p];
    const float* fb = feat + (size_t)s * HF + lane;
    const float* ab = alpha + (size_t)p * NH;
#pragma unroll
    for (int h = 0; h < NH; ++h) acc += ab[h] * fb[h * 64];
  }
  float bs = 0.f;
#pragma unroll
  for (int h = 0; h < NH; ++h) bs += b[h * 64 + lane];
  float v = acc + bs;
  xout[(size_t)node * 64 + lane] = (v > 0.f) ? v : 0.01f * v;
}

// ============================ final dense: out = x @ Wm^T + bm ============================
__global__ __launch_bounds__(256) void finalKernel(const float* __restrict__ x,
                                                   const float* __restrict__ Wm,
                                                   const float* __restrict__ bm,
                                                   float* __restrict__ out, int n) {
  __shared__ float wt[64 * 65];
  int tid = threadIdx.x;
  for (int i = tid; i < 4096; i += 256) {
    int j = i >> 6, k = i & 63;
    wt[k * 65 + j] = Wm[i];
  }
  __syncthreads();
  int node = blockIdx.x * 4 + (tid >> 6);
  int lane = tid & 63;
  if (node >= n) return;
  const float* xr = x + (size_t)node * 64;
  float acc = bm[lane];
#pragma unroll 8
  for (int k = 0; k < 64; ++k) acc += xr[k] * wt[k * 65 + lane];
  out[(size_t)node * 64 + lane] = acc;
}

// ============================ launch ============================
extern "C" void kernel_launch(void* const* d_in, const int* in_sizes, int n_in,
                              void* d_out, int out_size, void* d_ws, size_t ws_size,
                              hipStream_t stream) {
  const float* inputs = (const float*)d_in[0];
  const int* src = (const int*)d_in[1];
  const int* dst = (const int*)d_in[2];
  const float* W1 = (const float*)d_in[3];
  const float* al1 = (const float*)d_in[4];
  const float* ar1 = (const float*)d_in[5];
  const float* b1 = (const float*)d_in[6];
  const float* W2 = (const float*)d_in[7];
  const float* al2 = (const float*)d_in[8];
  const float* ar2 = (const float*)d_in[9];
  const float* b2 = (const float*)d_in[10];
  const float* W3 = (const float*)d_in[11];
  const float* al3 = (const float*)d_in[12];
  const float* ar3 = (const float*)d_in[13];
  const float* b3 = (const float*)d_in[14];
  const float* Wm = (const float*)d_in[15];
  const float* bm = (const float*)d_in[16];
  float* out = (float*)d_out;

  // workspace carve (256B aligned)
  char* p = (char*)d_ws;
  auto carve = [&](size_t bytes) {
    void* r = (void*)p;
    p += (bytes + 255) & ~(size_t)255;
    return r;
  };
  float* feat = (float*)carve((size_t)NN * HF * 4);      // 102.4 MB
  float* el = (float*)carve((size_t)NN * NH * 4);
  float* er = (float*)carve((size_t)NN * NH * 4);
  float* alpha = (float*)carve((size_t)NE * NH * 4);     // 25.6 MB
  float* xbuf = (float*)carve((size_t)NN * 64 * 4);      // 12.8 MB
  int* row_ptr = (int*)carve((size_t)(NN + 1) * 4);
  int* srcs = (int*)carve((size_t)NE * 4);
  int* deg = (int*)carve((size_t)NN * 4);
  int* cursor = (int*)carve((size_t)NN * 4);
  int* bsums = (int*)carve(256 * 4);

  const int nodeBlocks = (NN + 3) / 4;       // 12500 (4 waves per 256-thr block)
  const int edgeBlocks = (NE + 255) / 256;   // 3125
  const int nBlocks = (NN + 255) / 256;      // 196
  const int gemmBlocks = (NN + 31) / 32;     // 1563

  // ---- CSR build ----
  zeroIntKernel<<<nBlocks, 256, 0, stream>>>(deg, NN);
  histKernel<<<edgeBlocks, 256, 0, stream>>>(dst, deg, NE);
  scanBlockKernel<<<nBlocks, 256, 0, stream>>>(deg, row_ptr, bsums, NN);
  scanTopKernel<<<1, 256, 0, stream>>>(bsums, nBlocks);
  scanAddKernel<<<nBlocks, 256, 0, stream>>>(row_ptr, bsums, nullptr, NN);
  copyIntKernel<<<nBlocks, 256, 0, stream>>>(row_ptr, cursor, NN);
  fillKernel<<<edgeBlocks, 256, 0, stream>>>(src, dst, cursor, srcs, NE);

  // ---- layer 1 ----
  gemmKernel<IN_DIM><<<gemmBlocks, 256, 0, stream>>>(inputs, W1, feat, NN);
  elerKernel<<<nodeBlocks, 256, 0, stream>>>(feat, al1, ar1, el, er, NN);
  alphaKernel<<<nodeBlocks, 256, 0, stream>>>(el, er, row_ptr, srcs, alpha, NN);
  aggKernel<<<nodeBlocks, 256, 0, stream>>>(feat, alpha, row_ptr, srcs, b1, xbuf, NN);

  // ---- layer 2 ----
  gemmKernel<HIDF><<<gemmBlocks, 256, 0, stream>>>(xbuf, W2, feat, NN);
  elerKernel<<<nodeBlocks, 256, 0, stream>>>(feat, al2, ar2, el, er, NN);
  alphaKernel<<<nodeBlocks, 256, 0, stream>>>(el, er, row_ptr, srcs, alpha, NN);
  aggKernel<<<nodeBlocks, 256, 0, stream>>>(feat, alpha, row_ptr, srcs, b2, xbuf, NN);

  // ---- layer 3 ----
  gemmKernel<HIDF><<<gemmBlocks, 256, 0, stream>>>(xbuf, W3, feat, NN);
  elerKernel<<<nodeBlocks, 256, 0, stream>>>(feat, al3, ar3, el, er, NN);
  alphaKernel<<<nodeBlocks, 256, 0, stream>>>(el, er, row_ptr, srcs, alpha, NN);
  aggKernel<<<nodeBlocks, 256, 0, stream>>>(feat, alpha, row_ptr, srcs, b3, xbuf, NN);

  // ---- final dense ----
  finalKernel<<<nodeBlocks, 256, 0, stream>>>(xbuf, Wm, bm, out, NN);
}

// Round 3
// 1451.061 us; speedup vs baseline: 1.0076x; 1.0076x over previous
//
#include <hip/hip_runtime.h>
#include <math.h>

#define NN 50000
#define NE 800000
#define IN_DIM 128
#define HIDF 64
#define NH 8
#define HF 512   /* NH*HIDF */
#define OUT_DIM 64
#define INFF __builtin_huge_valf()

// ============================ utility ============================

__global__ __launch_bounds__(256) void zeroIntKernel(int* __restrict__ a, int n) {
  int i = blockIdx.x * 256 + threadIdx.x;
  if (i < n) a[i] = 0;
}

__global__ __launch_bounds__(64) void biasSumKernel(const float* __restrict__ b,
                                                    float* __restrict__ bsum) {
  int f = threadIdx.x;
  float s = 0.f;
#pragma unroll
  for (int h = 0; h < NH; ++h) s += b[h * 64 + f];
  bsum[f] = s;
}

// ============================ CSR build ============================

__global__ __launch_bounds__(256) void histKernel(const int* __restrict__ dst,
                                                  int* __restrict__ deg, int e) {
  int i = blockIdx.x * 256 + threadIdx.x;
  if (i < e) atomicAdd(&deg[dst[i]], 1);
}

__global__ __launch_bounds__(256) void scanBlockKernel(const int* __restrict__ deg,
                                                       int* __restrict__ row_ptr,
                                                       int* __restrict__ bsums, int n) {
  __shared__ int sd[256];
  int i = blockIdx.x * 256 + threadIdx.x;
  int v = (i < n) ? deg[i] : 0;
  sd[threadIdx.x] = v;
  __syncthreads();
  for (int off = 1; off < 256; off <<= 1) {
    int t = (threadIdx.x >= off) ? sd[threadIdx.x - off] : 0;
    __syncthreads();
    sd[threadIdx.x] += t;
    __syncthreads();
  }
  if (i < n) row_ptr[i + 1] = sd[threadIdx.x];  // inclusive -> row_ptr[i+1]
  if (threadIdx.x == 255) bsums[blockIdx.x] = sd[255];
  if (i == 0) row_ptr[0] = 0;
}

__global__ __launch_bounds__(256) void scanTopKernel(int* __restrict__ bsums, int nb) {
  __shared__ int sd[256];
  int v = (threadIdx.x < nb) ? bsums[threadIdx.x] : 0;
  sd[threadIdx.x] = v;
  __syncthreads();
  for (int off = 1; off < 256; off <<= 1) {
    int t = (threadIdx.x >= off) ? sd[threadIdx.x - off] : 0;
    __syncthreads();
    sd[threadIdx.x] += t;
    __syncthreads();
  }
  if (threadIdx.x < nb) bsums[threadIdx.x] = sd[threadIdx.x] - v;  // exclusive
}

__global__ __launch_bounds__(256) void scanAddKernel(int* __restrict__ row_ptr,
                                                     const int* __restrict__ bsums, int n) {
  int i = blockIdx.x * 256 + threadIdx.x;
  if (i < n) row_ptr[i + 1] += bsums[blockIdx.x];
}

__global__ __launch_bounds__(256) void copyIntKernel(const int* __restrict__ a,
                                                     int* __restrict__ b, int n) {
  int i = blockIdx.x * 256 + threadIdx.x;
  if (i < n) b[i] = a[i];
}

__global__ __launch_bounds__(256) void fillKernel(const int* __restrict__ src,
                                                  const int* __restrict__ dst,
                                                  int* __restrict__ cursor,
                                                  int* __restrict__ srcs, int e) {
  int i = blockIdx.x * 256 + threadIdx.x;
  if (i < e) {
    int d = dst[i];
    int pos = atomicAdd(&cursor[d], 1);
    srcs[pos] = src[i];
  }
}

// ============================ GEMM: feat = X @ W^T ============================
template <int KIN>
__global__ __launch_bounds__(256) void gemmKernel(const float* __restrict__ X,
                                                  const float* __restrict__ W,
                                                  float* __restrict__ out, int n) {
  __shared__ float xt[32 * KIN];
  int tid = threadIdx.x;
  int n0 = blockIdx.x * 32;
  for (int i = tid; i < 32 * KIN; i += 256) {
    int r = i / KIN, k = i % KIN;
    xt[i] = (n0 + r < n) ? X[(size_t)(n0 + r) * KIN + k] : 0.f;
  }
  __syncthreads();
  int j0 = tid * 2;
  float acc0[32], acc1[32];
#pragma unroll
  for (int r = 0; r < 32; ++r) { acc0[r] = 0.f; acc1[r] = 0.f; }
  const float4* w0p = (const float4*)(W + (size_t)j0 * KIN);
  const float4* w1p = (const float4*)(W + (size_t)(j0 + 1) * KIN);
  for (int k4 = 0; k4 < KIN / 4; ++k4) {
    float4 w0 = w0p[k4];
    float4 w1 = w1p[k4];
#pragma unroll
    for (int r = 0; r < 32; ++r) {
      float4 xv = *(const float4*)&xt[r * KIN + k4 * 4];
      acc0[r] += xv.x * w0.x + xv.y * w0.y + xv.z * w0.z + xv.w * w0.w;
      acc1[r] += xv.x * w1.x + xv.y * w1.y + xv.z * w1.z + xv.w * w1.w;
    }
  }
#pragma unroll
  for (int r = 0; r < 32; ++r) {
    int nn = n0 + r;
    if (nn < n) *(float2*)&out[(size_t)nn * HF + j0] = make_float2(acc0[r], acc1[r]);
  }
}

// ============================ el/er ============================
__global__ __launch_bounds__(256) void elerKernel(const float* __restrict__ feat,
                                                  const float* __restrict__ al,
                                                  const float* __restrict__ ar,
                                                  float* __restrict__ el,
                                                  float* __restrict__ er, int n) {
  int node = blockIdx.x * 4 + (threadIdx.x >> 6);
  int lane = threadIdx.x & 63;
  if (node >= n) return;
  const float* f = feat + (size_t)node * HF;
#pragma unroll
  for (int h = 0; h < NH; ++h) {
    float v = f[h * 64 + lane];
    float pl = v * al[h * 64 + lane];
    float pr = v * ar[h * 64 + lane];
#pragma unroll
    for (int m = 32; m >= 1; m >>= 1) {
      pl += __shfl_xor(pl, m);
      pr += __shfl_xor(pr, m);
    }
    if (lane == 0) {
      el[(size_t)node * NH + h] = pl;
      er[(size_t)node * NH + h] = pr;
    }
  }
}

// ============ per-(dst,head) online softmax max & inv-sum (no alpha buffer) ============
// wave per dst node; lane = esub*8 + h
__global__ __launch_bounds__(256) void msKernel(const float* __restrict__ el,
                                                const float* __restrict__ er,
                                                const int* __restrict__ row_ptr,
                                                const int* __restrict__ srcs,
                                                float* __restrict__ m,
                                                float* __restrict__ sinv, int n) {
  int node = blockIdx.x * 4 + (threadIdx.x >> 6);
  int lane = threadIdx.x & 63;
  if (node >= n) return;
  int s0 = row_ptr[node], s1 = row_ptr[node + 1];
  int h = lane & 7;
  int esub = lane >> 3;
  if (s1 - s0 <= 0) {
    if (lane < 8) { m[(size_t)node * NH + lane] = 0.f; sinv[(size_t)node * NH + lane] = 0.f; }
    return;
  }
  float erv = er[(size_t)node * NH + h];
  float mv = -INFF, sv = 0.f;
  for (int idx = s0 + esub; idx < s1; idx += 8) {
    int s = srcs[idx];
    float e = el[(size_t)s * NH + h] + erv;
    e = (e > 0.f) ? e : 0.2f * e;
    if (e > mv) {
      sv = sv * __expf(mv - e) + 1.f;  // exp(-inf)=0 on first iter
      mv = e;
    } else {
      sv += __expf(e - mv);
    }
  }
  // combine across esub groups (xor 8, 16, 32); NaN-safe for empty lanes
#pragma unroll
  for (int k = 8; k <= 32; k <<= 1) {
    float om = __shfl_xor(mv, k);
    float os = __shfl_xor(sv, k);
    float mn = fmaxf(mv, om);
    float c1 = (sv > 0.f) ? sv * __expf(mv - mn) : 0.f;
    float c2 = (os > 0.f) ? os * __expf(om - mn) : 0.f;
    mv = mn;
    sv = c1 + c2;
  }
  if (esub == 0) {
    m[(size_t)node * NH + h] = mv;
    sinv[(size_t)node * NH + h] = (sv > 0.f) ? 1.f / sv : 0.f;
  }
}

// ============ aggregate (on-the-fly alpha) + head-sum + bias + leaky ============
// wave per dst. lane l: heads hA=l>>4 and hB=hA+4, feats fb=(l&15)*4 .. +3.
__global__ __launch_bounds__(256) void aggKernel(const float* __restrict__ feat,
                                                 const float* __restrict__ el,
                                                 const float* __restrict__ er,
                                                 const float* __restrict__ m,
                                                 const float* __restrict__ sinv,
                                                 const int* __restrict__ row_ptr,
                                                 const int* __restrict__ srcs,
                                                 const float* __restrict__ bsum,
                                                 float* __restrict__ xout, int n) {
  int node = blockIdx.x * 4 + (threadIdx.x >> 6);
  int lane = threadIdx.x & 63;
  if (node >= n) return;
  int s0 = row_ptr[node], s1 = row_ptr[node + 1];
  int hA = lane >> 4;
  int hB = hA + 4;
  float erA = er[(size_t)node * NH + hA];
  float erB = er[(size_t)node * NH + hB];
  float mA = m[(size_t)node * NH + hA];
  float mB = m[(size_t)node * NH + hB];
  float4 accA = {0.f, 0.f, 0.f, 0.f};
  float4 accB = {0.f, 0.f, 0.f, 0.f};
  for (int base = s0; base < s1; base += 64) {
    int nb = s1 - base;
    if (nb > 64) nb = 64;
    int sv = srcs[base + (lane < nb ? lane : 0)];
    for (int e = 0; e < nb; ++e) {
      int s = __shfl(sv, e);
      float elA = el[(size_t)s * NH + hA];
      float elB = el[(size_t)s * NH + hB];
      const float4* fr = (const float4*)(feat + (size_t)s * HF);
      float4 vA = fr[lane];        // floats [lane*4, +4): heads 0..3
      float4 vB = fr[64 + lane];   // floats [256+lane*4, +4): heads 4..7
      float tA = elA + erA; tA = (tA > 0.f) ? tA : 0.2f * tA;
      float tB = elB + erB; tB = (tB > 0.f) ? tB : 0.2f * tB;
      float aA = __expf(tA - mA);
      float aB = __expf(tB - mB);
      accA.x += aA * vA.x; accA.y += aA * vA.y; accA.z += aA * vA.z; accA.w += aA * vA.w;
      accB.x += aB * vB.x; accB.y += aB * vB.y; accB.z += aB * vB.z; accB.w += aB * vB.w;
    }
  }
  float siA = sinv[(size_t)node * NH + hA];
  float siB = sinv[(size_t)node * NH + hB];
  float4 acc;
  acc.x = accA.x * siA + accB.x * siB;
  acc.y = accA.y * siA + accB.y * siB;
  acc.z = accA.z * siA + accB.z * siB;
  acc.w = accA.w * siA + accB.w * siB;
  // sum over the 4 head-group lanes (same fb): xor 16, 32
#pragma unroll
  for (int k = 16; k <= 32; k <<= 1) {
    acc.x += __shfl_xor(acc.x, k);
    acc.y += __shfl_xor(acc.y, k);
    acc.z += __shfl_xor(acc.z, k);
    acc.w += __shfl_xor(acc.w, k);
  }
  if (lane < 16) {
    float4 bz = ((const float4*)bsum)[lane];
    float4 o;
    o.x = acc.x + bz.x; o.x = (o.x > 0.f) ? o.x : 0.01f * o.x;
    o.y = acc.y + bz.y; o.y = (o.y > 0.f) ? o.y : 0.01f * o.y;
    o.z = acc.z + bz.z; o.z = (o.z > 0.f) ? o.z : 0.01f * o.z;
    o.w = acc.w + bz.w; o.w = (o.w > 0.f) ? o.w : 0.01f * o.w;
    ((float4*)(xout + (size_t)node * 64))[lane] = o;
  }
}

// ============================ final dense: out = x @ Wm^T + bm ============================
__global__ __launch_bounds__(256) void finalKernel(const float* __restrict__ x,
                                                   const float* __restrict__ Wm,
                                                   const float* __restrict__ bm,
                                                   float* __restrict__ out, int n) {
  __shared__ float wt[64 * 65];
  int tid = threadIdx.x;
  for (int i = tid; i < 4096; i += 256) {
    int j = i >> 6, k = i & 63;
    wt[k * 65 + j] = Wm[i];
  }
  __syncthreads();
  int node = blockIdx.x * 4 + (tid >> 6);
  int lane = tid & 63;
  if (node >= n) return;
  const float* xr = x + (size_t)node * 64;
  float acc = bm[lane];
#pragma unroll 8
  for (int k = 0; k < 64; ++k) acc += xr[k] * wt[k * 65 + lane];
  out[(size_t)node * 64 + lane] = acc;
}

// ============================ launch ============================
extern "C" void kernel_launch(void* const* d_in, const int* in_sizes, int n_in,
                              void* d_out, int out_size, void* d_ws, size_t ws_size,
                              hipStream_t stream) {
  const float* inputs = (const float*)d_in[0];
  const int* src = (const int*)d_in[1];
  const int* dst = (const int*)d_in[2];
  const float* W1 = (const float*)d_in[3];
  const float* al1 = (const float*)d_in[4];
  const float* ar1 = (const float*)d_in[5];
  const float* b1 = (const float*)d_in[6];
  const float* W2 = (const float*)d_in[7];
  const float* al2 = (const float*)d_in[8];
  const float* ar2 = (const float*)d_in[9];
  const float* b2 = (const float*)d_in[10];
  const float* W3 = (const float*)d_in[11];
  const float* al3 = (const float*)d_in[12];
  const float* ar3 = (const float*)d_in[13];
  const float* b3 = (const float*)d_in[14];
  const float* Wm = (const float*)d_in[15];
  const float* bm = (const float*)d_in[16];
  float* out = (float*)d_out;

  // workspace carve (256B aligned)
  char* p = (char*)d_ws;
  auto carve = [&](size_t bytes) {
    void* r = (void*)p;
    p += (bytes + 255) & ~(size_t)255;
    return r;
  };
  float* feat = (float*)carve((size_t)NN * HF * 4);      // 102.4 MB
  float* el = (float*)carve((size_t)NN * NH * 4);
  float* er = (float*)carve((size_t)NN * NH * 4);
  float* mbuf = (float*)carve((size_t)NN * NH * 4);
  float* sinv = (float*)carve((size_t)NN * NH * 4);
  float* xbuf = (float*)carve((size_t)NN * 64 * 4);      // 12.8 MB
  float* bsum = (float*)carve(64 * 4);
  int* row_ptr = (int*)carve((size_t)(NN + 1) * 4);
  int* srcs = (int*)carve((size_t)NE * 4);
  int* deg = (int*)carve((size_t)NN * 4);
  int* cursor = (int*)carve((size_t)NN * 4);
  int* bsums = (int*)carve(256 * 4);

  const int nodeBlocks = (NN + 3) / 4;       // 12500 (4 waves per 256-thr block)
  const int edgeBlocks = (NE + 255) / 256;   // 3125
  const int nBlocks = (NN + 255) / 256;      // 196
  const int gemmBlocks = (NN + 31) / 32;     // 1563

  // ---- CSR build ----
  zeroIntKernel<<<nBlocks, 256, 0, stream>>>(deg, NN);
  histKernel<<<edgeBlocks, 256, 0, stream>>>(dst, deg, NE);
  scanBlockKernel<<<nBlocks, 256, 0, stream>>>(deg, row_ptr, bsums, NN);
  scanTopKernel<<<1, 256, 0, stream>>>(bsums, nBlocks);
  scanAddKernel<<<nBlocks, 256, 0, stream>>>(row_ptr, bsums, NN);
  copyIntKernel<<<nBlocks, 256, 0, stream>>>(row_ptr, cursor, NN);
  fillKernel<<<edgeBlocks, 256, 0, stream>>>(src, dst, cursor, srcs, NE);

  // ---- layer 1 ----
  gemmKernel<IN_DIM><<<gemmBlocks, 256, 0, stream>>>(inputs, W1, feat, NN);
  biasSumKernel<<<1, 64, 0, stream>>>(b1, bsum);
  elerKernel<<<nodeBlocks, 256, 0, stream>>>(feat, al1, ar1, el, er, NN);
  msKernel<<<nodeBlocks, 256, 0, stream>>>(el, er, row_ptr, srcs, mbuf, sinv, NN);
  aggKernel<<<nodeBlocks, 256, 0, stream>>>(feat, el, er, mbuf, sinv, row_ptr, srcs, bsum, xbuf, NN);

  // ---- layer 2 ----
  gemmKernel<HIDF><<<gemmBlocks, 256, 0, stream>>>(xbuf, W2, feat, NN);
  biasSumKernel<<<1, 64, 0, stream>>>(b2, bsum);
  elerKernel<<<nodeBlocks, 256, 0, stream>>>(feat, al2, ar2, el, er, NN);
  msKernel<<<nodeBlocks, 256, 0, stream>>>(el, er, row_ptr, srcs, mbuf, sinv, NN);
  aggKernel<<<nodeBlocks, 256, 0, stream>>>(feat, el, er, mbuf, sinv, row_ptr, srcs, bsum, xbuf, NN);

  // ---- layer 3 ----
  gemmKernel<HIDF><<<gemmBlocks, 256, 0, stream>>>(xbuf, W3, feat, NN);
  biasSumKernel<<<1, 64, 0, stream>>>(b3, bsum);
  elerKernel<<<nodeBlocks, 256, 0, stream>>>(feat, al3, ar3, el, er, NN);
  msKernel<<<nodeBlocks, 256, 0, stream>>>(el, er, row_ptr, srcs, mbuf, sinv, NN);
  aggKernel<<<nodeBlocks, 256, 0, stream>>>(feat, el, er, mbuf, sinv, row_ptr, srcs, bsum, xbuf, NN);

  // ---- final dense ----
  finalKernel<<<nodeBlocks, 256, 0, stream>>>(xbuf, Wm, bm, out, NN);
}

// Round 4
// 1335.120 us; speedup vs baseline: 1.0951x; 1.0868x over previous
//
#include <hip/hip_runtime.h>
#include <math.h>

#define NN 50000
#define NE 800000
#define IN_DIM 128
#define HIDF 64
#define NH 8
#define HF 512   /* NH*HIDF */
#define OUT_DIM 64

// ============================ utility ============================

__global__ __launch_bounds__(256) void zeroIntKernel(int* __restrict__ a, int n) {
  int i = blockIdx.x * 256 + threadIdx.x;
  if (i < n) a[i] = 0;
}

// ============================ CSR build ============================

__global__ __launch_bounds__(256) void histKernel(const int* __restrict__ dst,
                                                  int* __restrict__ deg, int e) {
  int i = blockIdx.x * 256 + threadIdx.x;
  if (i < e) atomicAdd(&deg[dst[i]], 1);
}

__global__ __launch_bounds__(256) void scanBlockKernel(const int* __restrict__ deg,
                                                       int* __restrict__ row_ptr,
                                                       int* __restrict__ bsums, int n) {
  __shared__ int sd[256];
  int i = blockIdx.x * 256 + threadIdx.x;
  int v = (i < n) ? deg[i] : 0;
  sd[threadIdx.x] = v;
  __syncthreads();
  for (int off = 1; off < 256; off <<= 1) {
    int t = (threadIdx.x >= off) ? sd[threadIdx.x - off] : 0;
    __syncthreads();
    sd[threadIdx.x] += t;
    __syncthreads();
  }
  if (i < n) row_ptr[i + 1] = sd[threadIdx.x];
  if (threadIdx.x == 255) bsums[blockIdx.x] = sd[255];
  if (i == 0) row_ptr[0] = 0;
}

__global__ __launch_bounds__(256) void scanTopKernel(int* __restrict__ bsums, int nb) {
  __shared__ int sd[256];
  int v = (threadIdx.x < nb) ? bsums[threadIdx.x] : 0;
  sd[threadIdx.x] = v;
  __syncthreads();
  for (int off = 1; off < 256; off <<= 1) {
    int t = (threadIdx.x >= off) ? sd[threadIdx.x - off] : 0;
    __syncthreads();
    sd[threadIdx.x] += t;
    __syncthreads();
  }
  if (threadIdx.x < nb) bsums[threadIdx.x] = sd[threadIdx.x] - v;  // exclusive
}

__global__ __launch_bounds__(256) void scanAddKernel(int* __restrict__ row_ptr,
                                                     const int* __restrict__ bsums, int n) {
  int i = blockIdx.x * 256 + threadIdx.x;
  if (i < n) row_ptr[i + 1] += bsums[blockIdx.x];
}

__global__ __launch_bounds__(256) void copyIntKernel(const int* __restrict__ a,
                                                     int* __restrict__ b, int n) {
  int i = blockIdx.x * 256 + threadIdx.x;
  if (i < n) b[i] = a[i];
}

__global__ __launch_bounds__(256) void fillKernel(const int* __restrict__ src,
                                                  const int* __restrict__ dst,
                                                  int* __restrict__ cursor,
                                                  int* __restrict__ srcs, int e) {
  int i = blockIdx.x * 256 + threadIdx.x;
  if (i < e) {
    int d = dst[i];
    int pos = atomicAdd(&cursor[d], 1);
    srcs[pos] = src[i];
  }
}

// ====== prep: Al[h,k]=sum_f al[h,f]*W[h*64+f,k]; Ar likewise; bsum[f]=sum_h b[h,f] ======
template <int KIN>
__global__ __launch_bounds__(256) void prepKernel(const float* __restrict__ W,
                                                  const float* __restrict__ al,
                                                  const float* __restrict__ ar,
                                                  const float* __restrict__ b,
                                                  float* __restrict__ Al,
                                                  float* __restrict__ Ar,
                                                  float* __restrict__ bsum) {
  int tid = threadIdx.x;
  for (int idx = tid; idx < NH * KIN; idx += 256) {
    int h = idx / KIN, k = idx % KIN;
    float sl = 0.f, sr = 0.f;
    for (int f = 0; f < 64; ++f) {
      float w = W[(size_t)(h * 64 + f) * KIN + k];
      sl += al[h * 64 + f] * w;
      sr += ar[h * 64 + f] * w;
    }
    Al[idx] = sl;
    Ar[idx] = sr;
  }
  if (tid < 64) {
    float s = 0.f;
#pragma unroll
    for (int h = 0; h < NH; ++h) s += b[h * 64 + tid];
    bsum[tid] = s;
  }
}

// ====== GEMM: feat = X @ W^T; fused el/er = X @ Al^T / X @ Ar^T ======
template <int KIN>
__global__ __launch_bounds__(256) void gemmKernel(const float* __restrict__ X,
                                                  const float* __restrict__ W,
                                                  const float* __restrict__ Al,
                                                  const float* __restrict__ Ar,
                                                  float* __restrict__ out,
                                                  float* __restrict__ el,
                                                  float* __restrict__ er, int n) {
  const int XS = KIN + 4;  // padded LDS stride (bank-spread for the el/er epilogue)
  __shared__ float xt[32 * (KIN + 4)];
  int tid = threadIdx.x;
  int n0 = blockIdx.x * 32;
  for (int i = tid; i < 32 * KIN; i += 256) {
    int r = i / KIN, k = i % KIN;
    xt[r * XS + k] = (n0 + r < n) ? X[(size_t)(n0 + r) * KIN + k] : 0.f;
  }
  __syncthreads();
  int j0 = tid * 2;
  float acc0[32], acc1[32];
#pragma unroll
  for (int r = 0; r < 32; ++r) { acc0[r] = 0.f; acc1[r] = 0.f; }
  const float4* w0p = (const float4*)(W + (size_t)j0 * KIN);
  const float4* w1p = (const float4*)(W + (size_t)(j0 + 1) * KIN);
  for (int k4 = 0; k4 < KIN / 4; ++k4) {
    float4 w0 = w0p[k4];
    float4 w1 = w1p[k4];
#pragma unroll
    for (int r = 0; r < 32; ++r) {
      float4 xv = *(const float4*)&xt[r * XS + k4 * 4];
      acc0[r] += xv.x * w0.x + xv.y * w0.y + xv.z * w0.z + xv.w * w0.w;
      acc1[r] += xv.x * w1.x + xv.y * w1.y + xv.z * w1.z + xv.w * w1.w;
    }
  }
#pragma unroll
  for (int r = 0; r < 32; ++r) {
    int nn = n0 + r;
    if (nn < n) *(float2*)&out[(size_t)nn * HF + j0] = make_float2(acc0[r], acc1[r]);
  }
  // epilogue: el/er. thread t -> row r2=t>>3, head h2=t&7
  int r2 = tid >> 3, h2 = tid & 7;
  if (n0 + r2 < n) {
    float accl = 0.f, accr = 0.f;
    const float4* wl = (const float4*)(Al + (size_t)h2 * KIN);
    const float4* wr = (const float4*)(Ar + (size_t)h2 * KIN);
    for (int k4 = 0; k4 < KIN / 4; ++k4) {
      float4 xv = *(const float4*)&xt[r2 * XS + k4 * 4];
      float4 a = wl[k4], c = wr[k4];
      accl += xv.x * a.x + xv.y * a.y + xv.z * a.z + xv.w * a.w;
      accr += xv.x * c.x + xv.y * c.y + xv.z * c.z + xv.w * c.w;
    }
    el[(size_t)(n0 + r2) * NH + h2] = accl;
    er[(size_t)(n0 + r2) * NH + h2] = accr;
  }
}

// ====== aggregate: on-the-fly alpha (no max-sub), fused softmax-sum, 4-edge pipeline ======
// wave per dst. lane l: heads hA=l>>4, hB=hA+4; feats fb=(l&15)*4..+3.
__global__ __launch_bounds__(256) void aggKernel(const float* __restrict__ feat,
                                                 const float* __restrict__ el,
                                                 const float* __restrict__ er,
                                                 const int* __restrict__ row_ptr,
                                                 const int* __restrict__ srcs,
                                                 const float* __restrict__ bsum,
                                                 float* __restrict__ xout, int n) {
  int node = blockIdx.x * 4 + (threadIdx.x >> 6);
  int lane = threadIdx.x & 63;
  if (node >= n) return;
  int s0 = row_ptr[node], s1 = row_ptr[node + 1];
  int hA = lane >> 4;
  int hB = hA + 4;
  float erA = er[(size_t)node * NH + hA];
  float erB = er[(size_t)node * NH + hB];
  float4 accA = {0.f, 0.f, 0.f, 0.f};
  float4 accB = {0.f, 0.f, 0.f, 0.f};
  float sumA = 0.f, sumB = 0.f;

#define EDGE_BODY(SX, ELA, ELB, VA, VB)                                   \
  {                                                                       \
    float tA = (ELA) + erA; tA = (tA > 0.f) ? tA : 0.2f * tA;             \
    float tB = (ELB) + erB; tB = (tB > 0.f) ? tB : 0.2f * tB;             \
    float aA = __expf(tA);                                                \
    float aB = __expf(tB);                                                \
    sumA += aA; sumB += aB;                                               \
    accA.x += aA * (VA).x; accA.y += aA * (VA).y;                         \
    accA.z += aA * (VA).z; accA.w += aA * (VA).w;                         \
    accB.x += aB * (VB).x; accB.y += aB * (VB).y;                         \
    accB.z += aB * (VB).z; accB.w += aB * (VB).w;                         \
  }

  for (int base = s0; base < s1; base += 64) {
    int nb = s1 - base;
    if (nb > 64) nb = 64;
    int li = base + lane;
    int sv = srcs[li < s1 ? li : s1 - 1];
    int e = 0;
    for (; e + 4 <= nb; e += 4) {
      int sa = __shfl(sv, e);
      int sb = __shfl(sv, e + 1);
      int sc = __shfl(sv, e + 2);
      int sd = __shfl(sv, e + 3);
      float elA0 = el[(size_t)sa * NH + hA], elB0 = el[(size_t)sa * NH + hB];
      float elA1 = el[(size_t)sb * NH + hA], elB1 = el[(size_t)sb * NH + hB];
      float elA2 = el[(size_t)sc * NH + hA], elB2 = el[(size_t)sc * NH + hB];
      float elA3 = el[(size_t)sd * NH + hA], elB3 = el[(size_t)sd * NH + hB];
      const float4* f0 = (const float4*)(feat + (size_t)sa * HF);
      const float4* f1 = (const float4*)(feat + (size_t)sb * HF);
      const float4* f2 = (const float4*)(feat + (size_t)sc * HF);
      const float4* f3 = (const float4*)(feat + (size_t)sd * HF);
      float4 vA0 = f0[lane], vB0 = f0[64 + lane];
      float4 vA1 = f1[lane], vB1 = f1[64 + lane];
      float4 vA2 = f2[lane], vB2 = f2[64 + lane];
      float4 vA3 = f3[lane], vB3 = f3[64 + lane];
      EDGE_BODY(sa, elA0, elB0, vA0, vB0)
      EDGE_BODY(sb, elA1, elB1, vA1, vB1)
      EDGE_BODY(sc, elA2, elB2, vA2, vB2)
      EDGE_BODY(sd, elA3, elB3, vA3, vB3)
    }
    for (; e < nb; ++e) {
      int sx = __shfl(sv, e);
      float elA = el[(size_t)sx * NH + hA], elB = el[(size_t)sx * NH + hB];
      const float4* fr = (const float4*)(feat + (size_t)sx * HF);
      float4 vA = fr[lane], vB = fr[64 + lane];
      EDGE_BODY(sx, elA, elB, vA, vB)
    }
  }
#undef EDGE_BODY

  float siA = (s1 > s0) ? 1.f / sumA : 0.f;
  float siB = (s1 > s0) ? 1.f / sumB : 0.f;
  float4 acc;
  acc.x = accA.x * siA + accB.x * siB;
  acc.y = accA.y * siA + accB.y * siB;
  acc.z = accA.z * siA + accB.z * siB;
  acc.w = accA.w * siA + accB.w * siB;
#pragma unroll
  for (int k = 16; k <= 32; k <<= 1) {
    acc.x += __shfl_xor(acc.x, k);
    acc.y += __shfl_xor(acc.y, k);
    acc.z += __shfl_xor(acc.z, k);
    acc.w += __shfl_xor(acc.w, k);
  }
  if (lane < 16) {
    float4 bz = ((const float4*)bsum)[lane];
    float4 o;
    o.x = acc.x + bz.x; o.x = (o.x > 0.f) ? o.x : 0.01f * o.x;
    o.y = acc.y + bz.y; o.y = (o.y > 0.f) ? o.y : 0.01f * o.y;
    o.z = acc.z + bz.z; o.z = (o.z > 0.f) ? o.z : 0.01f * o.z;
    o.w = acc.w + bz.w; o.w = (o.w > 0.f) ? o.w : 0.01f * o.w;
    ((float4*)(xout + (size_t)node * 64))[lane] = o;
  }
}

// ============================ final dense: out = x @ Wm^T + bm ============================
__global__ __launch_bounds__(256) void finalKernel(const float* __restrict__ x,
                                                   const float* __restrict__ Wm,
                                                   const float* __restrict__ bm,
                                                   float* __restrict__ out, int n) {
  __shared__ float wt[64 * 65];
  int tid = threadIdx.x;
  for (int i = tid; i < 4096; i += 256) {
    int j = i >> 6, k = i & 63;
    wt[k * 65 + j] = Wm[i];
  }
  __syncthreads();
  int node = blockIdx.x * 4 + (tid >> 6);
  int lane = tid & 63;
  if (node >= n) return;
  const float* xr = x + (size_t)node * 64;
  float acc = bm[lane];
#pragma unroll 8
  for (int k = 0; k < 64; ++k) acc += xr[k] * wt[k * 65 + lane];
  out[(size_t)node * 64 + lane] = acc;
}

// ============================ launch ============================
extern "C" void kernel_launch(void* const* d_in, const int* in_sizes, int n_in,
                              void* d_out, int out_size, void* d_ws, size_t ws_size,
                              hipStream_t stream) {
  const float* inputs = (const float*)d_in[0];
  const int* src = (const int*)d_in[1];
  const int* dst = (const int*)d_in[2];
  const float* W1 = (const float*)d_in[3];
  const float* al1 = (const float*)d_in[4];
  const float* ar1 = (const float*)d_in[5];
  const float* b1 = (const float*)d_in[6];
  const float* W2 = (const float*)d_in[7];
  const float* al2 = (const float*)d_in[8];
  const float* ar2 = (const float*)d_in[9];
  const float* b2 = (const float*)d_in[10];
  const float* W3 = (const float*)d_in[11];
  const float* al3 = (const float*)d_in[12];
  const float* ar3 = (const float*)d_in[13];
  const float* b3 = (const float*)d_in[14];
  const float* Wm = (const float*)d_in[15];
  const float* bm = (const float*)d_in[16];
  float* out = (float*)d_out;

  char* p = (char*)d_ws;
  auto carve = [&](size_t bytes) {
    void* r = (void*)p;
    p += (bytes + 255) & ~(size_t)255;
    return r;
  };
  float* feat = (float*)carve((size_t)NN * HF * 4);      // 102.4 MB
  float* el = (float*)carve((size_t)NN * NH * 4);
  float* er = (float*)carve((size_t)NN * NH * 4);
  float* xbuf = (float*)carve((size_t)NN * 64 * 4);      // 12.8 MB
  float* Albuf = (float*)carve((size_t)NH * IN_DIM * 4);
  float* Arbuf = (float*)carve((size_t)NH * IN_DIM * 4);
  float* bsum = (float*)carve(64 * 4);
  int* row_ptr = (int*)carve((size_t)(NN + 1) * 4);
  int* srcs = (int*)carve((size_t)NE * 4);
  int* deg = (int*)carve((size_t)NN * 4);
  int* cursor = (int*)carve((size_t)NN * 4);
  int* bsums = (int*)carve(256 * 4);

  const int nodeBlocks = (NN + 3) / 4;       // 12500
  const int edgeBlocks = (NE + 255) / 256;   // 3125
  const int nBlocks = (NN + 255) / 256;      // 196
  const int gemmBlocks = (NN + 31) / 32;     // 1563

  // ---- CSR build ----
  zeroIntKernel<<<nBlocks, 256, 0, stream>>>(deg, NN);
  histKernel<<<edgeBlocks, 256, 0, stream>>>(dst, deg, NE);
  scanBlockKernel<<<nBlocks, 256, 0, stream>>>(deg, row_ptr, bsums, NN);
  scanTopKernel<<<1, 256, 0, stream>>>(bsums, nBlocks);
  scanAddKernel<<<nBlocks, 256, 0, stream>>>(row_ptr, bsums, NN);
  copyIntKernel<<<nBlocks, 256, 0, stream>>>(row_ptr, cursor, NN);
  fillKernel<<<edgeBlocks, 256, 0, stream>>>(src, dst, cursor, srcs, NE);

  // ---- layer 1 ----
  prepKernel<IN_DIM><<<1, 256, 0, stream>>>(W1, al1, ar1, b1, Albuf, Arbuf, bsum);
  gemmKernel<IN_DIM><<<gemmBlocks, 256, 0, stream>>>(inputs, W1, Albuf, Arbuf, feat, el, er, NN);
  aggKernel<<<nodeBlocks, 256, 0, stream>>>(feat, el, er, row_ptr, srcs, bsum, xbuf, NN);

  // ---- layer 2 ----
  prepKernel<HIDF><<<1, 256, 0, stream>>>(W2, al2, ar2, b2, Albuf, Arbuf, bsum);
  gemmKernel<HIDF><<<gemmBlocks, 256, 0, stream>>>(xbuf, W2, Albuf, Arbuf, feat, el, er, NN);
  aggKernel<<<nodeBlocks, 256, 0, stream>>>(feat, el, er, row_ptr, srcs, bsum, xbuf, NN);

  // ---- layer 3 ----
  prepKernel<HIDF><<<1, 256, 0, stream>>>(W3, al3, ar3, b3, Albuf, Arbuf, bsum);
  gemmKernel<HIDF><<<gemmBlocks, 256, 0, stream>>>(xbuf, W3, Albuf, Arbuf, feat, el, er, NN);
  aggKernel<<<nodeBlocks, 256, 0, stream>>>(feat, el, er, row_ptr, srcs, bsum, xbuf, NN);

  // ---- final dense ----
  finalKernel<<<nodeBlocks, 256, 0, stream>>>(xbuf, Wm, bm, out, NN);
}

// Round 5
// 1320.323 us; speedup vs baseline: 1.1074x; 1.0112x over previous
//
#include <hip/hip_runtime.h>
#include <math.h>

#define NN 50000
#define NE 800000
#define IN_DIM 128
#define HIDF 64
#define NH 8
#define HF 512   /* NH*HIDF */
#define OUT_DIM 64

// ============================ utility ============================

__global__ __launch_bounds__(256) void zeroIntKernel(int* __restrict__ a, int n) {
  int i = blockIdx.x * 256 + threadIdx.x;
  if (i < n) a[i] = 0;
}

// ============================ CSR build ============================

__global__ __launch_bounds__(256) void histKernel(const int* __restrict__ dst,
                                                  int* __restrict__ deg, int e) {
  int i = blockIdx.x * 256 + threadIdx.x;
  if (i < e) atomicAdd(&deg[dst[i]], 1);
}

__global__ __launch_bounds__(256) void scanBlockKernel(const int* __restrict__ deg,
                                                       int* __restrict__ row_ptr,
                                                       int* __restrict__ bsums, int n) {
  __shared__ int sd[256];
  int i = blockIdx.x * 256 + threadIdx.x;
  int v = (i < n) ? deg[i] : 0;
  sd[threadIdx.x] = v;
  __syncthreads();
  for (int off = 1; off < 256; off <<= 1) {
    int t = (threadIdx.x >= off) ? sd[threadIdx.x - off] : 0;
    __syncthreads();
    sd[threadIdx.x] += t;
    __syncthreads();
  }
  if (i < n) row_ptr[i + 1] = sd[threadIdx.x];
  if (threadIdx.x == 255) bsums[blockIdx.x] = sd[255];
  if (i == 0) row_ptr[0] = 0;
}

__global__ __launch_bounds__(256) void scanTopKernel(int* __restrict__ bsums, int nb) {
  __shared__ int sd[256];
  int v = (threadIdx.x < nb) ? bsums[threadIdx.x] : 0;
  sd[threadIdx.x] = v;
  __syncthreads();
  for (int off = 1; off < 256; off <<= 1) {
    int t = (threadIdx.x >= off) ? sd[threadIdx.x - off] : 0;
    __syncthreads();
    sd[threadIdx.x] += t;
    __syncthreads();
  }
  if (threadIdx.x < nb) bsums[threadIdx.x] = sd[threadIdx.x] - v;  // exclusive
}

__global__ __launch_bounds__(256) void scanAddKernel(int* __restrict__ row_ptr,
                                                     const int* __restrict__ bsums, int n) {
  int i = blockIdx.x * 256 + threadIdx.x;
  if (i < n) row_ptr[i + 1] += bsums[blockIdx.x];
}

__global__ __launch_bounds__(256) void copyIntKernel(const int* __restrict__ a,
                                                     int* __restrict__ b, int n) {
  int i = blockIdx.x * 256 + threadIdx.x;
  if (i < n) b[i] = a[i];
}

__global__ __launch_bounds__(256) void fillKernel(const int* __restrict__ src,
                                                  const int* __restrict__ dst,
                                                  int* __restrict__ cursor,
                                                  int* __restrict__ srcs, int e) {
  int i = blockIdx.x * 256 + threadIdx.x;
  if (i < e) {
    int d = dst[i];
    int pos = atomicAdd(&cursor[d], 1);
    srcs[pos] = src[i];
  }
}

// ====== prep: Al[h,k]=sum_f al[h,f]*W[h*64+f,k]; Ar likewise; bsum[f]=sum_h b[h,f] ======
template <int KIN>
__global__ __launch_bounds__(256) void prepKernel(const float* __restrict__ W,
                                                  const float* __restrict__ al,
                                                  const float* __restrict__ ar,
                                                  const float* __restrict__ b,
                                                  float* __restrict__ Al,
                                                  float* __restrict__ Ar,
                                                  float* __restrict__ bsum) {
  int tid = threadIdx.x;
  for (int idx = tid; idx < NH * KIN; idx += 256) {
    int h = idx / KIN, k = idx % KIN;
    float sl = 0.f, sr = 0.f;
    for (int f = 0; f < 64; ++f) {
      float w = W[(size_t)(h * 64 + f) * KIN + k];
      sl += al[h * 64 + f] * w;
      sr += ar[h * 64 + f] * w;
    }
    Al[idx] = sl;
    Ar[idx] = sr;
  }
  if (tid < 64) {
    float s = 0.f;
#pragma unroll
    for (int h = 0; h < NH; ++h) s += b[h * 64 + tid];
    bsum[tid] = s;
  }
}

// ====== GEMM: feat = X @ W^T; fused el/er = X @ Al^T / X @ Ar^T ======
template <int KIN>
__global__ __launch_bounds__(256) void gemmKernel(const float* __restrict__ X,
                                                  const float* __restrict__ W,
                                                  const float* __restrict__ Al,
                                                  const float* __restrict__ Ar,
                                                  float* __restrict__ out,
                                                  float* __restrict__ el,
                                                  float* __restrict__ er, int n) {
  const int XS = KIN + 4;  // padded LDS stride
  __shared__ float xt[32 * (KIN + 4)];
  int tid = threadIdx.x;
  int n0 = blockIdx.x * 32;
  for (int i = tid; i < 32 * KIN; i += 256) {
    int r = i / KIN, k = i % KIN;
    xt[r * XS + k] = (n0 + r < n) ? X[(size_t)(n0 + r) * KIN + k] : 0.f;
  }
  __syncthreads();
  int j0 = tid * 2;
  float acc0[32], acc1[32];
#pragma unroll
  for (int r = 0; r < 32; ++r) { acc0[r] = 0.f; acc1[r] = 0.f; }
  const float4* w0p = (const float4*)(W + (size_t)j0 * KIN);
  const float4* w1p = (const float4*)(W + (size_t)(j0 + 1) * KIN);
  for (int k4 = 0; k4 < KIN / 4; ++k4) {
    float4 w0 = w0p[k4];
    float4 w1 = w1p[k4];
#pragma unroll
    for (int r = 0; r < 32; ++r) {
      float4 xv = *(const float4*)&xt[r * XS + k4 * 4];
      acc0[r] += xv.x * w0.x + xv.y * w0.y + xv.z * w0.z + xv.w * w0.w;
      acc1[r] += xv.x * w1.x + xv.y * w1.y + xv.z * w1.z + xv.w * w1.w;
    }
  }
#pragma unroll
  for (int r = 0; r < 32; ++r) {
    int nn = n0 + r;
    if (nn < n) *(float2*)&out[(size_t)nn * HF + j0] = make_float2(acc0[r], acc1[r]);
  }
  // epilogue: el/er. thread t -> row r2=t>>3, head h2=t&7
  int r2 = tid >> 3, h2 = tid & 7;
  if (n0 + r2 < n) {
    float accl = 0.f, accr = 0.f;
    const float4* wl = (const float4*)(Al + (size_t)h2 * KIN);
    const float4* wr = (const float4*)(Ar + (size_t)h2 * KIN);
    for (int k4 = 0; k4 < KIN / 4; ++k4) {
      float4 xv = *(const float4*)&xt[r2 * XS + k4 * 4];
      float4 a = wl[k4], c = wr[k4];
      accl += xv.x * a.x + xv.y * a.y + xv.z * a.z + xv.w * a.w;
      accr += xv.x * c.x + xv.y * c.y + xv.z * c.z + xv.w * c.w;
    }
    el[(size_t)(n0 + r2) * NH + h2] = accl;
    er[(size_t)(n0 + r2) * NH + h2] = accr;
  }
}

// ====== aggregate: one node per block, 4 waves split the edges, LDS combine ======
// lane l: heads hA=l>>4, hB=hA+4; feats fb=(l&15)*4..+3.
__global__ __launch_bounds__(256) void aggKernel(const float* __restrict__ feat,
                                                 const float* __restrict__ el,
                                                 const float* __restrict__ er,
                                                 const int* __restrict__ row_ptr,
                                                 const int* __restrict__ srcs,
                                                 const float* __restrict__ bsum,
                                                 float* __restrict__ xout, int n) {
  __shared__ float sd[3][64][10];  // waves 1..3 partials: accA(4) accB(4) sumA sumB
  int node = blockIdx.x;
  if (node >= n) return;
  int tid = threadIdx.x;
  int w = tid >> 6;
  int lane = tid & 63;
  int s0 = row_ptr[node], s1 = row_ptr[node + 1];
  int hA = lane >> 4;
  int hB = hA + 4;
  float erA = er[(size_t)node * NH + hA];
  float erB = er[(size_t)node * NH + hB];
  float4 accA = {0.f, 0.f, 0.f, 0.f};
  float4 accB = {0.f, 0.f, 0.f, 0.f};
  float sumA = 0.f, sumB = 0.f;

#define EDGE_BODY(ELA, ELB, VA, VB)                                       \
  {                                                                       \
    float tA = (ELA) + erA; tA = (tA > 0.f) ? tA : 0.2f * tA;             \
    float tB = (ELB) + erB; tB = (tB > 0.f) ? tB : 0.2f * tB;             \
    float aA = __expf(tA);                                                \
    float aB = __expf(tB);                                                \
    sumA += aA; sumB += aB;                                               \
    accA.x += aA * (VA).x; accA.y += aA * (VA).y;                         \
    accA.z += aA * (VA).z; accA.w += aA * (VA).w;                         \
    accB.x += aB * (VB).x; accB.y += aB * (VB).y;                         \
    accB.z += aB * (VB).z; accB.w += aB * (VB).w;                         \
  }

  for (int base = s0; base < s1; base += 64) {
    int nb = s1 - base;
    if (nb > 64) nb = 64;
    int li = base + lane;
    int sv = srcs[li < s1 ? li : s1 - 1];
    // full quads, distributed: wave w takes quad indices qi == w (mod 4)
    for (int e = w * 4; e + 4 <= nb; e += 16) {
      int sa = __shfl(sv, e);
      int sb = __shfl(sv, e + 1);
      int sc = __shfl(sv, e + 2);
      int se = __shfl(sv, e + 3);
      float elA0 = el[(size_t)sa * NH + hA], elB0 = el[(size_t)sa * NH + hB];
      float elA1 = el[(size_t)sb * NH + hA], elB1 = el[(size_t)sb * NH + hB];
      float elA2 = el[(size_t)sc * NH + hA], elB2 = el[(size_t)sc * NH + hB];
      float elA3 = el[(size_t)se * NH + hA], elB3 = el[(size_t)se * NH + hB];
      const float4* f0 = (const float4*)(feat + (size_t)sa * HF);
      const float4* f1 = (const float4*)(feat + (size_t)sb * HF);
      const float4* f2 = (const float4*)(feat + (size_t)sc * HF);
      const float4* f3 = (const float4*)(feat + (size_t)se * HF);
      float4 vA0 = f0[lane], vB0 = f0[64 + lane];
      float4 vA1 = f1[lane], vB1 = f1[64 + lane];
      float4 vA2 = f2[lane], vB2 = f2[64 + lane];
      float4 vA3 = f3[lane], vB3 = f3[64 + lane];
      EDGE_BODY(elA0, elB0, vA0, vB0)
      EDGE_BODY(elA1, elB1, vA1, vB1)
      EDGE_BODY(elA2, elB2, vA2, vB2)
      EDGE_BODY(elA3, elB3, vA3, vB3)
    }
    // tail (<4 edges): wave 0
    if (w == 0) {
      for (int e = nb & ~3; e < nb; ++e) {
        int sx = __shfl(sv, e);
        float elA = el[(size_t)sx * NH + hA], elB = el[(size_t)sx * NH + hB];
        const float4* fr = (const float4*)(feat + (size_t)sx * HF);
        float4 vA = fr[lane], vB = fr[64 + lane];
        EDGE_BODY(elA, elB, vA, vB)
      }
    }
  }
#undef EDGE_BODY

  if (w > 0) {
    float* q = sd[w - 1][lane];
    *(float4*)q = accA;
    *(float4*)(q + 4) = accB;
    q[8] = sumA;
    q[9] = sumB;
  }
  __syncthreads();
  if (w == 0) {
#pragma unroll
    for (int j = 0; j < 3; ++j) {
      const float* q = sd[j][lane];
      float4 tA = *(const float4*)q;
      float4 tB = *(const float4*)(q + 4);
      accA.x += tA.x; accA.y += tA.y; accA.z += tA.z; accA.w += tA.w;
      accB.x += tB.x; accB.y += tB.y; accB.z += tB.z; accB.w += tB.w;
      sumA += q[8];
      sumB += q[9];
    }
    float siA = (s1 > s0) ? 1.f / sumA : 0.f;
    float siB = (s1 > s0) ? 1.f / sumB : 0.f;
    float4 acc;
    acc.x = accA.x * siA + accB.x * siB;
    acc.y = accA.y * siA + accB.y * siB;
    acc.z = accA.z * siA + accB.z * siB;
    acc.w = accA.w * siA + accB.w * siB;
#pragma unroll
    for (int k = 16; k <= 32; k <<= 1) {
      acc.x += __shfl_xor(acc.x, k);
      acc.y += __shfl_xor(acc.y, k);
      acc.z += __shfl_xor(acc.z, k);
      acc.w += __shfl_xor(acc.w, k);
    }
    if (lane < 16) {
      float4 bz = ((const float4*)bsum)[lane];
      float4 o;
      o.x = acc.x + bz.x; o.x = (o.x > 0.f) ? o.x : 0.01f * o.x;
      o.y = acc.y + bz.y; o.y = (o.y > 0.f) ? o.y : 0.01f * o.y;
      o.z = acc.z + bz.z; o.z = (o.z > 0.f) ? o.z : 0.01f * o.z;
      o.w = acc.w + bz.w; o.w = (o.w > 0.f) ? o.w : 0.01f * o.w;
      ((float4*)(xout + (size_t)node * 64))[lane] = o;
    }
  }
}

// ============================ final dense: out = x @ Wm^T + bm ============================
__global__ __launch_bounds__(256) void finalKernel(const float* __restrict__ x,
                                                   const float* __restrict__ Wm,
                                                   const float* __restrict__ bm,
                                                   float* __restrict__ out, int n) {
  __shared__ float wt[64 * 65];
  int tid = threadIdx.x;
  for (int i = tid; i < 4096; i += 256) {
    int j = i >> 6, k = i & 63;
    wt[k * 65 + j] = Wm[i];
  }
  __syncthreads();
  int node = blockIdx.x * 4 + (tid >> 6);
  int lane = tid & 63;
  if (node >= n) return;
  const float* xr = x + (size_t)node * 64;
  float acc = bm[lane];
#pragma unroll 8
  for (int k = 0; k < 64; ++k) acc += xr[k] * wt[k * 65 + lane];
  out[(size_t)node * 64 + lane] = acc;
}

// ============================ launch ============================
extern "C" void kernel_launch(void* const* d_in, const int* in_sizes, int n_in,
                              void* d_out, int out_size, void* d_ws, size_t ws_size,
                              hipStream_t stream) {
  const float* inputs = (const float*)d_in[0];
  const int* src = (const int*)d_in[1];
  const int* dst = (const int*)d_in[2];
  const float* W1 = (const float*)d_in[3];
  const float* al1 = (const float*)d_in[4];
  const float* ar1 = (const float*)d_in[5];
  const float* b1 = (const float*)d_in[6];
  const float* W2 = (const float*)d_in[7];
  const float* al2 = (const float*)d_in[8];
  const float* ar2 = (const float*)d_in[9];
  const float* b2 = (const float*)d_in[10];
  const float* W3 = (const float*)d_in[11];
  const float* al3 = (const float*)d_in[12];
  const float* ar3 = (const float*)d_in[13];
  const float* b3 = (const float*)d_in[14];
  const float* Wm = (const float*)d_in[15];
  const float* bm = (const float*)d_in[16];
  float* out = (float*)d_out;

  char* p = (char*)d_ws;
  auto carve = [&](size_t bytes) {
    void* r = (void*)p;
    p += (bytes + 255) & ~(size_t)255;
    return r;
  };
  float* feat = (float*)carve((size_t)NN * HF * 4);      // 102.4 MB
  float* el = (float*)carve((size_t)NN * NH * 4);
  float* er = (float*)carve((size_t)NN * NH * 4);
  float* xbuf = (float*)carve((size_t)NN * 64 * 4);      // 12.8 MB
  float* Albuf = (float*)carve((size_t)NH * IN_DIM * 4);
  float* Arbuf = (float*)carve((size_t)NH * IN_DIM * 4);
  float* bsum = (float*)carve(64 * 4);
  int* row_ptr = (int*)carve((size_t)(NN + 1) * 4);
  int* srcs = (int*)carve((size_t)NE * 4);
  int* deg = (int*)carve((size_t)NN * 4);
  int* cursor = (int*)carve((size_t)NN * 4);
  int* bsums = (int*)carve(256 * 4);

  const int edgeBlocks = (NE + 255) / 256;   // 3125
  const int nBlocks = (NN + 255) / 256;      // 196
  const int gemmBlocks = (NN + 31) / 32;     // 1563
  const int node4Blocks = (NN + 3) / 4;      // 12500 (finalKernel)

  // ---- CSR build ----
  zeroIntKernel<<<nBlocks, 256, 0, stream>>>(deg, NN);
  histKernel<<<edgeBlocks, 256, 0, stream>>>(dst, deg, NE);
  scanBlockKernel<<<nBlocks, 256, 0, stream>>>(deg, row_ptr, bsums, NN);
  scanTopKernel<<<1, 256, 0, stream>>>(bsums, nBlocks);
  scanAddKernel<<<nBlocks, 256, 0, stream>>>(row_ptr, bsums, NN);
  copyIntKernel<<<nBlocks, 256, 0, stream>>>(row_ptr, cursor, NN);
  fillKernel<<<edgeBlocks, 256, 0, stream>>>(src, dst, cursor, srcs, NE);

  // ---- layer 1 ----
  prepKernel<IN_DIM><<<1, 256, 0, stream>>>(W1, al1, ar1, b1, Albuf, Arbuf, bsum);
  gemmKernel<IN_DIM><<<gemmBlocks, 256, 0, stream>>>(inputs, W1, Albuf, Arbuf, feat, el, er, NN);
  aggKernel<<<NN, 256, 0, stream>>>(feat, el, er, row_ptr, srcs, bsum, xbuf, NN);

  // ---- layer 2 ----
  prepKernel<HIDF><<<1, 256, 0, stream>>>(W2, al2, ar2, b2, Albuf, Arbuf, bsum);
  gemmKernel<HIDF><<<gemmBlocks, 256, 0, stream>>>(xbuf, W2, Albuf, Arbuf, feat, el, er, NN);
  aggKernel<<<NN, 256, 0, stream>>>(feat, el, er, row_ptr, srcs, bsum, xbuf, NN);

  // ---- layer 3 ----
  prepKernel<HIDF><<<1, 256, 0, stream>>>(W3, al3, ar3, b3, Albuf, Arbuf, bsum);
  gemmKernel<HIDF><<<gemmBlocks, 256, 0, stream>>>(xbuf, W3, Albuf, Arbuf, feat, el, er, NN);
  aggKernel<<<NN, 256, 0, stream>>>(feat, el, er, row_ptr, srcs, bsum, xbuf, NN);

  // ---- final dense ----
  finalKernel<<<node4Blocks, 256, 0, stream>>>(xbuf, Wm, bm, out, NN);
}

// Round 6
// 968.704 us; speedup vs baseline: 1.5094x; 1.3630x over previous
//
#include <hip/hip_runtime.h>
#include <hip/hip_bf16.h>
#include <math.h>

#define NN 50000
#define NE 800000
#define IN_DIM 128
#define HIDF 64
#define NH 8
#define HF 512   /* NH*HIDF */
#define OUT_DIM 64

// ============================ utility ============================

__global__ __launch_bounds__(256) void zeroIntKernel(int* __restrict__ a, int n) {
  int i = blockIdx.x * 256 + threadIdx.x;
  if (i < n) a[i] = 0;
}

// ============================ CSR build ============================

__global__ __launch_bounds__(256) void histKernel(const int* __restrict__ dst,
                                                  int* __restrict__ deg, int e) {
  int i = blockIdx.x * 256 + threadIdx.x;
  if (i < e) atomicAdd(&deg[dst[i]], 1);
}

__global__ __launch_bounds__(256) void scanBlockKernel(const int* __restrict__ deg,
                                                       int* __restrict__ row_ptr,
                                                       int* __restrict__ bsums, int n) {
  __shared__ int sd[256];
  int i = blockIdx.x * 256 + threadIdx.x;
  int v = (i < n) ? deg[i] : 0;
  sd[threadIdx.x] = v;
  __syncthreads();
  for (int off = 1; off < 256; off <<= 1) {
    int t = (threadIdx.x >= off) ? sd[threadIdx.x - off] : 0;
    __syncthreads();
    sd[threadIdx.x] += t;
    __syncthreads();
  }
  if (i < n) row_ptr[i + 1] = sd[threadIdx.x];
  if (threadIdx.x == 255) bsums[blockIdx.x] = sd[255];
  if (i == 0) row_ptr[0] = 0;
}

__global__ __launch_bounds__(256) void scanTopKernel(int* __restrict__ bsums, int nb) {
  __shared__ int sd[256];
  int v = (threadIdx.x < nb) ? bsums[threadIdx.x] : 0;
  sd[threadIdx.x] = v;
  __syncthreads();
  for (int off = 1; off < 256; off <<= 1) {
    int t = (threadIdx.x >= off) ? sd[threadIdx.x - off] : 0;
    __syncthreads();
    sd[threadIdx.x] += t;
    __syncthreads();
  }
  if (threadIdx.x < nb) bsums[threadIdx.x] = sd[threadIdx.x] - v;  // exclusive
}

__global__ __launch_bounds__(256) void scanAddKernel(int* __restrict__ row_ptr,
                                                     const int* __restrict__ bsums, int n) {
  int i = blockIdx.x * 256 + threadIdx.x;
  if (i < n) row_ptr[i + 1] += bsums[blockIdx.x];
}

__global__ __launch_bounds__(256) void copyIntKernel(const int* __restrict__ a,
                                                     int* __restrict__ b, int n) {
  int i = blockIdx.x * 256 + threadIdx.x;
  if (i < n) b[i] = a[i];
}

__global__ __launch_bounds__(256) void fillKernel(const int* __restrict__ src,
                                                  const int* __restrict__ dst,
                                                  int* __restrict__ cursor,
                                                  int* __restrict__ srcs, int e) {
  int i = blockIdx.x * 256 + threadIdx.x;
  if (i < e) {
    int d = dst[i];
    int pos = atomicAdd(&cursor[d], 1);
    srcs[pos] = src[i];
  }
}

// ====== prep: Al[h,k]=sum_f al[h,f]*W[h*64+f,k]; Ar likewise; bsum[f]=sum_h b[h,f] ======
template <int KIN>
__global__ __launch_bounds__(256) void prepKernel(const float* __restrict__ W,
                                                  const float* __restrict__ al,
                                                  const float* __restrict__ ar,
                                                  const float* __restrict__ b,
                                                  float* __restrict__ Al,
                                                  float* __restrict__ Ar,
                                                  float* __restrict__ bsum) {
  int tid = threadIdx.x;
  for (int idx = tid; idx < NH * KIN; idx += 256) {
    int h = idx / KIN, k = idx % KIN;
    float sl = 0.f, sr = 0.f;
    for (int f = 0; f < 64; ++f) {
      float w = W[(size_t)(h * 64 + f) * KIN + k];
      sl += al[h * 64 + f] * w;
      sr += ar[h * 64 + f] * w;
    }
    Al[idx] = sl;
    Ar[idx] = sr;
  }
  if (tid < 64) {
    float s = 0.f;
#pragma unroll
    for (int h = 0; h < NH; ++h) s += b[h * 64 + tid];
    bsum[tid] = s;
  }
}

// ====== transpose W [512][KIN] -> Wt [KIN][512] ======
template <int KIN>
__global__ __launch_bounds__(256) void transWKernel(const float* __restrict__ W,
                                                    float* __restrict__ Wt) {
  int idx = blockIdx.x * 256 + threadIdx.x;
  if (idx < 512 * KIN) {
    int j = idx / KIN, k = idx % KIN;
    Wt[k * 512 + j] = W[idx];
  }
}

// ====== GEMM: featb(bf16) = X @ W^T; fused el/er = X @ Al^T / X @ Ar^T ======
// Wt is [KIN][512] so col loads are coalesced.
template <int KIN>
__global__ __launch_bounds__(256) void gemmKernel(const float* __restrict__ X,
                                                  const float* __restrict__ Wt,
                                                  const float* __restrict__ Al,
                                                  const float* __restrict__ Ar,
                                                  __hip_bfloat162* __restrict__ featb2,
                                                  float* __restrict__ el,
                                                  float* __restrict__ er, int n) {
  const int XS = KIN + 4;  // padded LDS stride
  __shared__ float xt[32 * (KIN + 4)];
  int tid = threadIdx.x;
  int n0 = blockIdx.x * 32;
  for (int i = tid; i < 32 * KIN; i += 256) {
    int r = i / KIN, k = i % KIN;
    xt[r * XS + k] = (n0 + r < n) ? X[(size_t)(n0 + r) * KIN + k] : 0.f;
  }
  __syncthreads();
  int j0 = tid * 2;
  float acc0[32], acc1[32];
#pragma unroll
  for (int r = 0; r < 32; ++r) { acc0[r] = 0.f; acc1[r] = 0.f; }
  for (int k4 = 0; k4 < KIN / 4; ++k4) {
    float2 wa = *(const float2*)&Wt[(size_t)(k4 * 4 + 0) * 512 + j0];
    float2 wb = *(const float2*)&Wt[(size_t)(k4 * 4 + 1) * 512 + j0];
    float2 wc = *(const float2*)&Wt[(size_t)(k4 * 4 + 2) * 512 + j0];
    float2 wd = *(const float2*)&Wt[(size_t)(k4 * 4 + 3) * 512 + j0];
#pragma unroll
    for (int r = 0; r < 32; ++r) {
      float4 xv = *(const float4*)&xt[r * XS + k4 * 4];
      acc0[r] += xv.x * wa.x + xv.y * wb.x + xv.z * wc.x + xv.w * wd.x;
      acc1[r] += xv.x * wa.y + xv.y * wb.y + xv.z * wc.y + xv.w * wd.y;
    }
  }
#pragma unroll
  for (int r = 0; r < 32; ++r) {
    int nn = n0 + r;
    if (nn < n)
      featb2[(size_t)nn * 256 + tid] = __float22bfloat162_rn(make_float2(acc0[r], acc1[r]));
  }
  // epilogue: el/er. thread t -> row r2=t>>3, head h2=t&7
  int r2 = tid >> 3, h2 = tid & 7;
  if (n0 + r2 < n) {
    float accl = 0.f, accr = 0.f;
    const float4* wl = (const float4*)(Al + (size_t)h2 * KIN);
    const float4* wr = (const float4*)(Ar + (size_t)h2 * KIN);
    for (int k4 = 0; k4 < KIN / 4; ++k4) {
      float4 xv = *(const float4*)&xt[r2 * XS + k4 * 4];
      float4 a = wl[k4], c = wr[k4];
      accl += xv.x * a.x + xv.y * a.y + xv.z * a.z + xv.w * a.w;
      accr += xv.x * c.x + xv.y * c.y + xv.z * c.z + xv.w * c.w;
    }
    el[(size_t)(n0 + r2) * NH + h2] = accl;
    er[(size_t)(n0 + r2) * NH + h2] = accr;
  }
}

// ====== aggregate: one node per block, 4 waves split edges, bf16 feat (1 uint4/lane/edge) ======
// lane l: head hl = l>>3, feats fbase=(l&7)*8 .. +7
__global__ __launch_bounds__(256) void aggKernel(const uint4* __restrict__ featb4,
                                                 const float* __restrict__ el,
                                                 const float* __restrict__ er,
                                                 const int* __restrict__ row_ptr,
                                                 const int* __restrict__ srcs,
                                                 const float* __restrict__ bsum,
                                                 float* __restrict__ xout, int n) {
  __shared__ float sd[3][64][10];  // waves 1..3 partials: acc(8) + sum + pad
  int node = blockIdx.x;
  if (node >= n) return;
  int tid = threadIdx.x;
  int w = tid >> 6;
  int lane = tid & 63;
  int s0 = row_ptr[node], s1 = row_ptr[node + 1];
  int hl = lane >> 3;
  float erv = er[(size_t)node * NH + hl];
  float a0 = 0.f, a1 = 0.f, a2 = 0.f, a3 = 0.f, a4 = 0.f, a5 = 0.f, a6 = 0.f, a7 = 0.f;
  float sum = 0.f;

#define EDGE_BODY(SX, V)                                                  \
  {                                                                       \
    float t = el[(size_t)(SX)*NH + hl] + erv;                             \
    t = (t > 0.f) ? t : 0.2f * t;                                         \
    float av = __expf(t);                                                 \
    sum += av;                                                            \
    a0 += av * __uint_as_float((V).x << 16);                              \
    a1 += av * __uint_as_float((V).x & 0xffff0000u);                      \
    a2 += av * __uint_as_float((V).y << 16);                              \
    a3 += av * __uint_as_float((V).y & 0xffff0000u);                      \
    a4 += av * __uint_as_float((V).z << 16);                              \
    a5 += av * __uint_as_float((V).z & 0xffff0000u);                      \
    a6 += av * __uint_as_float((V).w << 16);                              \
    a7 += av * __uint_as_float((V).w & 0xffff0000u);                      \
  }

  for (int base = s0; base < s1; base += 64) {
    int nb = s1 - base;
    if (nb > 64) nb = 64;
    int li = base + lane;
    int sv = srcs[li < s1 ? li : s1 - 1];
    for (int e = w * 4; e + 4 <= nb; e += 16) {
      int sa = __shfl(sv, e);
      int sb = __shfl(sv, e + 1);
      int sc = __shfl(sv, e + 2);
      int se = __shfl(sv, e + 3);
      uint4 v0 = featb4[(size_t)sa * 64 + lane];
      uint4 v1 = featb4[(size_t)sb * 64 + lane];
      uint4 v2 = featb4[(size_t)sc * 64 + lane];
      uint4 v3 = featb4[(size_t)se * 64 + lane];
      EDGE_BODY(sa, v0)
      EDGE_BODY(sb, v1)
      EDGE_BODY(sc, v2)
      EDGE_BODY(se, v3)
    }
    if (w == 0) {
      for (int e = nb & ~3; e < nb; ++e) {
        int sx = __shfl(sv, e);
        uint4 v = featb4[(size_t)sx * 64 + lane];
        EDGE_BODY(sx, v)
      }
    }
  }
#undef EDGE_BODY

  if (w > 0) {
    float* q = sd[w - 1][lane];
    q[0] = a0; q[1] = a1; q[2] = a2; q[3] = a3;
    q[4] = a4; q[5] = a5; q[6] = a6; q[7] = a7;
    q[8] = sum;
  }
  __syncthreads();
  if (w == 0) {
#pragma unroll
    for (int j = 0; j < 3; ++j) {
      const float* q = sd[j][lane];
      a0 += q[0]; a1 += q[1]; a2 += q[2]; a3 += q[3];
      a4 += q[4]; a5 += q[5]; a6 += q[6]; a7 += q[7];
      sum += q[8];
    }
    float inv = (s1 > s0) ? 1.f / sum : 0.f;
    a0 *= inv; a1 *= inv; a2 *= inv; a3 *= inv;
    a4 *= inv; a5 *= inv; a6 *= inv; a7 *= inv;
    // sum over heads: lanes with same (l&7)
#pragma unroll
    for (int k = 8; k <= 32; k <<= 1) {
      a0 += __shfl_xor(a0, k); a1 += __shfl_xor(a1, k);
      a2 += __shfl_xor(a2, k); a3 += __shfl_xor(a3, k);
      a4 += __shfl_xor(a4, k); a5 += __shfl_xor(a5, k);
      a6 += __shfl_xor(a6, k); a7 += __shfl_xor(a7, k);
    }
    if (lane < 8) {
      float4 b0 = ((const float4*)bsum)[lane * 2];
      float4 b1 = ((const float4*)bsum)[lane * 2 + 1];
      float4 o0, o1;
      o0.x = a0 + b0.x; o0.x = (o0.x > 0.f) ? o0.x : 0.01f * o0.x;
      o0.y = a1 + b0.y; o0.y = (o0.y > 0.f) ? o0.y : 0.01f * o0.y;
      o0.z = a2 + b0.z; o0.z = (o0.z > 0.f) ? o0.z : 0.01f * o0.z;
      o0.w = a3 + b0.w; o0.w = (o0.w > 0.f) ? o0.w : 0.01f * o0.w;
      o1.x = a4 + b1.x; o1.x = (o1.x > 0.f) ? o1.x : 0.01f * o1.x;
      o1.y = a5 + b1.y; o1.y = (o1.y > 0.f) ? o1.y : 0.01f * o1.y;
      o1.z = a6 + b1.z; o1.z = (o1.z > 0.f) ? o1.z : 0.01f * o1.z;
      o1.w = a7 + b1.w; o1.w = (o1.w > 0.f) ? o1.w : 0.01f * o1.w;
      float4* op = (float4*)(xout + (size_t)node * 64 + lane * 8);
      op[0] = o0;
      op[1] = o1;
    }
  }
}

// ============================ final dense: out = x @ Wm^T + bm ============================
__global__ __launch_bounds__(256) void finalKernel(const float* __restrict__ x,
                                                   const float* __restrict__ Wm,
                                                   const float* __restrict__ bm,
                                                   float* __restrict__ out, int n) {
  __shared__ float wt[64 * 65];
  int tid = threadIdx.x;
  for (int i = tid; i < 4096; i += 256) {
    int j = i >> 6, k = i & 63;
    wt[k * 65 + j] = Wm[i];
  }
  __syncthreads();
  int node = blockIdx.x * 4 + (tid >> 6);
  int lane = tid & 63;
  if (node >= n) return;
  const float* xr = x + (size_t)node * 64;
  float acc = bm[lane];
#pragma unroll 8
  for (int k = 0; k < 64; ++k) acc += xr[k] * wt[k * 65 + lane];
  out[(size_t)node * 64 + lane] = acc;
}

// ============================ launch ============================
extern "C" void kernel_launch(void* const* d_in, const int* in_sizes, int n_in,
                              void* d_out, int out_size, void* d_ws, size_t ws_size,
                              hipStream_t stream) {
  const float* inputs = (const float*)d_in[0];
  const int* src = (const int*)d_in[1];
  const int* dst = (const int*)d_in[2];
  const float* W1 = (const float*)d_in[3];
  const float* al1 = (const float*)d_in[4];
  const float* ar1 = (const float*)d_in[5];
  const float* b1 = (const float*)d_in[6];
  const float* W2 = (const float*)d_in[7];
  const float* al2 = (const float*)d_in[8];
  const float* ar2 = (const float*)d_in[9];
  const float* b2 = (const float*)d_in[10];
  const float* W3 = (const float*)d_in[11];
  const float* al3 = (const float*)d_in[12];
  const float* ar3 = (const float*)d_in[13];
  const float* b3 = (const float*)d_in[14];
  const float* Wm = (const float*)d_in[15];
  const float* bm = (const float*)d_in[16];
  float* out = (float*)d_out;

  char* p = (char*)d_ws;
  auto carve = [&](size_t bytes) {
    void* r = (void*)p;
    p += (bytes + 255) & ~(size_t)255;
    return r;
  };
  __hip_bfloat162* featb2 = (__hip_bfloat162*)carve((size_t)NN * HF * 2);  // 51.2 MB bf16
  float* el = (float*)carve((size_t)NN * NH * 4);
  float* er = (float*)carve((size_t)NN * NH * 4);
  float* xbuf = (float*)carve((size_t)NN * 64 * 4);      // 12.8 MB
  float* Albuf = (float*)carve((size_t)NH * IN_DIM * 4);
  float* Arbuf = (float*)carve((size_t)NH * IN_DIM * 4);
  float* Wt = (float*)carve((size_t)IN_DIM * 512 * 4);   // 256 KB
  float* bsum = (float*)carve(64 * 4);
  int* row_ptr = (int*)carve((size_t)(NN + 1) * 4);
  int* srcs = (int*)carve((size_t)NE * 4);
  int* deg = (int*)carve((size_t)NN * 4);
  int* cursor = (int*)carve((size_t)NN * 4);
  int* bsums = (int*)carve(256 * 4);

  const int edgeBlocks = (NE + 255) / 256;   // 3125
  const int nBlocks = (NN + 255) / 256;      // 196
  const int gemmBlocks = (NN + 31) / 32;     // 1563
  const int node4Blocks = (NN + 3) / 4;      // 12500 (finalKernel)

  // ---- CSR build ----
  zeroIntKernel<<<nBlocks, 256, 0, stream>>>(deg, NN);
  histKernel<<<edgeBlocks, 256, 0, stream>>>(dst, deg, NE);
  scanBlockKernel<<<nBlocks, 256, 0, stream>>>(deg, row_ptr, bsums, NN);
  scanTopKernel<<<1, 256, 0, stream>>>(bsums, nBlocks);
  scanAddKernel<<<nBlocks, 256, 0, stream>>>(row_ptr, bsums, NN);
  copyIntKernel<<<nBlocks, 256, 0, stream>>>(row_ptr, cursor, NN);
  fillKernel<<<edgeBlocks, 256, 0, stream>>>(src, dst, cursor, srcs, NE);

  // ---- layer 1 ----
  prepKernel<IN_DIM><<<1, 256, 0, stream>>>(W1, al1, ar1, b1, Albuf, Arbuf, bsum);
  transWKernel<IN_DIM><<<(512 * IN_DIM) / 256, 256, 0, stream>>>(W1, Wt);
  gemmKernel<IN_DIM><<<gemmBlocks, 256, 0, stream>>>(inputs, Wt, Albuf, Arbuf, featb2, el, er, NN);
  aggKernel<<<NN, 256, 0, stream>>>((const uint4*)featb2, el, er, row_ptr, srcs, bsum, xbuf, NN);

  // ---- layer 2 ----
  prepKernel<HIDF><<<1, 256, 0, stream>>>(W2, al2, ar2, b2, Albuf, Arbuf, bsum);
  transWKernel<HIDF><<<(512 * HIDF) / 256, 256, 0, stream>>>(W2, Wt);
  gemmKernel<HIDF><<<gemmBlocks, 256, 0, stream>>>(xbuf, Wt, Albuf, Arbuf, featb2, el, er, NN);
  aggKernel<<<NN, 256, 0, stream>>>((const uint4*)featb2, el, er, row_ptr, srcs, bsum, xbuf, NN);

  // ---- layer 3 ----
  prepKernel<HIDF><<<1, 256, 0, stream>>>(W3, al3, ar3, b3, Albuf, Arbuf, bsum);
  transWKernel<HIDF><<<(512 * HIDF) / 256, 256, 0, stream>>>(W3, Wt);
  gemmKernel<HIDF><<<gemmBlocks, 256, 0, stream>>>(xbuf, Wt, Albuf, Arbuf, featb2, el, er, NN);
  aggKernel<<<NN, 256, 0, stream>>>((const uint4*)featb2, el, er, row_ptr, srcs, bsum, xbuf, NN);

  // ---- final dense ----
  finalKernel<<<node4Blocks, 256, 0, stream>>>(xbuf, Wm, bm, out, NN);
}

// Round 7
// 853.441 us; speedup vs baseline: 1.7132x; 1.1351x over previous
//
#include <hip/hip_runtime.h>
#include <hip/hip_bf16.h>
#include <math.h>

#define NN 50000
#define NE 800000
#define IN_DIM 128
#define HIDF 64
#define NH 8
#define HF 512   /* NH*HIDF */
#define OUT_DIM 64

typedef __attribute__((ext_vector_type(8))) short bf16x8;
typedef __attribute__((ext_vector_type(4))) float f32x4;

__device__ inline ushort f2b(float x) {
  union { __hip_bfloat16 b; ushort u; } c;
  c.b = __float2bfloat16(x);
  return c.u;
}

// ============================ utility ============================

__global__ __launch_bounds__(256) void zeroIntKernel(int* __restrict__ a, int n) {
  int i = blockIdx.x * 256 + threadIdx.x;
  if (i < n) a[i] = 0;
}

// ============================ CSR build ============================

__global__ __launch_bounds__(256) void histKernel(const int* __restrict__ dst,
                                                  int* __restrict__ deg, int e) {
  int i = blockIdx.x * 256 + threadIdx.x;
  if (i < e) atomicAdd(&deg[dst[i]], 1);
}

__global__ __launch_bounds__(256) void scanBlockKernel(const int* __restrict__ deg,
                                                       int* __restrict__ row_ptr,
                                                       int* __restrict__ bsums, int n) {
  __shared__ int sd[256];
  int i = blockIdx.x * 256 + threadIdx.x;
  int v = (i < n) ? deg[i] : 0;
  sd[threadIdx.x] = v;
  __syncthreads();
  for (int off = 1; off < 256; off <<= 1) {
    int t = (threadIdx.x >= off) ? sd[threadIdx.x - off] : 0;
    __syncthreads();
    sd[threadIdx.x] += t;
    __syncthreads();
  }
  if (i < n) row_ptr[i + 1] = sd[threadIdx.x];
  if (threadIdx.x == 255) bsums[blockIdx.x] = sd[255];
  if (i == 0) row_ptr[0] = 0;
}

__global__ __launch_bounds__(256) void scanTopKernel(int* __restrict__ bsums, int nb) {
  __shared__ int sd[256];
  int v = (threadIdx.x < nb) ? bsums[threadIdx.x] : 0;
  sd[threadIdx.x] = v;
  __syncthreads();
  for (int off = 1; off < 256; off <<= 1) {
    int t = (threadIdx.x >= off) ? sd[threadIdx.x - off] : 0;
    __syncthreads();
    sd[threadIdx.x] += t;
    __syncthreads();
  }
  if (threadIdx.x < nb) bsums[threadIdx.x] = sd[threadIdx.x] - v;  // exclusive
}

__global__ __launch_bounds__(256) void scanAddKernel(int* __restrict__ row_ptr,
                                                     const int* __restrict__ bsums, int n) {
  int i = blockIdx.x * 256 + threadIdx.x;
  if (i < n) row_ptr[i + 1] += bsums[blockIdx.x];
}

__global__ __launch_bounds__(256) void copyIntKernel(const int* __restrict__ a,
                                                     int* __restrict__ b, int n) {
  int i = blockIdx.x * 256 + threadIdx.x;
  if (i < n) b[i] = a[i];
}

__global__ __launch_bounds__(256) void fillKernel(const int* __restrict__ src,
                                                  const int* __restrict__ dst,
                                                  int* __restrict__ cursor,
                                                  int* __restrict__ srcs, int e) {
  int i = blockIdx.x * 256 + threadIdx.x;
  if (i < e) {
    int d = dst[i];
    int pos = atomicAdd(&cursor[d], 1);
    srcs[pos] = src[i];
  }
}

// ====== prep: Al[h,k]=sum_f al[h,f]*W[h*64+f,k]; Ar likewise; bsum[f]=sum_h b[h,f] ======
template <int KIN>
__global__ __launch_bounds__(256) void prepKernel(const float* __restrict__ W,
                                                  const float* __restrict__ al,
                                                  const float* __restrict__ ar,
                                                  const float* __restrict__ b,
                                                  float* __restrict__ Al,
                                                  float* __restrict__ Ar,
                                                  float* __restrict__ bsum) {
  int tid = threadIdx.x;
  for (int idx = tid; idx < NH * KIN; idx += 256) {
    int h = idx / KIN, k = idx % KIN;
    float sl = 0.f, sr = 0.f;
    for (int f = 0; f < 64; ++f) {
      float w = W[(size_t)(h * 64 + f) * KIN + k];
      sl += al[h * 64 + f] * w;
      sr += ar[h * 64 + f] * w;
    }
    Al[idx] = sl;
    Ar[idx] = sr;
  }
  if (tid < 64) {
    float s = 0.f;
#pragma unroll
    for (int h = 0; h < NH; ++h) s += b[h * 64 + tid];
    bsum[tid] = s;
  }
}

// ====== pack W [512][KIN] f32 -> bf16 B-fragments ======
// Wp[ ((kb*4+g)*512 + n)*8 + j ] = bf16( W[n][ kb*32 + (j>=4)*16 + g*4 + (j&3) ] )
template <int KIN>
__global__ __launch_bounds__(256) void packWKernel(const float* __restrict__ W,
                                                   ushort* __restrict__ Wp) {
  int idx = blockIdx.x * 256 + threadIdx.x;
  if (idx < 512 * KIN) {
    int j = idx & 7;
    int nn = (idx >> 3) & 511;
    int rest = idx >> 12;
    int g = rest & 3, kb = rest >> 2;
    int k = kb * 32 + (j >> 2) * 16 + g * 4 + (j & 3);
    Wp[idx] = f2b(W[(size_t)nn * KIN + k]);
  }
}

// ====== MFMA GEMM: featb(bf16)[n][512] = X @ W^T; fused el/er epilogue (f32 X) ======
// block: 32 rows x 512 cols, 4 waves; wave w owns cols [w*128, w*128+128)
template <int KIN>
__global__ __launch_bounds__(256) void gemmMfmaKernel(const float* __restrict__ X,
                                                      const ushort* __restrict__ Wp,
                                                      const float* __restrict__ Al,
                                                      const float* __restrict__ Ar,
                                                      ushort* __restrict__ featb,
                                                      float* __restrict__ el,
                                                      float* __restrict__ er, int n) {
  const int XS = KIN + 4;  // padded LDS stride (ushort units)
  __shared__ ushort xs[32 * (KIN + 4)];
  int tid = threadIdx.x;
  int n0 = blockIdx.x * 32;
  // stage X tile as bf16 (coalesced f32 reads)
  for (int i = tid; i < 32 * KIN; i += 256) {
    int r = i / KIN, k = i % KIN;
    float v = (n0 + r < n) ? X[(size_t)(n0 + r) * KIN + k] : 0.f;
    xs[r * XS + k] = f2b(v);
  }
  __syncthreads();

  int w = tid >> 6;
  int l = tid & 63;
  int lc = l & 15;   // fragment col / row lane index
  int g = l >> 4;    // k-group
  f32x4 acc[2][8];
#pragma unroll
  for (int mr = 0; mr < 2; ++mr)
#pragma unroll
    for (int nr = 0; nr < 8; ++nr) acc[mr][nr] = (f32x4){0.f, 0.f, 0.f, 0.f};

#pragma unroll
  for (int kb = 0; kb < KIN / 32; ++kb) {
    int kk = kb * 32;
    bf16x8 afr[2];
#pragma unroll
    for (int mr = 0; mr < 2; ++mr) {
      int row = mr * 16 + lc;
      uint2 lo = *(const uint2*)&xs[row * XS + kk + g * 4];
      uint2 hi = *(const uint2*)&xs[row * XS + kk + 16 + g * 4];
      int4 tmp = make_int4((int)lo.x, (int)lo.y, (int)hi.x, (int)hi.y);
      afr[mr] = __builtin_bit_cast(bf16x8, tmp);
    }
    const ushort* wpb = Wp + ((size_t)(kb * 4 + g) * 512) * 8;
#pragma unroll
    for (int nr = 0; nr < 8; ++nr) {
      int nc = w * 128 + nr * 16 + lc;
      bf16x8 bfr = *(const bf16x8*)&wpb[(size_t)nc * 8];
      acc[0][nr] = __builtin_amdgcn_mfma_f32_16x16x32_bf16(afr[0], bfr, acc[0][nr], 0, 0, 0);
      acc[1][nr] = __builtin_amdgcn_mfma_f32_16x16x32_bf16(afr[1], bfr, acc[1][nr], 0, 0, 0);
    }
  }

  // store: row = n0 + mr*16 + g*4 + j ; col = w*128 + nr*16 + lc
#pragma unroll
  for (int mr = 0; mr < 2; ++mr) {
#pragma unroll
    for (int j = 0; j < 4; ++j) {
      int rr = n0 + mr * 16 + g * 4 + j;
      if (rr < n) {
        ushort* orow = featb + (size_t)rr * 512 + w * 128 + lc;
#pragma unroll
        for (int nr = 0; nr < 8; ++nr) orow[nr * 16] = f2b(acc[mr][nr][j]);
      }
    }
  }

  // epilogue: el/er from f32 X (exact logits). thread t -> row r2=t>>3, head h2=t&7
  int r2 = tid >> 3, h2 = tid & 7;
  if (n0 + r2 < n) {
    float accl = 0.f, accr = 0.f;
    const float4* xr = (const float4*)(X + (size_t)(n0 + r2) * KIN);
    const float4* wl = (const float4*)(Al + (size_t)h2 * KIN);
    const float4* wr = (const float4*)(Ar + (size_t)h2 * KIN);
    for (int k4 = 0; k4 < KIN / 4; ++k4) {
      float4 xv = xr[k4];
      float4 a = wl[k4], c = wr[k4];
      accl += xv.x * a.x + xv.y * a.y + xv.z * a.z + xv.w * a.w;
      accr += xv.x * c.x + xv.y * c.y + xv.z * c.z + xv.w * c.w;
    }
    el[(size_t)(n0 + r2) * NH + h2] = accl;
    er[(size_t)(n0 + r2) * NH + h2] = accr;
  }
}

// ====== aggregate: one node per block, 4 waves split edges, bf16 feat (1 uint4/lane/edge) ======
// lane l: head hl = l>>3, feats fbase=(l&7)*8 .. +7
__global__ __launch_bounds__(256) void aggKernel(const uint4* __restrict__ featb4,
                                                 const float* __restrict__ el,
                                                 const float* __restrict__ er,
                                                 const int* __restrict__ row_ptr,
                                                 const int* __restrict__ srcs,
                                                 const float* __restrict__ bsum,
                                                 float* __restrict__ xout, int n) {
  __shared__ float sd[3][64][10];  // waves 1..3 partials: acc(8) + sum + pad
  int node = blockIdx.x;
  if (node >= n) return;
  int tid = threadIdx.x;
  int w = tid >> 6;
  int lane = tid & 63;
  int s0 = row_ptr[node], s1 = row_ptr[node + 1];
  int hl = lane >> 3;
  float erv = er[(size_t)node * NH + hl];
  float a0 = 0.f, a1 = 0.f, a2 = 0.f, a3 = 0.f, a4 = 0.f, a5 = 0.f, a6 = 0.f, a7 = 0.f;
  float sum = 0.f;

#define EDGE_BODY(SX, V)                                                  \
  {                                                                       \
    float t = el[(size_t)(SX)*NH + hl] + erv;                             \
    t = (t > 0.f) ? t : 0.2f * t;                                         \
    float av = __expf(t);                                                 \
    sum += av;                                                            \
    a0 += av * __uint_as_float((V).x << 16);                              \
    a1 += av * __uint_as_float((V).x & 0xffff0000u);                      \
    a2 += av * __uint_as_float((V).y << 16);                              \
    a3 += av * __uint_as_float((V).y & 0xffff0000u);                      \
    a4 += av * __uint_as_float((V).z << 16);                              \
    a5 += av * __uint_as_float((V).z & 0xffff0000u);                      \
    a6 += av * __uint_as_float((V).w << 16);                              \
    a7 += av * __uint_as_float((V).w & 0xffff0000u);                      \
  }

  for (int base = s0; base < s1; base += 64) {
    int nb = s1 - base;
    if (nb > 64) nb = 64;
    int li = base + lane;
    int sv = srcs[li < s1 ? li : s1 - 1];
    for (int e = w * 4; e + 4 <= nb; e += 16) {
      int sa = __shfl(sv, e);
      int sb = __shfl(sv, e + 1);
      int sc = __shfl(sv, e + 2);
      int se = __shfl(sv, e + 3);
      uint4 v0 = featb4[(size_t)sa * 64 + lane];
      uint4 v1 = featb4[(size_t)sb * 64 + lane];
      uint4 v2 = featb4[(size_t)sc * 64 + lane];
      uint4 v3 = featb4[(size_t)se * 64 + lane];
      EDGE_BODY(sa, v0)
      EDGE_BODY(sb, v1)
      EDGE_BODY(sc, v2)
      EDGE_BODY(se, v3)
    }
    if (w == 0) {
      for (int e = nb & ~3; e < nb; ++e) {
        int sx = __shfl(sv, e);
        uint4 v = featb4[(size_t)sx * 64 + lane];
        EDGE_BODY(sx, v)
      }
    }
  }
#undef EDGE_BODY

  if (w > 0) {
    float* q = sd[w - 1][lane];
    q[0] = a0; q[1] = a1; q[2] = a2; q[3] = a3;
    q[4] = a4; q[5] = a5; q[6] = a6; q[7] = a7;
    q[8] = sum;
  }
  __syncthreads();
  if (w == 0) {
#pragma unroll
    for (int j = 0; j < 3; ++j) {
      const float* q = sd[j][lane];
      a0 += q[0]; a1 += q[1]; a2 += q[2]; a3 += q[3];
      a4 += q[4]; a5 += q[5]; a6 += q[6]; a7 += q[7];
      sum += q[8];
    }
    float inv = (s1 > s0) ? 1.f / sum : 0.f;
    a0 *= inv; a1 *= inv; a2 *= inv; a3 *= inv;
    a4 *= inv; a5 *= inv; a6 *= inv; a7 *= inv;
    // sum over heads: lanes with same (l&7)
#pragma unroll
    for (int k = 8; k <= 32; k <<= 1) {
      a0 += __shfl_xor(a0, k); a1 += __shfl_xor(a1, k);
      a2 += __shfl_xor(a2, k); a3 += __shfl_xor(a3, k);
      a4 += __shfl_xor(a4, k); a5 += __shfl_xor(a5, k);
      a6 += __shfl_xor(a6, k); a7 += __shfl_xor(a7, k);
    }
    if (lane < 8) {
      float4 b0 = ((const float4*)bsum)[lane * 2];
      float4 b1 = ((const float4*)bsum)[lane * 2 + 1];
      float4 o0, o1;
      o0.x = a0 + b0.x; o0.x = (o0.x > 0.f) ? o0.x : 0.01f * o0.x;
      o0.y = a1 + b0.y; o0.y = (o0.y > 0.f) ? o0.y : 0.01f * o0.y;
      o0.z = a2 + b0.z; o0.z = (o0.z > 0.f) ? o0.z : 0.01f * o0.z;
      o0.w = a3 + b0.w; o0.w = (o0.w > 0.f) ? o0.w : 0.01f * o0.w;
      o1.x = a4 + b1.x; o1.x = (o1.x > 0.f) ? o1.x : 0.01f * o1.x;
      o1.y = a5 + b1.y; o1.y = (o1.y > 0.f) ? o1.y : 0.01f * o1.y;
      o1.z = a6 + b1.z; o1.z = (o1.z > 0.f) ? o1.z : 0.01f * o1.z;
      o1.w = a7 + b1.w; o1.w = (o1.w > 0.f) ? o1.w : 0.01f * o1.w;
      float4* op = (float4*)(xout + (size_t)node * 64 + lane * 8);
      op[0] = o0;
      op[1] = o1;
    }
  }
}

// ============================ final dense: out = x @ Wm^T + bm ============================
__global__ __launch_bounds__(256) void finalKernel(const float* __restrict__ x,
                                                   const float* __restrict__ Wm,
                                                   const float* __restrict__ bm,
                                                   float* __restrict__ out, int n) {
  __shared__ float wt[64 * 65];
  int tid = threadIdx.x;
  for (int i = tid; i < 4096; i += 256) {
    int j = i >> 6, k = i & 63;
    wt[k * 65 + j] = Wm[i];
  }
  __syncthreads();
  int node = blockIdx.x * 4 + (tid >> 6);
  int lane = tid & 63;
  if (node >= n) return;
  const float* xr = x + (size_t)node * 64;
  float acc = bm[lane];
#pragma unroll 8
  for (int k = 0; k < 64; ++k) acc += xr[k] * wt[k * 65 + lane];
  out[(size_t)node * 64 + lane] = acc;
}

// ============================ launch ============================
extern "C" void kernel_launch(void* const* d_in, const int* in_sizes, int n_in,
                              void* d_out, int out_size, void* d_ws, size_t ws_size,
                              hipStream_t stream) {
  const float* inputs = (const float*)d_in[0];
  const int* src = (const int*)d_in[1];
  const int* dst = (const int*)d_in[2];
  const float* W1 = (const float*)d_in[3];
  const float* al1 = (const float*)d_in[4];
  const float* ar1 = (const float*)d_in[5];
  const float* b1 = (const float*)d_in[6];
  const float* W2 = (const float*)d_in[7];
  const float* al2 = (const float*)d_in[8];
  const float* ar2 = (const float*)d_in[9];
  const float* b2 = (const float*)d_in[10];
  const float* W3 = (const float*)d_in[11];
  const float* al3 = (const float*)d_in[12];
  const float* ar3 = (const float*)d_in[13];
  const float* b3 = (const float*)d_in[14];
  const float* Wm = (const float*)d_in[15];
  const float* bm = (const float*)d_in[16];
  float* out = (float*)d_out;

  char* p = (char*)d_ws;
  auto carve = [&](size_t bytes) {
    void* r = (void*)p;
    p += (bytes + 255) & ~(size_t)255;
    return r;
  };
  ushort* featb = (ushort*)carve((size_t)NN * HF * 2);   // 51.2 MB bf16
  float* el = (float*)carve((size_t)NN * NH * 4);
  float* er = (float*)carve((size_t)NN * NH * 4);
  float* xbuf = (float*)carve((size_t)NN * 64 * 4);      // 12.8 MB
  float* Albuf = (float*)carve((size_t)NH * IN_DIM * 4);
  float* Arbuf = (float*)carve((size_t)NH * IN_DIM * 4);
  ushort* Wp = (ushort*)carve((size_t)IN_DIM * 512 * 2); // 128 KB
  float* bsum = (float*)carve(64 * 4);
  int* row_ptr = (int*)carve((size_t)(NN + 1) * 4);
  int* srcs = (int*)carve((size_t)NE * 4);
  int* deg = (int*)carve((size_t)NN * 4);
  int* cursor = (int*)carve((size_t)NN * 4);
  int* bsums = (int*)carve(256 * 4);

  const int edgeBlocks = (NE + 255) / 256;   // 3125
  const int nBlocks = (NN + 255) / 256;      // 196
  const int gemmBlocks = (NN + 31) / 32;     // 1563
  const int node4Blocks = (NN + 3) / 4;      // 12500 (finalKernel)

  // ---- CSR build ----
  zeroIntKernel<<<nBlocks, 256, 0, stream>>>(deg, NN);
  histKernel<<<edgeBlocks, 256, 0, stream>>>(dst, deg, NE);
  scanBlockKernel<<<nBlocks, 256, 0, stream>>>(deg, row_ptr, bsums, NN);
  scanTopKernel<<<1, 256, 0, stream>>>(bsums, nBlocks);
  scanAddKernel<<<nBlocks, 256, 0, stream>>>(row_ptr, bsums, NN);
  copyIntKernel<<<nBlocks, 256, 0, stream>>>(row_ptr, cursor, NN);
  fillKernel<<<edgeBlocks, 256, 0, stream>>>(src, dst, cursor, srcs, NE);

  // ---- layer 1 ----
  prepKernel<IN_DIM><<<1, 256, 0, stream>>>(W1, al1, ar1, b1, Albuf, Arbuf, bsum);
  packWKernel<IN_DIM><<<(512 * IN_DIM) / 256, 256, 0, stream>>>(W1, Wp);
  gemmMfmaKernel<IN_DIM><<<gemmBlocks, 256, 0, stream>>>(inputs, Wp, Albuf, Arbuf, featb, el, er, NN);
  aggKernel<<<NN, 256, 0, stream>>>((const uint4*)featb, el, er, row_ptr, srcs, bsum, xbuf, NN);

  // ---- layer 2 ----
  prepKernel<HIDF><<<1, 256, 0, stream>>>(W2, al2, ar2, b2, Albuf, Arbuf, bsum);
  packWKernel<HIDF><<<(512 * HIDF) / 256, 256, 0, stream>>>(W2, Wp);
  gemmMfmaKernel<HIDF><<<gemmBlocks, 256, 0, stream>>>(xbuf, Wp, Albuf, Arbuf, featb, el, er, NN);
  aggKernel<<<NN, 256, 0, stream>>>((const uint4*)featb, el, er, row_ptr, srcs, bsum, xbuf, NN);

  // ---- layer 3 ----
  prepKernel<HIDF><<<1, 256, 0, stream>>>(W3, al3, ar3, b3, Albuf, Arbuf, bsum);
  packWKernel<HIDF><<<(512 * HIDF) / 256, 256, 0, stream>>>(W3, Wp);
  gemmMfmaKernel<HIDF><<<gemmBlocks, 256, 0, stream>>>(xbuf, Wp, Albuf, Arbuf, featb, el, er, NN);
  aggKernel<<<NN, 256, 0, stream>>>((const uint4*)featb, el, er, row_ptr, srcs, bsum, xbuf, NN);

  // ---- final dense ----
  finalKernel<<<node4Blocks, 256, 0, stream>>>(xbuf, Wm, bm, out, NN);
}

// Round 8
// 827.119 us; speedup vs baseline: 1.7677x; 1.0318x over previous
//
#include <hip/hip_runtime.h>
#include <hip/hip_bf16.h>
#include <math.h>

#define NN 50000
#define NE 800000
#define IN_DIM 128
#define HIDF 64
#define NH 8
#define HF 512   /* NH*HIDF */
#define OUT_DIM 64

typedef __attribute__((ext_vector_type(8))) short bf16x8;
typedef __attribute__((ext_vector_type(4))) float f32x4;

__device__ inline ushort f2b(float x) {
  union { __hip_bfloat16 b; ushort u; } c;
  c.b = __float2bfloat16(x);
  return c.u;
}

// ============================ utility ============================

__global__ __launch_bounds__(256) void zeroIntKernel(int* __restrict__ a, int n) {
  int i = blockIdx.x * 256 + threadIdx.x;
  if (i < n) a[i] = 0;
}

// ============================ CSR build ============================

__global__ __launch_bounds__(256) void histKernel(const int* __restrict__ dst,
                                                  int* __restrict__ deg, int e) {
  int i = blockIdx.x * 256 + threadIdx.x;
  if (i < e) atomicAdd(&deg[dst[i]], 1);
}

__global__ __launch_bounds__(256) void scanBlockKernel(const int* __restrict__ deg,
                                                       int* __restrict__ row_ptr,
                                                       int* __restrict__ bsums, int n) {
  __shared__ int sd[256];
  int i = blockIdx.x * 256 + threadIdx.x;
  int v = (i < n) ? deg[i] : 0;
  sd[threadIdx.x] = v;
  __syncthreads();
  for (int off = 1; off < 256; off <<= 1) {
    int t = (threadIdx.x >= off) ? sd[threadIdx.x - off] : 0;
    __syncthreads();
    sd[threadIdx.x] += t;
    __syncthreads();
  }
  if (i < n) row_ptr[i + 1] = sd[threadIdx.x];
  if (threadIdx.x == 255) bsums[blockIdx.x] = sd[255];
  if (i == 0) row_ptr[0] = 0;
}

__global__ __launch_bounds__(256) void scanTopKernel(int* __restrict__ bsums, int nb) {
  __shared__ int sd[256];
  int v = (threadIdx.x < nb) ? bsums[threadIdx.x] : 0;
  sd[threadIdx.x] = v;
  __syncthreads();
  for (int off = 1; off < 256; off <<= 1) {
    int t = (threadIdx.x >= off) ? sd[threadIdx.x - off] : 0;
    __syncthreads();
    sd[threadIdx.x] += t;
    __syncthreads();
  }
  if (threadIdx.x < nb) bsums[threadIdx.x] = sd[threadIdx.x] - v;  // exclusive
}

__global__ __launch_bounds__(256) void scanAddKernel(int* __restrict__ row_ptr,
                                                     const int* __restrict__ bsums, int n) {
  int i = blockIdx.x * 256 + threadIdx.x;
  if (i < n) row_ptr[i + 1] += bsums[blockIdx.x];
}

__global__ __launch_bounds__(256) void copyIntKernel(const int* __restrict__ a,
                                                     int* __restrict__ b, int n) {
  int i = blockIdx.x * 256 + threadIdx.x;
  if (i < n) b[i] = a[i];
}

__global__ __launch_bounds__(256) void fillKernel(const int* __restrict__ src,
                                                  const int* __restrict__ dst,
                                                  int* __restrict__ cursor,
                                                  int* __restrict__ srcs, int e) {
  int i = blockIdx.x * 256 + threadIdx.x;
  if (i < e) {
    int d = dst[i];
    int pos = atomicAdd(&cursor[d], 1);
    srcs[pos] = src[i];
  }
}

// ====== prep: Al[h,k]=sum_f al[h,f]*W[h*64+f,k]; Ar likewise; bsum[f]=sum_h b[h,f] ======
template <int KIN>
__global__ __launch_bounds__(256) void prepKernel(const float* __restrict__ W,
                                                  const float* __restrict__ al,
                                                  const float* __restrict__ ar,
                                                  const float* __restrict__ b,
                                                  float* __restrict__ Al,
                                                  float* __restrict__ Ar,
                                                  float* __restrict__ bsum) {
  int tid = threadIdx.x;
  for (int idx = tid; idx < NH * KIN; idx += 256) {
    int h = idx / KIN, k = idx % KIN;
    float sl = 0.f, sr = 0.f;
    for (int f = 0; f < 64; ++f) {
      float w = W[(size_t)(h * 64 + f) * KIN + k];
      sl += al[h * 64 + f] * w;
      sr += ar[h * 64 + f] * w;
    }
    Al[idx] = sl;
    Ar[idx] = sr;
  }
  if (tid < 64) {
    float s = 0.f;
#pragma unroll
    for (int h = 0; h < NH; ++h) s += b[h * 64 + tid];
    bsum[tid] = s;
  }
}

// ====== pack W [512][KIN] f32 -> bf16 B-fragments ======
// Wp[ ((kb*4+g)*512 + n)*8 + j ] = bf16( W[n][ kb*32 + (j>=4)*16 + g*4 + (j&3) ] )
template <int KIN>
__global__ __launch_bounds__(256) void packWKernel(const float* __restrict__ W,
                                                   ushort* __restrict__ Wp) {
  int idx = blockIdx.x * 256 + threadIdx.x;
  if (idx < 512 * KIN) {
    int j = idx & 7;
    int nn = (idx >> 3) & 511;
    int rest = idx >> 12;
    int g = rest & 3, kb = rest >> 2;
    int k = kb * 32 + (j >> 2) * 16 + g * 4 + (j & 3);
    Wp[idx] = f2b(W[(size_t)nn * KIN + k]);
  }
}

// ====== MFMA GEMM: featb(bf16)[n][512] = X @ W^T; fused el/er epilogue (f32 X) ======
// block: 32 rows x 512 cols, 4 waves; wave w owns cols [w*128, w*128+128)
// Output goes through LDS so global stores are coalesced uint4.
template <int KIN>
__global__ __launch_bounds__(256) void gemmMfmaKernel(const float* __restrict__ X,
                                                      const ushort* __restrict__ Wp,
                                                      const float* __restrict__ Al,
                                                      const float* __restrict__ Ar,
                                                      ushort* __restrict__ featb,
                                                      float* __restrict__ el,
                                                      float* __restrict__ er, int n) {
  const int XS = KIN + 4;   // ushort stride for X tile
  const int OS = 520;       // ushort stride for out tile (520 = 65*8, 16B-aligned rows)
  __shared__ ushort lbuf[32 * 520];  // 33.3 KB; reused: X tile then out tile
  ushort* xs = lbuf;
  int tid = threadIdx.x;
  int n0 = blockIdx.x * 32;
  // stage X tile as bf16 (coalesced f32 reads)
  for (int i = tid; i < 32 * KIN; i += 256) {
    int r = i / KIN, k = i % KIN;
    float v = (n0 + r < n) ? X[(size_t)(n0 + r) * KIN + k] : 0.f;
    xs[r * XS + k] = f2b(v);
  }
  __syncthreads();

  int w = tid >> 6;
  int l = tid & 63;
  int lc = l & 15;   // fragment col / row lane index
  int g = l >> 4;    // k-group
  f32x4 acc[2][8];
#pragma unroll
  for (int mr = 0; mr < 2; ++mr)
#pragma unroll
    for (int nr = 0; nr < 8; ++nr) acc[mr][nr] = (f32x4){0.f, 0.f, 0.f, 0.f};

#pragma unroll
  for (int kb = 0; kb < KIN / 32; ++kb) {
    int kk = kb * 32;
    bf16x8 afr[2];
#pragma unroll
    for (int mr = 0; mr < 2; ++mr) {
      int row = mr * 16 + lc;
      uint2 lo = *(const uint2*)&xs[row * XS + kk + g * 4];
      uint2 hi = *(const uint2*)&xs[row * XS + kk + 16 + g * 4];
      int4 tmp = make_int4((int)lo.x, (int)lo.y, (int)hi.x, (int)hi.y);
      afr[mr] = __builtin_bit_cast(bf16x8, tmp);
    }
    const ushort* wpb = Wp + ((size_t)(kb * 4 + g) * 512) * 8;
#pragma unroll
    for (int nr = 0; nr < 8; ++nr) {
      int nc = w * 128 + nr * 16 + lc;
      bf16x8 bfr = *(const bf16x8*)&wpb[(size_t)nc * 8];
      acc[0][nr] = __builtin_amdgcn_mfma_f32_16x16x32_bf16(afr[0], bfr, acc[0][nr], 0, 0, 0);
      acc[1][nr] = __builtin_amdgcn_mfma_f32_16x16x32_bf16(afr[1], bfr, acc[1][nr], 0, 0, 0);
    }
  }

  // epilogue: el/er from f32 X (exact logits). thread t -> row r2=t>>3, head h2=t&7
  int r2 = tid >> 3, h2 = tid & 7;
  float accl = 0.f, accr = 0.f;
  if (n0 + r2 < n) {
    const float4* xr = (const float4*)(X + (size_t)(n0 + r2) * KIN);
    const float4* wl = (const float4*)(Al + (size_t)h2 * KIN);
    const float4* wr = (const float4*)(Ar + (size_t)h2 * KIN);
    for (int k4 = 0; k4 < KIN / 4; ++k4) {
      float4 xv = xr[k4];
      float4 a = wl[k4], c = wr[k4];
      accl += xv.x * a.x + xv.y * a.y + xv.z * a.z + xv.w * a.w;
      accr += xv.x * c.x + xv.y * c.y + xv.z * c.z + xv.w * c.w;
    }
  }

  __syncthreads();  // X-tile reads all done; reuse lbuf as out tile
  // scatter acc -> LDS (row = mr*16+g*4+j, col = w*128+nr*16+lc)
#pragma unroll
  for (int mr = 0; mr < 2; ++mr) {
#pragma unroll
    for (int j = 0; j < 4; ++j) {
      int row = mr * 16 + g * 4 + j;
      ushort* orow = lbuf + row * OS + w * 128 + lc;
#pragma unroll
      for (int nr = 0; nr < 8; ++nr) orow[nr * 16] = f2b(acc[mr][nr][j]);
    }
  }
  __syncthreads();
  // coalesced store: 32 rows x 64 uint4
#pragma unroll
  for (int it = 0; it < 8; ++it) {
    int idx = it * 256 + tid;
    int row = idx >> 6, ucol = idx & 63;
    int rr = n0 + row;
    if (rr < n)
      *(uint4*)&featb[(size_t)rr * 512 + ucol * 8] = *(const uint4*)&lbuf[row * OS + ucol * 8];
  }

  if (n0 + r2 < n) {
    el[(size_t)(n0 + r2) * NH + h2] = accl;
    er[(size_t)(n0 + r2) * NH + h2] = accr;
  }
}

// ====== aggregate: one node per block, 4 waves split edges, bf16 feat (1 uint4/lane/edge) ======
// lane l: head hl = l>>3, feats fbase=(l&7)*8 .. +7
__global__ __launch_bounds__(256) void aggKernel(const uint4* __restrict__ featb4,
                                                 const float* __restrict__ el,
                                                 const float* __restrict__ er,
                                                 const int* __restrict__ row_ptr,
                                                 const int* __restrict__ srcs,
                                                 const float* __restrict__ bsum,
                                                 float* __restrict__ xout, int n) {
  __shared__ float sd[3][64][11];  // waves 1..3 partials: acc(8) + sum (stride 11: conflict-free)
  int node = blockIdx.x;
  if (node >= n) return;
  int tid = threadIdx.x;
  int w = tid >> 6;
  int lane = tid & 63;
  int s0 = row_ptr[node], s1 = row_ptr[node + 1];
  int hl = lane >> 3;
  float erv = er[(size_t)node * NH + hl];
  float a0 = 0.f, a1 = 0.f, a2 = 0.f, a3 = 0.f, a4 = 0.f, a5 = 0.f, a6 = 0.f, a7 = 0.f;
  float sum = 0.f;

#define EDGE_BODY(SX, V)                                                  \
  {                                                                       \
    float t = el[(size_t)(SX)*NH + hl] + erv;                             \
    t = (t > 0.f) ? t : 0.2f * t;                                         \
    float av = __expf(t);                                                 \
    sum += av;                                                            \
    a0 += av * __uint_as_float((V).x << 16);                              \
    a1 += av * __uint_as_float((V).x & 0xffff0000u);                      \
    a2 += av * __uint_as_float((V).y << 16);                              \
    a3 += av * __uint_as_float((V).y & 0xffff0000u);                      \
    a4 += av * __uint_as_float((V).z << 16);                              \
    a5 += av * __uint_as_float((V).z & 0xffff0000u);                      \
    a6 += av * __uint_as_float((V).w << 16);                              \
    a7 += av * __uint_as_float((V).w & 0xffff0000u);                      \
  }

  for (int base = s0; base < s1; base += 64) {
    int nb = s1 - base;
    if (nb > 64) nb = 64;
    int li = base + lane;
    int sv = srcs[li < s1 ? li : s1 - 1];
    for (int e = w * 4; e + 4 <= nb; e += 16) {
      int sa = __shfl(sv, e);
      int sb = __shfl(sv, e + 1);
      int sc = __shfl(sv, e + 2);
      int se = __shfl(sv, e + 3);
      uint4 v0 = featb4[(size_t)sa * 64 + lane];
      uint4 v1 = featb4[(size_t)sb * 64 + lane];
      uint4 v2 = featb4[(size_t)sc * 64 + lane];
      uint4 v3 = featb4[(size_t)se * 64 + lane];
      EDGE_BODY(sa, v0)
      EDGE_BODY(sb, v1)
      EDGE_BODY(sc, v2)
      EDGE_BODY(se, v3)
    }
    if (w == 0) {
      for (int e = nb & ~3; e < nb; ++e) {
        int sx = __shfl(sv, e);
        uint4 v = featb4[(size_t)sx * 64 + lane];
        EDGE_BODY(sx, v)
      }
    }
  }
#undef EDGE_BODY

  if (w > 0) {
    float* q = sd[w - 1][lane];
    q[0] = a0; q[1] = a1; q[2] = a2; q[3] = a3;
    q[4] = a4; q[5] = a5; q[6] = a6; q[7] = a7;
    q[8] = sum;
  }
  __syncthreads();
  if (w == 0) {
#pragma unroll
    for (int j = 0; j < 3; ++j) {
      const float* q = sd[j][lane];
      a0 += q[0]; a1 += q[1]; a2 += q[2]; a3 += q[3];
      a4 += q[4]; a5 += q[5]; a6 += q[6]; a7 += q[7];
      sum += q[8];
    }
    float inv = (s1 > s0) ? 1.f / sum : 0.f;
    a0 *= inv; a1 *= inv; a2 *= inv; a3 *= inv;
    a4 *= inv; a5 *= inv; a6 *= inv; a7 *= inv;
    // sum over heads: lanes with same (l&7)
#pragma unroll
    for (int k = 8; k <= 32; k <<= 1) {
      a0 += __shfl_xor(a0, k); a1 += __shfl_xor(a1, k);
      a2 += __shfl_xor(a2, k); a3 += __shfl_xor(a3, k);
      a4 += __shfl_xor(a4, k); a5 += __shfl_xor(a5, k);
      a6 += __shfl_xor(a6, k); a7 += __shfl_xor(a7, k);
    }
    if (lane < 8) {
      float4 b0 = ((const float4*)bsum)[lane * 2];
      float4 b1 = ((const float4*)bsum)[lane * 2 + 1];
      float4 o0, o1;
      o0.x = a0 + b0.x; o0.x = (o0.x > 0.f) ? o0.x : 0.01f * o0.x;
      o0.y = a1 + b0.y; o0.y = (o0.y > 0.f) ? o0.y : 0.01f * o0.y;
      o0.z = a2 + b0.z; o0.z = (o0.z > 0.f) ? o0.z : 0.01f * o0.z;
      o0.w = a3 + b0.w; o0.w = (o0.w > 0.f) ? o0.w : 0.01f * o0.w;
      o1.x = a4 + b1.x; o1.x = (o1.x > 0.f) ? o1.x : 0.01f * o1.x;
      o1.y = a5 + b1.y; o1.y = (o1.y > 0.f) ? o1.y : 0.01f * o1.y;
      o1.z = a6 + b1.z; o1.z = (o1.z > 0.f) ? o1.z : 0.01f * o1.z;
      o1.w = a7 + b1.w; o1.w = (o1.w > 0.f) ? o1.w : 0.01f * o1.w;
      float4* op = (float4*)(xout + (size_t)node * 64 + lane * 8);
      op[0] = o0;
      op[1] = o1;
    }
  }
}

// ============================ final dense: out = x @ Wm^T + bm ============================
__global__ __launch_bounds__(256) void finalKernel(const float* __restrict__ x,
                                                   const float* __restrict__ Wm,
                                                   const float* __restrict__ bm,
                                                   float* __restrict__ out, int n) {
  __shared__ float wt[64 * 65];
  int tid = threadIdx.x;
  for (int i = tid; i < 4096; i += 256) {
    int j = i >> 6, k = i & 63;
    wt[k * 65 + j] = Wm[i];
  }
  __syncthreads();
  int node = blockIdx.x * 4 + (tid >> 6);
  int lane = tid & 63;
  if (node >= n) return;
  const float* xr = x + (size_t)node * 64;
  float acc = bm[lane];
#pragma unroll 8
  for (int k = 0; k < 64; ++k) acc += xr[k] * wt[k * 65 + lane];
  out[(size_t)node * 64 + lane] = acc;
}

// ============================ launch ============================
extern "C" void kernel_launch(void* const* d_in, const int* in_sizes, int n_in,
                              void* d_out, int out_size, void* d_ws, size_t ws_size,
                              hipStream_t stream) {
  const float* inputs = (const float*)d_in[0];
  const int* src = (const int*)d_in[1];
  const int* dst = (const int*)d_in[2];
  const float* W1 = (const float*)d_in[3];
  const float* al1 = (const float*)d_in[4];
  const float* ar1 = (const float*)d_in[5];
  const float* b1 = (const float*)d_in[6];
  const float* W2 = (const float*)d_in[7];
  const float* al2 = (const float*)d_in[8];
  const float* ar2 = (const float*)d_in[9];
  const float* b2 = (const float*)d_in[10];
  const float* W3 = (const float*)d_in[11];
  const float* al3 = (const float*)d_in[12];
  const float* ar3 = (const float*)d_in[13];
  const float* b3 = (const float*)d_in[14];
  const float* Wm = (const float*)d_in[15];
  const float* bm = (const float*)d_in[16];
  float* out = (float*)d_out;

  char* p = (char*)d_ws;
  auto carve = [&](size_t bytes) {
    void* r = (void*)p;
    p += (bytes + 255) & ~(size_t)255;
    return r;
  };
  ushort* featb = (ushort*)carve((size_t)NN * HF * 2);   // 51.2 MB bf16
  float* el = (float*)carve((size_t)NN * NH * 4);
  float* er = (float*)carve((size_t)NN * NH * 4);
  float* xbuf = (float*)carve((size_t)NN * 64 * 4);      // 12.8 MB
  float* Albuf = (float*)carve((size_t)NH * IN_DIM * 4);
  float* Arbuf = (float*)carve((size_t)NH * IN_DIM * 4);
  ushort* Wp = (ushort*)carve((size_t)IN_DIM * 512 * 2); // 128 KB
  float* bsum = (float*)carve(64 * 4);
  int* row_ptr = (int*)carve((size_t)(NN + 1) * 4);
  int* srcs = (int*)carve((size_t)NE * 4);
  int* deg = (int*)carve((size_t)NN * 4);
  int* cursor = (int*)carve((size_t)NN * 4);
  int* bsums = (int*)carve(256 * 4);

  const int edgeBlocks = (NE + 255) / 256;   // 3125
  const int nBlocks = (NN + 255) / 256;      // 196
  const int gemmBlocks = (NN + 31) / 32;     // 1563
  const int node4Blocks = (NN + 3) / 4;      // 12500 (finalKernel)

  // ---- CSR build ----
  zeroIntKernel<<<nBlocks, 256, 0, stream>>>(deg, NN);
  histKernel<<<edgeBlocks, 256, 0, stream>>>(dst, deg, NE);
  scanBlockKernel<<<nBlocks, 256, 0, stream>>>(deg, row_ptr, bsums, NN);
  scanTopKernel<<<1, 256, 0, stream>>>(bsums, nBlocks);
  scanAddKernel<<<nBlocks, 256, 0, stream>>>(row_ptr, bsums, NN);
  copyIntKernel<<<nBlocks, 256, 0, stream>>>(row_ptr, cursor, NN);
  fillKernel<<<edgeBlocks, 256, 0, stream>>>(src, dst, cursor, srcs, NE);

  // ---- layer 1 ----
  prepKernel<IN_DIM><<<1, 256, 0, stream>>>(W1, al1, ar1, b1, Albuf, Arbuf, bsum);
  packWKernel<IN_DIM><<<(512 * IN_DIM) / 256, 256, 0, stream>>>(W1, Wp);
  gemmMfmaKernel<IN_DIM><<<gemmBlocks, 256, 0, stream>>>(inputs, Wp, Albuf, Arbuf, featb, el, er, NN);
  aggKernel<<<NN, 256, 0, stream>>>((const uint4*)featb, el, er, row_ptr, srcs, bsum, xbuf, NN);

  // ---- layer 2 ----
  prepKernel<HIDF><<<1, 256, 0, stream>>>(W2, al2, ar2, b2, Albuf, Arbuf, bsum);
  packWKernel<HIDF><<<(512 * HIDF) / 256, 256, 0, stream>>>(W2, Wp);
  gemmMfmaKernel<HIDF><<<gemmBlocks, 256, 0, stream>>>(xbuf, Wp, Albuf, Arbuf, featb, el, er, NN);
  aggKernel<<<NN, 256, 0, stream>>>((const uint4*)featb, el, er, row_ptr, srcs, bsum, xbuf, NN);

  // ---- layer 3 ----
  prepKernel<HIDF><<<1, 256, 0, stream>>>(W3, al3, ar3, b3, Albuf, Arbuf, bsum);
  packWKernel<HIDF><<<(512 * HIDF) / 256, 256, 0, stream>>>(W3, Wp);
  gemmMfmaKernel<HIDF><<<gemmBlocks, 256, 0, stream>>>(xbuf, Wp, Albuf, Arbuf, featb, el, er, NN);
  aggKernel<<<NN, 256, 0, stream>>>((const uint4*)featb, el, er, row_ptr, srcs, bsum, xbuf, NN);

  // ---- final dense ----
  finalKernel<<<node4Blocks, 256, 0, stream>>>(xbuf, Wm, bm, out, NN);
}

// Round 10
// 776.426 us; speedup vs baseline: 1.8832x; 1.0653x over previous
//
#include <hip/hip_runtime.h>
#include <hip/hip_bf16.h>
#include <math.h>

#define NN 50000
#define NE 800000
#define IN_DIM 128
#define HIDF 64
#define NH 8
#define HF 512   /* NH*HIDF */
#define OUT_DIM 64

typedef __attribute__((ext_vector_type(8))) short bf16x8;
typedef __attribute__((ext_vector_type(4))) float f32x4;

__device__ inline ushort f2b(float x) {
  union { __hip_bfloat16 b; ushort u; } c;
  c.b = __float2bfloat16(x);
  return c.u;
}

// ============================ utility ============================

__global__ __launch_bounds__(256) void zeroIntKernel(int* __restrict__ a, int n) {
  int i = blockIdx.x * 256 + threadIdx.x;
  if (i < n) a[i] = 0;
}

// ============================ CSR build ============================

__global__ __launch_bounds__(256) void histKernel(const int* __restrict__ dst,
                                                  int* __restrict__ deg, int e) {
  int i = blockIdx.x * 256 + threadIdx.x;
  if (i < e) atomicAdd(&deg[dst[i]], 1);
}

__global__ __launch_bounds__(256) void scanBlockKernel(const int* __restrict__ deg,
                                                       int* __restrict__ row_ptr,
                                                       int* __restrict__ bsums, int n) {
  __shared__ int sd[256];
  int i = blockIdx.x * 256 + threadIdx.x;
  int v = (i < n) ? deg[i] : 0;
  sd[threadIdx.x] = v;
  __syncthreads();
  for (int off = 1; off < 256; off <<= 1) {
    int t = (threadIdx.x >= off) ? sd[threadIdx.x - off] : 0;
    __syncthreads();
    sd[threadIdx.x] += t;
    __syncthreads();
  }
  if (i < n) row_ptr[i + 1] = sd[threadIdx.x];
  if (threadIdx.x == 255) bsums[blockIdx.x] = sd[255];
  if (i == 0) row_ptr[0] = 0;
}

__global__ __launch_bounds__(256) void scanTopKernel(int* __restrict__ bsums, int nb) {
  __shared__ int sd[256];
  int v = (threadIdx.x < nb) ? bsums[threadIdx.x] : 0;
  sd[threadIdx.x] = v;
  __syncthreads();
  for (int off = 1; off < 256; off <<= 1) {
    int t = (threadIdx.x >= off) ? sd[threadIdx.x - off] : 0;
    __syncthreads();
    sd[threadIdx.x] += t;
    __syncthreads();
  }
  if (threadIdx.x < nb) bsums[threadIdx.x] = sd[threadIdx.x] - v;  // exclusive
}

__global__ __launch_bounds__(256) void scanAddKernel(int* __restrict__ row_ptr,
                                                     const int* __restrict__ bsums, int n) {
  int i = blockIdx.x * 256 + threadIdx.x;
  if (i < n) row_ptr[i + 1] += bsums[blockIdx.x];
}

__global__ __launch_bounds__(256) void copyIntKernel(const int* __restrict__ a,
                                                     int* __restrict__ b, int n) {
  int i = blockIdx.x * 256 + threadIdx.x;
  if (i < n) b[i] = a[i];
}

__global__ __launch_bounds__(256) void fillKernel(const int* __restrict__ src,
                                                  const int* __restrict__ dst,
                                                  int* __restrict__ cursor,
                                                  int* __restrict__ srcs, int e) {
  int i = blockIdx.x * 256 + threadIdx.x;
  if (i < e) {
    int d = dst[i];
    int pos = atomicAdd(&cursor[d], 1);
    srcs[pos] = src[i];
  }
}

// ====== pack W [512][KIN] f32 -> bf16 B-fragments; block 0 also computes bsum ======
// Wp[ ((kb*4+g)*512 + n)*8 + j ] = bf16( W[n][ kb*32 + (j>=4)*16 + g*4 + (j&3) ] )
template <int KIN>
__global__ __launch_bounds__(256) void packWKernel(const float* __restrict__ W,
                                                   const float* __restrict__ b,
                                                   ushort* __restrict__ Wp,
                                                   float* __restrict__ bsum) {
  int idx = blockIdx.x * 256 + threadIdx.x;
  if (idx < 512 * KIN) {
    int j = idx & 7;
    int nn = (idx >> 3) & 511;
    int rest = idx >> 12;
    int g = rest & 3, kb = rest >> 2;
    int k = kb * 32 + (j >> 2) * 16 + g * 4 + (j & 3);
    Wp[idx] = f2b(W[(size_t)nn * KIN + k]);
  }
  if (blockIdx.x == 0 && threadIdx.x < 64) {
    float s = 0.f;
#pragma unroll
    for (int h = 0; h < NH; ++h) s += b[h * 64 + threadIdx.x];
    bsum[threadIdx.x] = s;
  }
}

// ====== MFMA GEMM: featb(bf16)[n][512] = X @ W^T; el/er from the feat LDS tile ======
// block: 32 rows x 512 cols, 4 waves; wave w owns cols [w*128, w*128+128)
template <int KIN>
__global__ __launch_bounds__(256) void gemmMfmaKernel(const float* __restrict__ X,
                                                      const ushort* __restrict__ Wp,
                                                      const float* __restrict__ al,
                                                      const float* __restrict__ ar,
                                                      ushort* __restrict__ featb,
                                                      float* __restrict__ el,
                                                      float* __restrict__ er, int n) {
  const int XS = KIN + 4;   // ushort stride for X tile
  const int OS = 520;       // ushort stride for out tile (rows 16B-aligned)
  __shared__ ushort lbuf[32 * 520];  // 33.3 KB; reused: X tile then feat tile
  ushort* xs = lbuf;
  int tid = threadIdx.x;
  int n0 = blockIdx.x * 32;
  // stage X tile as bf16, paired converts (coalesced float2 reads)
  const int PR = KIN / 2;
  for (int i = tid; i < 32 * PR; i += 256) {
    int r = i / PR, k = (i - r * PR) * 2;
    float2 v = (n0 + r < n) ? *(const float2*)&X[(size_t)(n0 + r) * KIN + k]
                            : make_float2(0.f, 0.f);
    uint packed = (uint)f2b(v.x) | ((uint)f2b(v.y) << 16);
    *(uint*)&xs[r * XS + k] = packed;
  }
  __syncthreads();

  int w = tid >> 6;
  int l = tid & 63;
  int lc = l & 15;   // fragment col / row lane index
  int g = l >> 4;    // k-group
  f32x4 acc[2][8];
#pragma unroll
  for (int mr = 0; mr < 2; ++mr)
#pragma unroll
    for (int nr = 0; nr < 8; ++nr) acc[mr][nr] = (f32x4){0.f, 0.f, 0.f, 0.f};

#pragma unroll
  for (int kb = 0; kb < KIN / 32; ++kb) {
    int kk = kb * 32;
    bf16x8 afr[2];
#pragma unroll
    for (int mr = 0; mr < 2; ++mr) {
      int row = mr * 16 + lc;
      uint2 lo = *(const uint2*)&xs[row * XS + kk + g * 4];
      uint2 hi = *(const uint2*)&xs[row * XS + kk + 16 + g * 4];
      int4 tmp = make_int4((int)lo.x, (int)lo.y, (int)hi.x, (int)hi.y);
      afr[mr] = __builtin_bit_cast(bf16x8, tmp);
    }
    const ushort* wpb = Wp + ((size_t)(kb * 4 + g) * 512) * 8;
#pragma unroll
    for (int nr = 0; nr < 8; ++nr) {
      int nc = w * 128 + nr * 16 + lc;
      bf16x8 bfr = *(const bf16x8*)&wpb[(size_t)nc * 8];
      acc[0][nr] = __builtin_amdgcn_mfma_f32_16x16x32_bf16(afr[0], bfr, acc[0][nr], 0, 0, 0);
      acc[1][nr] = __builtin_amdgcn_mfma_f32_16x16x32_bf16(afr[1], bfr, acc[1][nr], 0, 0, 0);
    }
  }

  __syncthreads();  // X-tile reads done; reuse lbuf as feat tile
  // scatter acc -> LDS (row = mr*16+g*4+j, col = w*128+nr*16+lc)
#pragma unroll
  for (int mr = 0; mr < 2; ++mr) {
#pragma unroll
    for (int j = 0; j < 4; ++j) {
      int row = mr * 16 + g * 4 + j;
      ushort* orow = lbuf + row * OS + w * 128 + lc;
#pragma unroll
      for (int nr = 0; nr < 8; ++nr) orow[nr * 16] = f2b(acc[mr][nr][j]);
    }
  }
  __syncthreads();
  // coalesced global store: 32 rows x 64 uint4
#pragma unroll
  for (int it = 0; it < 8; ++it) {
    int idx = it * 256 + tid;
    int row = idx >> 6, ucol = idx & 63;
    int rr = n0 + row;
    if (rr < n)
      *(uint4*)&featb[(size_t)rr * 512 + ucol * 8] = *(const uint4*)&lbuf[row * OS + ucol * 8];
  }

  // el/er from the bf16 feat tile: thread t -> row r2=t>>3, head h2=t&7
  int r2 = tid >> 3, h2 = tid & 7;
  if (n0 + r2 < n) {
    const ushort* frow = lbuf + r2 * OS + h2 * 64;
    const float4* alp = (const float4*)(al + (size_t)h2 * 64);
    const float4* arp = (const float4*)(ar + (size_t)h2 * 64);
    float accl = 0.f, accr = 0.f;
#pragma unroll
    for (int fb = 0; fb < 8; ++fb) {
      uint4 u = *(const uint4*)&frow[fb * 8];
      float4 a0 = alp[fb * 2], a1 = alp[fb * 2 + 1];
      float4 c0 = arp[fb * 2], c1 = arp[fb * 2 + 1];
      float f0 = __uint_as_float(u.x << 16), f1 = __uint_as_float(u.x & 0xffff0000u);
      float f2 = __uint_as_float(u.y << 16), f3 = __uint_as_float(u.y & 0xffff0000u);
      float f4 = __uint_as_float(u.z << 16), f5 = __uint_as_float(u.z & 0xffff0000u);
      float f6 = __uint_as_float(u.w << 16), f7 = __uint_as_float(u.w & 0xffff0000u);
      accl += f0 * a0.x + f1 * a0.y + f2 * a0.z + f3 * a0.w +
              f4 * a1.x + f5 * a1.y + f6 * a1.z + f7 * a1.w;
      accr += f0 * c0.x + f1 * c0.y + f2 * c0.z + f3 * c0.w +
              f4 * c1.x + f5 * c1.y + f6 * c1.z + f7 * c1.w;
    }
    el[(size_t)(n0 + r2) * NH + h2] = accl;
    er[(size_t)(n0 + r2) * NH + h2] = accr;
  }
}

// ====== aggregate: one node per block, 4 waves split edges, bf16 feat ======
// lane l: head hl = l>>3, feats fbase=(l&7)*8 .. +7
// FINAL=1: fuse out = leaky(agg) @ Wm^T + bm (wave 0), writing f32 out[node][64]
template <int FINAL>
__global__ __launch_bounds__(256) void aggKernel(const uint4* __restrict__ featb4,
                                                 const float* __restrict__ el,
                                                 const float* __restrict__ er,
                                                 const int* __restrict__ row_ptr,
                                                 const int* __restrict__ srcs,
                                                 const float* __restrict__ bsum,
                                                 const float* __restrict__ Wm,
                                                 const float* __restrict__ bm,
                                                 float* __restrict__ xout, int n) {
  __shared__ float sd[3][64][11];  // waves 1..3 partials: acc(8) + sum
  __shared__ float xo[64];
  int node = blockIdx.x;
  if (node >= n) return;
  int tid = threadIdx.x;
  int w = tid >> 6;
  int lane = tid & 63;
  int s0 = row_ptr[node], s1 = row_ptr[node + 1];
  int hl = lane >> 3;
  float erv = er[(size_t)node * NH + hl];
  float a0 = 0.f, a1 = 0.f, a2 = 0.f, a3 = 0.f, a4 = 0.f, a5 = 0.f, a6 = 0.f, a7 = 0.f;
  float sum = 0.f;

#define EDGE_BODY(SX, V)                                                  \
  {                                                                       \
    float t = el[(size_t)(SX)*NH + hl] + erv;                             \
    t = (t > 0.f) ? t : 0.2f * t;                                         \
    float av = __expf(t);                                                 \
    sum += av;                                                            \
    a0 += av * __uint_as_float((V).x << 16);                              \
    a1 += av * __uint_as_float((V).x & 0xffff0000u);                      \
    a2 += av * __uint_as_float((V).y << 16);                              \
    a3 += av * __uint_as_float((V).y & 0xffff0000u);                      \
    a4 += av * __uint_as_float((V).z << 16);                              \
    a5 += av * __uint_as_float((V).z & 0xffff0000u);                      \
    a6 += av * __uint_as_float((V).w << 16);                              \
    a7 += av * __uint_as_float((V).w & 0xffff0000u);                      \
  }

  for (int base = s0; base < s1; base += 64) {
    int nb = s1 - base;
    if (nb > 64) nb = 64;
    int li = base + lane;
    int sv = srcs[li < s1 ? li : s1 - 1];
    for (int e = w * 4; e + 4 <= nb; e += 16) {
      int sa = __shfl(sv, e);
      int sb = __shfl(sv, e + 1);
      int sc = __shfl(sv, e + 2);
      int se = __shfl(sv, e + 3);
      uint4 v0 = featb4[(size_t)sa * 64 + lane];
      uint4 v1 = featb4[(size_t)sb * 64 + lane];
      uint4 v2 = featb4[(size_t)sc * 64 + lane];
      uint4 v3 = featb4[(size_t)se * 64 + lane];
      EDGE_BODY(sa, v0)
      EDGE_BODY(sb, v1)
      EDGE_BODY(sc, v2)
      EDGE_BODY(se, v3)
    }
    if (w == 0) {
      for (int e = nb & ~3; e < nb; ++e) {
        int sx = __shfl(sv, e);
        uint4 v = featb4[(size_t)sx * 64 + lane];
        EDGE_BODY(sx, v)
      }
    }
  }
#undef EDGE_BODY

  if (w > 0) {
    float* q = sd[w - 1][lane];
    q[0] = a0; q[1] = a1; q[2] = a2; q[3] = a3;
    q[4] = a4; q[5] = a5; q[6] = a6; q[7] = a7;
    q[8] = sum;
  }
  __syncthreads();
  if (w == 0) {
#pragma unroll
    for (int j = 0; j < 3; ++j) {
      const float* q = sd[j][lane];
      a0 += q[0]; a1 += q[1]; a2 += q[2]; a3 += q[3];
      a4 += q[4]; a5 += q[5]; a6 += q[6]; a7 += q[7];
      sum += q[8];
    }
    float inv = (s1 > s0) ? 1.f / sum : 0.f;
    a0 *= inv; a1 *= inv; a2 *= inv; a3 *= inv;
    a4 *= inv; a5 *= inv; a6 *= inv; a7 *= inv;
    // sum over heads: lanes with same (l&7)
#pragma unroll
    for (int k = 8; k <= 32; k <<= 1) {
      a0 += __shfl_xor(a0, k); a1 += __shfl_xor(a1, k);
      a2 += __shfl_xor(a2, k); a3 += __shfl_xor(a3, k);
      a4 += __shfl_xor(a4, k); a5 += __shfl_xor(a5, k);
      a6 += __shfl_xor(a6, k); a7 += __shfl_xor(a7, k);
    }
    if (lane < 8) {
      float4 b0 = ((const float4*)bsum)[lane * 2];
      float4 b1 = ((const float4*)bsum)[lane * 2 + 1];
      float4 o0, o1;
      o0.x = a0 + b0.x; o0.x = (o0.x > 0.f) ? o0.x : 0.01f * o0.x;
      o0.y = a1 + b0.y; o0.y = (o0.y > 0.f) ? o0.y : 0.01f * o0.y;
      o0.z = a2 + b0.z; o0.z = (o0.z > 0.f) ? o0.z : 0.01f * o0.z;
      o0.w = a3 + b0.w; o0.w = (o0.w > 0.f) ? o0.w : 0.01f * o0.w;
      o1.x = a4 + b1.x; o1.x = (o1.x > 0.f) ? o1.x : 0.01f * o1.x;
      o1.y = a5 + b1.y; o1.y = (o1.y > 0.f) ? o1.y : 0.01f * o1.y;
      o1.z = a6 + b1.z; o1.z = (o1.z > 0.f) ? o1.z : 0.01f * o1.z;
      o1.w = a7 + b1.w; o1.w = (o1.w > 0.f) ? o1.w : 0.01f * o1.w;
      if (FINAL) {
        float4* xp = (float4*)&xo[lane * 8];
        xp[0] = o0;
        xp[1] = o1;
      } else {
        float4* op = (float4*)(xout + (size_t)node * 64 + lane * 8);
        op[0] = o0;
        op[1] = o1;
      }
    }
    if (FINAL) {
      // wave 0: out[node][lane] = bm[lane] + sum_k xo[k]*Wm[lane][k]
      float s = bm[lane];
      const float4* wrow = (const float4*)(Wm + (size_t)lane * 64);
#pragma unroll
      for (int k4 = 0; k4 < 16; ++k4) {
        float4 wv = wrow[k4];
        float4 xv = *(const float4*)&xo[k4 * 4];
        s += xv.x * wv.x + xv.y * wv.y + xv.z * wv.z + xv.w * wv.w;
      }
      xout[(size_t)node * 64 + lane] = s;
    }
  }
}

// ============================ launch ============================
extern "C" void kernel_launch(void* const* d_in, const int* in_sizes, int n_in,
                              void* d_out, int out_size, void* d_ws, size_t ws_size,
                              hipStream_t stream) {
  const float* inputs = (const float*)d_in[0];
  const int* src = (const int*)d_in[1];
  const int* dst = (const int*)d_in[2];
  const float* W1 = (const float*)d_in[3];
  const float* al1 = (const float*)d_in[4];
  const float* ar1 = (const float*)d_in[5];
  const float* b1 = (const float*)d_in[6];
  const float* W2 = (const float*)d_in[7];
  const float* al2 = (const float*)d_in[8];
  const float* ar2 = (const float*)d_in[9];
  const float* b2 = (const float*)d_in[10];
  const float* W3 = (const float*)d_in[11];
  const float* al3 = (const float*)d_in[12];
  const float* ar3 = (const float*)d_in[13];
  const float* b3 = (const float*)d_in[14];
  const float* Wm = (const float*)d_in[15];
  const float* bm = (const float*)d_in[16];
  float* out = (float*)d_out;

  char* p = (char*)d_ws;
  auto carve = [&](size_t bytes) {
    void* r = (void*)p;
    p += (bytes + 255) & ~(size_t)255;
    return r;
  };
  ushort* featb = (ushort*)carve((size_t)NN * HF * 2);   // 51.2 MB bf16
  float* el = (float*)carve((size_t)NN * NH * 4);
  float* er = (float*)carve((size_t)NN * NH * 4);
  float* xbuf = (float*)carve((size_t)NN * 64 * 4);      // 12.8 MB
  ushort* Wp = (ushort*)carve((size_t)IN_DIM * 512 * 2); // 128 KB
  float* bsum = (float*)carve(64 * 4);
  int* row_ptr = (int*)carve((size_t)(NN + 1) * 4);
  int* srcs = (int*)carve((size_t)NE * 4);
  int* deg = (int*)carve((size_t)NN * 4);
  int* cursor = (int*)carve((size_t)NN * 4);
  int* bsums = (int*)carve(256 * 4);

  const int edgeBlocks = (NE + 255) / 256;   // 3125
  const int nBlocks = (NN + 255) / 256;      // 196
  const int gemmBlocks = (NN + 31) / 32;     // 1563

  // ---- CSR build ----
  zeroIntKernel<<<nBlocks, 256, 0, stream>>>(deg, NN);
  histKernel<<<edgeBlocks, 256, 0, stream>>>(dst, deg, NE);
  scanBlockKernel<<<nBlocks, 256, 0, stream>>>(deg, row_ptr, bsums, NN);
  scanTopKernel<<<1, 256, 0, stream>>>(bsums, nBlocks);
  scanAddKernel<<<nBlocks, 256, 0, stream>>>(row_ptr, bsums, NN);
  copyIntKernel<<<nBlocks, 256, 0, stream>>>(row_ptr, cursor, NN);
  fillKernel<<<edgeBlocks, 256, 0, stream>>>(src, dst, cursor, srcs, NE);

  // ---- layer 1 ----
  packWKernel<IN_DIM><<<(512 * IN_DIM) / 256, 256, 0, stream>>>(W1, b1, Wp, bsum);
  gemmMfmaKernel<IN_DIM><<<gemmBlocks, 256, 0, stream>>>(inputs, Wp, al1, ar1, featb, el, er, NN);
  aggKernel<0><<<NN, 256, 0, stream>>>((const uint4*)featb, el, er, row_ptr, srcs, bsum, Wm, bm, xbuf, NN);

  // ---- layer 2 ----
  packWKernel<HIDF><<<(512 * HIDF) / 256, 256, 0, stream>>>(W2, b2, Wp, bsum);
  gemmMfmaKernel<HIDF><<<gemmBlocks, 256, 0, stream>>>(xbuf, Wp, al2, ar2, featb, el, er, NN);
  aggKernel<0><<<NN, 256, 0, stream>>>((const uint4*)featb, el, er, row_ptr, srcs, bsum, Wm, bm, xbuf, NN);

  // ---- layer 3 (agg fuses final dense) ----
  packWKernel<HIDF><<<(512 * HIDF) / 256, 256, 0, stream>>>(W3, b3, Wp, bsum);
  gemmMfmaKernel<HIDF><<<gemmBlocks, 256, 0, stream>>>(xbuf, Wp, al3, ar3, featb, el, er, NN);
  aggKernel<1><<<NN, 256, 0, stream>>>((const uint4*)featb, el, er, row_ptr, srcs, bsum, Wm, bm, out, NN);
}

// Round 11
// 772.394 us; speedup vs baseline: 1.8930x; 1.0052x over previous
//
#include <hip/hip_runtime.h>
#include <hip/hip_bf16.h>
#include <math.h>

#define NN 50000
#define NE 800000
#define IN_DIM 128
#define HIDF 64
#define NH 8
#define HF 512   /* NH*HIDF */
#define OUT_DIM 64

typedef __attribute__((ext_vector_type(8))) short bf16x8;
typedef __attribute__((ext_vector_type(4))) float f32x4;

__device__ inline ushort f2b(float x) {
  union { __hip_bfloat16 b; ushort u; } c;
  c.b = __float2bfloat16(x);
  return c.u;
}

// ============================ utility ============================

__global__ __launch_bounds__(256) void zeroIntKernel(int* __restrict__ a, int n) {
  int i = blockIdx.x * 256 + threadIdx.x;
  if (i < n) a[i] = 0;
}

// ============================ CSR build ============================

__global__ __launch_bounds__(256) void histKernel(const int* __restrict__ dst,
                                                  int* __restrict__ deg, int e) {
  int i = blockIdx.x * 256 + threadIdx.x;
  if (i < e) atomicAdd(&deg[dst[i]], 1);
}

__global__ __launch_bounds__(256) void scanBlockKernel(const int* __restrict__ deg,
                                                       int* __restrict__ row_ptr,
                                                       int* __restrict__ bsums, int n) {
  __shared__ int sd[256];
  int i = blockIdx.x * 256 + threadIdx.x;
  int v = (i < n) ? deg[i] : 0;
  sd[threadIdx.x] = v;
  __syncthreads();
  for (int off = 1; off < 256; off <<= 1) {
    int t = (threadIdx.x >= off) ? sd[threadIdx.x - off] : 0;
    __syncthreads();
    sd[threadIdx.x] += t;
    __syncthreads();
  }
  if (i < n) row_ptr[i + 1] = sd[threadIdx.x];
  if (threadIdx.x == 255) bsums[blockIdx.x] = sd[255];
  if (i == 0) row_ptr[0] = 0;
}

__global__ __launch_bounds__(256) void scanTopKernel(int* __restrict__ bsums, int nb) {
  __shared__ int sd[256];
  int v = (threadIdx.x < nb) ? bsums[threadIdx.x] : 0;
  sd[threadIdx.x] = v;
  __syncthreads();
  for (int off = 1; off < 256; off <<= 1) {
    int t = (threadIdx.x >= off) ? sd[threadIdx.x - off] : 0;
    __syncthreads();
    sd[threadIdx.x] += t;
    __syncthreads();
  }
  if (threadIdx.x < nb) bsums[threadIdx.x] = sd[threadIdx.x] - v;  // exclusive
}

__global__ __launch_bounds__(256) void scanAddKernel(int* __restrict__ row_ptr,
                                                     const int* __restrict__ bsums, int n) {
  int i = blockIdx.x * 256 + threadIdx.x;
  if (i < n) row_ptr[i + 1] += bsums[blockIdx.x];
}

__global__ __launch_bounds__(256) void copyIntKernel(const int* __restrict__ a,
                                                     int* __restrict__ b, int n) {
  int i = blockIdx.x * 256 + threadIdx.x;
  if (i < n) b[i] = a[i];
}

__global__ __launch_bounds__(256) void fillKernel(const int* __restrict__ src,
                                                  const int* __restrict__ dst,
                                                  int* __restrict__ cursor,
                                                  int* __restrict__ srcs, int e) {
  int i = blockIdx.x * 256 + threadIdx.x;
  if (i < e) {
    int d = dst[i];
    int pos = atomicAdd(&cursor[d], 1);
    srcs[pos] = src[i];
  }
}

// ====== pack W [512][KIN] f32 -> bf16 B-fragments; block 0 also computes bsum ======
template <int KIN>
__global__ __launch_bounds__(256) void packWKernel(const float* __restrict__ W,
                                                   const float* __restrict__ b,
                                                   ushort* __restrict__ Wp,
                                                   float* __restrict__ bsum) {
  int idx = blockIdx.x * 256 + threadIdx.x;
  if (idx < 512 * KIN) {
    int j = idx & 7;
    int nn = (idx >> 3) & 511;
    int rest = idx >> 12;
    int g = rest & 3, kb = rest >> 2;
    int k = kb * 32 + (j >> 2) * 16 + g * 4 + (j & 3);
    Wp[idx] = f2b(W[(size_t)nn * KIN + k]);
  }
  if (blockIdx.x == 0 && threadIdx.x < 64) {
    float s = 0.f;
#pragma unroll
    for (int h = 0; h < NH; ++h) s += b[h * 64 + threadIdx.x];
    bsum[threadIdx.x] = s;
  }
}

// ====== MFMA GEMM: featb(bf16)[n][512] = X @ W^T; el/er from the feat LDS tile ======
template <int KIN>
__global__ __launch_bounds__(256) void gemmMfmaKernel(const float* __restrict__ X,
                                                      const ushort* __restrict__ Wp,
                                                      const float* __restrict__ al,
                                                      const float* __restrict__ ar,
                                                      ushort* __restrict__ featb,
                                                      float* __restrict__ el,
                                                      float* __restrict__ er, int n) {
  const int XS = KIN + 4;   // ushort stride for X tile
  const int OS = 520;       // ushort stride for out tile (rows 16B-aligned)
  __shared__ ushort lbuf[32 * 520];  // 33.3 KB; reused: X tile then feat tile
  ushort* xs = lbuf;
  int tid = threadIdx.x;
  int n0 = blockIdx.x * 32;
  const int PR = KIN / 2;
  for (int i = tid; i < 32 * PR; i += 256) {
    int r = i / PR, k = (i - r * PR) * 2;
    float2 v = (n0 + r < n) ? *(const float2*)&X[(size_t)(n0 + r) * KIN + k]
                            : make_float2(0.f, 0.f);
    uint packed = (uint)f2b(v.x) | ((uint)f2b(v.y) << 16);
    *(uint*)&xs[r * XS + k] = packed;
  }
  __syncthreads();

  int w = tid >> 6;
  int l = tid & 63;
  int lc = l & 15;   // fragment col / row lane index
  int g = l >> 4;    // k-group
  f32x4 acc[2][8];
#pragma unroll
  for (int mr = 0; mr < 2; ++mr)
#pragma unroll
    for (int nr = 0; nr < 8; ++nr) acc[mr][nr] = (f32x4){0.f, 0.f, 0.f, 0.f};

#pragma unroll
  for (int kb = 0; kb < KIN / 32; ++kb) {
    int kk = kb * 32;
    bf16x8 afr[2];
#pragma unroll
    for (int mr = 0; mr < 2; ++mr) {
      int row = mr * 16 + lc;
      uint2 lo = *(const uint2*)&xs[row * XS + kk + g * 4];
      uint2 hi = *(const uint2*)&xs[row * XS + kk + 16 + g * 4];
      int4 tmp = make_int4((int)lo.x, (int)lo.y, (int)hi.x, (int)hi.y);
      afr[mr] = __builtin_bit_cast(bf16x8, tmp);
    }
    const ushort* wpb = Wp + ((size_t)(kb * 4 + g) * 512) * 8;
#pragma unroll
    for (int nr = 0; nr < 8; ++nr) {
      int nc = w * 128 + nr * 16 + lc;
      bf16x8 bfr = *(const bf16x8*)&wpb[(size_t)nc * 8];
      acc[0][nr] = __builtin_amdgcn_mfma_f32_16x16x32_bf16(afr[0], bfr, acc[0][nr], 0, 0, 0);
      acc[1][nr] = __builtin_amdgcn_mfma_f32_16x16x32_bf16(afr[1], bfr, acc[1][nr], 0, 0, 0);
    }
  }

  __syncthreads();  // X-tile reads done; reuse lbuf as feat tile
#pragma unroll
  for (int mr = 0; mr < 2; ++mr) {
#pragma unroll
    for (int j = 0; j < 4; ++j) {
      int row = mr * 16 + g * 4 + j;
      ushort* orow = lbuf + row * OS + w * 128 + lc;
#pragma unroll
      for (int nr = 0; nr < 8; ++nr) orow[nr * 16] = f2b(acc[mr][nr][j]);
    }
  }
  __syncthreads();
  // coalesced global store: 32 rows x 64 uint4
#pragma unroll
  for (int it = 0; it < 8; ++it) {
    int idx = it * 256 + tid;
    int row = idx >> 6, ucol = idx & 63;
    int rr = n0 + row;
    if (rr < n)
      *(uint4*)&featb[(size_t)rr * 512 + ucol * 8] = *(const uint4*)&lbuf[row * OS + ucol * 8];
  }

  // el/er from the bf16 feat tile: thread t -> row r2=t>>3, head h2=t&7
  int r2 = tid >> 3, h2 = tid & 7;
  if (n0 + r2 < n) {
    const ushort* frow = lbuf + r2 * OS + h2 * 64;
    const float4* alp = (const float4*)(al + (size_t)h2 * 64);
    const float4* arp = (const float4*)(ar + (size_t)h2 * 64);
    float accl = 0.f, accr = 0.f;
#pragma unroll
    for (int fb = 0; fb < 8; ++fb) {
      uint4 u = *(const uint4*)&frow[fb * 8];
      float4 a0 = alp[fb * 2], a1 = alp[fb * 2 + 1];
      float4 c0 = arp[fb * 2], c1 = arp[fb * 2 + 1];
      float f0 = __uint_as_float(u.x << 16), f1 = __uint_as_float(u.x & 0xffff0000u);
      float f2 = __uint_as_float(u.y << 16), f3 = __uint_as_float(u.y & 0xffff0000u);
      float f4 = __uint_as_float(u.z << 16), f5 = __uint_as_float(u.z & 0xffff0000u);
      float f6 = __uint_as_float(u.w << 16), f7 = __uint_as_float(u.w & 0xffff0000u);
      accl += f0 * a0.x + f1 * a0.y + f2 * a0.z + f3 * a0.w +
              f4 * a1.x + f5 * a1.y + f6 * a1.z + f7 * a1.w;
      accr += f0 * c0.x + f1 * c0.y + f2 * c0.z + f3 * c0.w +
              f4 * c1.x + f5 * c1.y + f6 * c1.z + f7 * c1.w;
    }
    el[(size_t)(n0 + r2) * NH + h2] = accl;
    er[(size_t)(n0 + r2) * NH + h2] = accr;
  }
}

// ====== aggregate (round-8 exact): one node per block, 4 waves split edges ======
// lane l: head hl = l>>3, feats fbase=(l&7)*8 .. +7
__global__ __launch_bounds__(256) void aggKernel(const uint4* __restrict__ featb4,
                                                 const float* __restrict__ el,
                                                 const float* __restrict__ er,
                                                 const int* __restrict__ row_ptr,
                                                 const int* __restrict__ srcs,
                                                 const float* __restrict__ bsum,
                                                 float* __restrict__ xout, int n) {
  __shared__ float sd[3][64][11];  // waves 1..3 partials: acc(8) + sum
  int node = blockIdx.x;
  if (node >= n) return;
  int tid = threadIdx.x;
  int w = tid >> 6;
  int lane = tid & 63;
  int s0 = row_ptr[node], s1 = row_ptr[node + 1];
  int hl = lane >> 3;
  float erv = er[(size_t)node * NH + hl];
  float a0 = 0.f, a1 = 0.f, a2 = 0.f, a3 = 0.f, a4 = 0.f, a5 = 0.f, a6 = 0.f, a7 = 0.f;
  float sum = 0.f;

#define EDGE_BODY(SX, V)                                                  \
  {                                                                       \
    float t = el[(size_t)(SX)*NH + hl] + erv;                             \
    t = (t > 0.f) ? t : 0.2f * t;                                         \
    float av = __expf(t);                                                 \
    sum += av;                                                            \
    a0 += av * __uint_as_float((V).x << 16);                              \
    a1 += av * __uint_as_float((V).x & 0xffff0000u);                      \
    a2 += av * __uint_as_float((V).y << 16);                              \
    a3 += av * __uint_as_float((V).y & 0xffff0000u);                      \
    a4 += av * __uint_as_float((V).z << 16);                              \
    a5 += av * __uint_as_float((V).z & 0xffff0000u);                      \
    a6 += av * __uint_as_float((V).w << 16);                              \
    a7 += av * __uint_as_float((V).w & 0xffff0000u);                      \
  }

  for (int base = s0; base < s1; base += 64) {
    int nb = s1 - base;
    if (nb > 64) nb = 64;
    int li = base + lane;
    int sv = srcs[li < s1 ? li : s1 - 1];
    for (int e = w * 4; e + 4 <= nb; e += 16) {
      int sa = __shfl(sv, e);
      int sb = __shfl(sv, e + 1);
      int sc = __shfl(sv, e + 2);
      int se = __shfl(sv, e + 3);
      uint4 v0 = featb4[(size_t)sa * 64 + lane];
      uint4 v1 = featb4[(size_t)sb * 64 + lane];
      uint4 v2 = featb4[(size_t)sc * 64 + lane];
      uint4 v3 = featb4[(size_t)se * 64 + lane];
      EDGE_BODY(sa, v0)
      EDGE_BODY(sb, v1)
      EDGE_BODY(sc, v2)
      EDGE_BODY(se, v3)
    }
    if (w == 0) {
      for (int e = nb & ~3; e < nb; ++e) {
        int sx = __shfl(sv, e);
        uint4 v = featb4[(size_t)sx * 64 + lane];
        EDGE_BODY(sx, v)
      }
    }
  }
#undef EDGE_BODY

  if (w > 0) {
    float* q = sd[w - 1][lane];
    q[0] = a0; q[1] = a1; q[2] = a2; q[3] = a3;
    q[4] = a4; q[5] = a5; q[6] = a6; q[7] = a7;
    q[8] = sum;
  }
  __syncthreads();
  if (w == 0) {
#pragma unroll
    for (int j = 0; j < 3; ++j) {
      const float* q = sd[j][lane];
      a0 += q[0]; a1 += q[1]; a2 += q[2]; a3 += q[3];
      a4 += q[4]; a5 += q[5]; a6 += q[6]; a7 += q[7];
      sum += q[8];
    }
    float inv = (s1 > s0) ? 1.f / sum : 0.f;
    a0 *= inv; a1 *= inv; a2 *= inv; a3 *= inv;
    a4 *= inv; a5 *= inv; a6 *= inv; a7 *= inv;
#pragma unroll
    for (int k = 8; k <= 32; k <<= 1) {
      a0 += __shfl_xor(a0, k); a1 += __shfl_xor(a1, k);
      a2 += __shfl_xor(a2, k); a3 += __shfl_xor(a3, k);
      a4 += __shfl_xor(a4, k); a5 += __shfl_xor(a5, k);
      a6 += __shfl_xor(a6, k); a7 += __shfl_xor(a7, k);
    }
    if (lane < 8) {
      float4 b0 = ((const float4*)bsum)[lane * 2];
      float4 b1 = ((const float4*)bsum)[lane * 2 + 1];
      float4 o0, o1;
      o0.x = a0 + b0.x; o0.x = (o0.x > 0.f) ? o0.x : 0.01f * o0.x;
      o0.y = a1 + b0.y; o0.y = (o0.y > 0.f) ? o0.y : 0.01f * o0.y;
      o0.z = a2 + b0.z; o0.z = (o0.z > 0.f) ? o0.z : 0.01f * o0.z;
      o0.w = a3 + b0.w; o0.w = (o0.w > 0.f) ? o0.w : 0.01f * o0.w;
      o1.x = a4 + b1.x; o1.x = (o1.x > 0.f) ? o1.x : 0.01f * o1.x;
      o1.y = a5 + b1.y; o1.y = (o1.y > 0.f) ? o1.y : 0.01f * o1.y;
      o1.z = a6 + b1.z; o1.z = (o1.z > 0.f) ? o1.z : 0.01f * o1.z;
      o1.w = a7 + b1.w; o1.w = (o1.w > 0.f) ? o1.w : 0.01f * o1.w;
      float4* op = (float4*)(xout + (size_t)node * 64 + lane * 8);
      op[0] = o0;
      op[1] = o1;
    }
  }
}

// ====== aggFinal: agg + fused final dense (layer 3 only; separate function) ======
__global__ __launch_bounds__(256) void aggFinalKernel(const uint4* __restrict__ featb4,
                                                      const float* __restrict__ el,
                                                      const float* __restrict__ er,
                                                      const int* __restrict__ row_ptr,
                                                      const int* __restrict__ srcs,
                                                      const float* __restrict__ bsum,
                                                      const float* __restrict__ Wm,
                                                      const float* __restrict__ bm,
                                                      float* __restrict__ out, int n) {
  __shared__ float sd[3][64][11];
  __shared__ float xo[64];
  int node = blockIdx.x;
  if (node >= n) return;
  int tid = threadIdx.x;
  int w = tid >> 6;
  int lane = tid & 63;
  int s0 = row_ptr[node], s1 = row_ptr[node + 1];
  int hl = lane >> 3;
  float erv = er[(size_t)node * NH + hl];
  float a0 = 0.f, a1 = 0.f, a2 = 0.f, a3 = 0.f, a4 = 0.f, a5 = 0.f, a6 = 0.f, a7 = 0.f;
  float sum = 0.f;

#define EDGE_BODY(SX, V)                                                  \
  {                                                                       \
    float t = el[(size_t)(SX)*NH + hl] + erv;                             \
    t = (t > 0.f) ? t : 0.2f * t;                                         \
    float av = __expf(t);                                                 \
    sum += av;                                                            \
    a0 += av * __uint_as_float((V).x << 16);                              \
    a1 += av * __uint_as_float((V).x & 0xffff0000u);                      \
    a2 += av * __uint_as_float((V).y << 16);                              \
    a3 += av * __uint_as_float((V).y & 0xffff0000u);                      \
    a4 += av * __uint_as_float((V).z << 16);                              \
    a5 += av * __uint_as_float((V).z & 0xffff0000u);                      \
    a6 += av * __uint_as_float((V).w << 16);                              \
    a7 += av * __uint_as_float((V).w & 0xffff0000u);                      \
  }

  for (int base = s0; base < s1; base += 64) {
    int nb = s1 - base;
    if (nb > 64) nb = 64;
    int li = base + lane;
    int sv = srcs[li < s1 ? li : s1 - 1];
    for (int e = w * 4; e + 4 <= nb; e += 16) {
      int sa = __shfl(sv, e);
      int sb = __shfl(sv, e + 1);
      int sc = __shfl(sv, e + 2);
      int se = __shfl(sv, e + 3);
      uint4 v0 = featb4[(size_t)sa * 64 + lane];
      uint4 v1 = featb4[(size_t)sb * 64 + lane];
      uint4 v2 = featb4[(size_t)sc * 64 + lane];
      uint4 v3 = featb4[(size_t)se * 64 + lane];
      EDGE_BODY(sa, v0)
      EDGE_BODY(sb, v1)
      EDGE_BODY(sc, v2)
      EDGE_BODY(se, v3)
    }
    if (w == 0) {
      for (int e = nb & ~3; e < nb; ++e) {
        int sx = __shfl(sv, e);
        uint4 v = featb4[(size_t)sx * 64 + lane];
        EDGE_BODY(sx, v)
      }
    }
  }
#undef EDGE_BODY

  if (w > 0) {
    float* q = sd[w - 1][lane];
    q[0] = a0; q[1] = a1; q[2] = a2; q[3] = a3;
    q[4] = a4; q[5] = a5; q[6] = a6; q[7] = a7;
    q[8] = sum;
  }
  __syncthreads();
  if (w == 0) {
#pragma unroll
    for (int j = 0; j < 3; ++j) {
      const float* q = sd[j][lane];
      a0 += q[0]; a1 += q[1]; a2 += q[2]; a3 += q[3];
      a4 += q[4]; a5 += q[5]; a6 += q[6]; a7 += q[7];
      sum += q[8];
    }
    float inv = (s1 > s0) ? 1.f / sum : 0.f;
    a0 *= inv; a1 *= inv; a2 *= inv; a3 *= inv;
    a4 *= inv; a5 *= inv; a6 *= inv; a7 *= inv;
#pragma unroll
    for (int k = 8; k <= 32; k <<= 1) {
      a0 += __shfl_xor(a0, k); a1 += __shfl_xor(a1, k);
      a2 += __shfl_xor(a2, k); a3 += __shfl_xor(a3, k);
      a4 += __shfl_xor(a4, k); a5 += __shfl_xor(a5, k);
      a6 += __shfl_xor(a6, k); a7 += __shfl_xor(a7, k);
    }
    if (lane < 8) {
      float4 b0 = ((const float4*)bsum)[lane * 2];
      float4 b1 = ((const float4*)bsum)[lane * 2 + 1];
      float4 o0, o1;
      o0.x = a0 + b0.x; o0.x = (o0.x > 0.f) ? o0.x : 0.01f * o0.x;
      o0.y = a1 + b0.y; o0.y = (o0.y > 0.f) ? o0.y : 0.01f * o0.y;
      o0.z = a2 + b0.z; o0.z = (o0.z > 0.f) ? o0.z : 0.01f * o0.z;
      o0.w = a3 + b0.w; o0.w = (o0.w > 0.f) ? o0.w : 0.01f * o0.w;
      o1.x = a4 + b1.x; o1.x = (o1.x > 0.f) ? o1.x : 0.01f * o1.x;
      o1.y = a5 + b1.y; o1.y = (o1.y > 0.f) ? o1.y : 0.01f * o1.y;
      o1.z = a6 + b1.z; o1.z = (o1.z > 0.f) ? o1.z : 0.01f * o1.z;
      o1.w = a7 + b1.w; o1.w = (o1.w > 0.f) ? o1.w : 0.01f * o1.w;
      float4* xp = (float4*)&xo[lane * 8];
      xp[0] = o0;
      xp[1] = o1;
    }
    // wave 0: out[node][lane] = bm[lane] + sum_k xo[k]*Wm[lane][k]
    float s = bm[lane];
    const float4* wrow = (const float4*)(Wm + (size_t)lane * 64);
#pragma unroll
    for (int k4 = 0; k4 < 16; ++k4) {
      float4 wv = wrow[k4];
      float4 xv = *(const float4*)&xo[k4 * 4];
      s += xv.x * wv.x + xv.y * wv.y + xv.z * wv.z + xv.w * wv.w;
    }
    out[(size_t)node * 64 + lane] = s;
  }
}

// ============================ launch ============================
extern "C" void kernel_launch(void* const* d_in, const int* in_sizes, int n_in,
                              void* d_out, int out_size, void* d_ws, size_t ws_size,
                              hipStream_t stream) {
  const float* inputs = (const float*)d_in[0];
  const int* src = (const int*)d_in[1];
  const int* dst = (const int*)d_in[2];
  const float* W1 = (const float*)d_in[3];
  const float* al1 = (const float*)d_in[4];
  const float* ar1 = (const float*)d_in[5];
  const float* b1 = (const float*)d_in[6];
  const float* W2 = (const float*)d_in[7];
  const float* al2 = (const float*)d_in[8];
  const float* ar2 = (const float*)d_in[9];
  const float* b2 = (const float*)d_in[10];
  const float* W3 = (const float*)d_in[11];
  const float* al3 = (const float*)d_in[12];
  const float* ar3 = (const float*)d_in[13];
  const float* b3 = (const float*)d_in[14];
  const float* Wm = (const float*)d_in[15];
  const float* bm = (const float*)d_in[16];
  float* out = (float*)d_out;

  char* p = (char*)d_ws;
  auto carve = [&](size_t bytes) {
    void* r = (void*)p;
    p += (bytes + 255) & ~(size_t)255;
    return r;
  };
  ushort* featb = (ushort*)carve((size_t)NN * HF * 2);   // 51.2 MB bf16
  float* el = (float*)carve((size_t)NN * NH * 4);
  float* er = (float*)carve((size_t)NN * NH * 4);
  float* xbuf = (float*)carve((size_t)NN * 64 * 4);      // 12.8 MB
  ushort* Wp = (ushort*)carve((size_t)IN_DIM * 512 * 2); // 128 KB
  float* bsum = (float*)carve(64 * 4);
  int* row_ptr = (int*)carve((size_t)(NN + 1) * 4);
  int* srcs = (int*)carve((size_t)NE * 4);
  int* deg = (int*)carve((size_t)NN * 4);
  int* cursor = (int*)carve((size_t)NN * 4);
  int* bsums = (int*)carve(256 * 4);

  const int edgeBlocks = (NE + 255) / 256;   // 3125
  const int nBlocks = (NN + 255) / 256;      // 196
  const int gemmBlocks = (NN + 31) / 32;     // 1563

  // ---- CSR build ----
  zeroIntKernel<<<nBlocks, 256, 0, stream>>>(deg, NN);
  histKernel<<<edgeBlocks, 256, 0, stream>>>(dst, deg, NE);
  scanBlockKernel<<<nBlocks, 256, 0, stream>>>(deg, row_ptr, bsums, NN);
  scanTopKernel<<<1, 256, 0, stream>>>(bsums, nBlocks);
  scanAddKernel<<<nBlocks, 256, 0, stream>>>(row_ptr, bsums, NN);
  copyIntKernel<<<nBlocks, 256, 0, stream>>>(row_ptr, cursor, NN);
  fillKernel<<<edgeBlocks, 256, 0, stream>>>(src, dst, cursor, srcs, NE);

  // ---- layer 1 ----
  packWKernel<IN_DIM><<<(512 * IN_DIM) / 256, 256, 0, stream>>>(W1, b1, Wp, bsum);
  gemmMfmaKernel<IN_DIM><<<gemmBlocks, 256, 0, stream>>>(inputs, Wp, al1, ar1, featb, el, er, NN);
  aggKernel<<<NN, 256, 0, stream>>>((const uint4*)featb, el, er, row_ptr, srcs, bsum, xbuf, NN);

  // ---- layer 2 ----
  packWKernel<HIDF><<<(512 * HIDF) / 256, 256, 0, stream>>>(W2, b2, Wp, bsum);
  gemmMfmaKernel<HIDF><<<gemmBlocks, 256, 0, stream>>>(xbuf, Wp, al2, ar2, featb, el, er, NN);
  aggKernel<<<NN, 256, 0, stream>>>((const uint4*)featb, el, er, row_ptr, srcs, bsum, xbuf, NN);

  // ---- layer 3 (agg fuses final dense) ----
  packWKernel<HIDF><<<(512 * HIDF) / 256, 256, 0, stream>>>(W3, b3, Wp, bsum);
  gemmMfmaKernel<HIDF><<<gemmBlocks, 256, 0, stream>>>(xbuf, Wp, al3, ar3, featb, el, er, NN);
  aggFinalKernel<<<NN, 256, 0, stream>>>((const uint4*)featb, el, er, row_ptr, srcs, bsum, Wm, bm, out, NN);
}

// Round 12
// 763.071 us; speedup vs baseline: 1.9161x; 1.0122x over previous
//
#include <hip/hip_runtime.h>
#include <hip/hip_bf16.h>
#include <math.h>

#define NN 50000
#define NE 800000
#define IN_DIM 128
#define HIDF 64
#define NH 8
#define HF 512   /* NH*HIDF */
#define OUT_DIM 64

typedef __attribute__((ext_vector_type(8))) short bf16x8;
typedef __attribute__((ext_vector_type(4))) float f32x4;

__device__ inline ushort f2b(float x) {
  union { __hip_bfloat16 b; ushort u; } c;
  c.b = __float2bfloat16(x);
  return c.u;
}

// ============================ utility ============================

__global__ __launch_bounds__(256) void zeroIntKernel(int* __restrict__ a, int n) {
  int i = blockIdx.x * 256 + threadIdx.x;
  if (i < n) a[i] = 0;
}

// ============================ CSR build ============================

__global__ __launch_bounds__(256) void histKernel(const int* __restrict__ dst,
                                                  int* __restrict__ deg, int e) {
  int i = blockIdx.x * 256 + threadIdx.x;
  if (i < e) atomicAdd(&deg[dst[i]], 1);
}

__global__ __launch_bounds__(256) void scanBlockKernel(const int* __restrict__ deg,
                                                       int* __restrict__ row_ptr,
                                                       int* __restrict__ bsums, int n) {
  __shared__ int sd[256];
  int i = blockIdx.x * 256 + threadIdx.x;
  int v = (i < n) ? deg[i] : 0;
  sd[threadIdx.x] = v;
  __syncthreads();
  for (int off = 1; off < 256; off <<= 1) {
    int t = (threadIdx.x >= off) ? sd[threadIdx.x - off] : 0;
    __syncthreads();
    sd[threadIdx.x] += t;
    __syncthreads();
  }
  if (i < n) row_ptr[i + 1] = sd[threadIdx.x];
  if (threadIdx.x == 255) bsums[blockIdx.x] = sd[255];
  if (i == 0) row_ptr[0] = 0;
}

__global__ __launch_bounds__(256) void scanTopKernel(int* __restrict__ bsums, int nb) {
  __shared__ int sd[256];
  int v = (threadIdx.x < nb) ? bsums[threadIdx.x] : 0;
  sd[threadIdx.x] = v;
  __syncthreads();
  for (int off = 1; off < 256; off <<= 1) {
    int t = (threadIdx.x >= off) ? sd[threadIdx.x - off] : 0;
    __syncthreads();
    sd[threadIdx.x] += t;
    __syncthreads();
  }
  if (threadIdx.x < nb) bsums[threadIdx.x] = sd[threadIdx.x] - v;  // exclusive
}

// row_ptr[i+1] += bsums[block]; cursor[i+1] = final row_ptr[i+1]; cursor[0] = 0
__global__ __launch_bounds__(256) void scanAddKernel(int* __restrict__ row_ptr,
                                                     const int* __restrict__ bsums,
                                                     int* __restrict__ cursor, int n) {
  int i = blockIdx.x * 256 + threadIdx.x;
  if (i < n) {
    int v = row_ptr[i + 1] + bsums[blockIdx.x];
    row_ptr[i + 1] = v;
    if (i + 1 < n) cursor[i + 1] = v;
  }
  if (i == 0) cursor[0] = 0;
}

__global__ __launch_bounds__(256) void fillKernel(const int* __restrict__ src,
                                                  const int* __restrict__ dst,
                                                  int* __restrict__ cursor,
                                                  int* __restrict__ srcs, int e) {
  int i = blockIdx.x * 256 + threadIdx.x;
  if (i < e) {
    int d = dst[i];
    int pos = atomicAdd(&cursor[d], 1);
    srcs[pos] = src[i];
  }
}

// ====== pack W [512][KIN] f32 -> bf16 B-fragments; block 0 also computes bsum ======
template <int KIN>
__global__ __launch_bounds__(256) void packWKernel(const float* __restrict__ W,
                                                   const float* __restrict__ b,
                                                   ushort* __restrict__ Wp,
                                                   float* __restrict__ bsum) {
  int idx = blockIdx.x * 256 + threadIdx.x;
  if (idx < 512 * KIN) {
    int j = idx & 7;
    int nn = (idx >> 3) & 511;
    int rest = idx >> 12;
    int g = rest & 3, kb = rest >> 2;
    int k = kb * 32 + (j >> 2) * 16 + g * 4 + (j & 3);
    Wp[idx] = f2b(W[(size_t)nn * KIN + k]);
  }
  if (blockIdx.x == 0 && threadIdx.x < 64) {
    float s = 0.f;
#pragma unroll
    for (int h = 0; h < NH; ++h) s += b[h * 64 + threadIdx.x];
    bsum[threadIdx.x] = s;
  }
}

// ====== MFMA GEMM: featb(bf16)[n][512] = X @ W^T; el/er from the feat LDS tile ======
template <int KIN>
__global__ __launch_bounds__(256) void gemmMfmaKernel(const float* __restrict__ X,
                                                      const ushort* __restrict__ Wp,
                                                      const float* __restrict__ al,
                                                      const float* __restrict__ ar,
                                                      ushort* __restrict__ featb,
                                                      float* __restrict__ el,
                                                      float* __restrict__ er, int n) {
  const int XS = KIN + 4;   // ushort stride for X tile
  const int OS = 520;       // ushort stride for out tile (rows 16B-aligned)
  __shared__ ushort lbuf[32 * 520];  // 33.3 KB; reused: X tile then feat tile
  ushort* xs = lbuf;
  int tid = threadIdx.x;
  int n0 = blockIdx.x * 32;
  const int PR = KIN / 2;
  for (int i = tid; i < 32 * PR; i += 256) {
    int r = i / PR, k = (i - r * PR) * 2;
    float2 v = (n0 + r < n) ? *(const float2*)&X[(size_t)(n0 + r) * KIN + k]
                            : make_float2(0.f, 0.f);
    uint packed = (uint)f2b(v.x) | ((uint)f2b(v.y) << 16);
    *(uint*)&xs[r * XS + k] = packed;
  }
  __syncthreads();

  int w = tid >> 6;
  int l = tid & 63;
  int lc = l & 15;   // fragment col / row lane index
  int g = l >> 4;    // k-group
  f32x4 acc[2][8];
#pragma unroll
  for (int mr = 0; mr < 2; ++mr)
#pragma unroll
    for (int nr = 0; nr < 8; ++nr) acc[mr][nr] = (f32x4){0.f, 0.f, 0.f, 0.f};

#pragma unroll
  for (int kb = 0; kb < KIN / 32; ++kb) {
    int kk = kb * 32;
    bf16x8 afr[2];
#pragma unroll
    for (int mr = 0; mr < 2; ++mr) {
      int row = mr * 16 + lc;
      uint2 lo = *(const uint2*)&xs[row * XS + kk + g * 4];
      uint2 hi = *(const uint2*)&xs[row * XS + kk + 16 + g * 4];
      int4 tmp = make_int4((int)lo.x, (int)lo.y, (int)hi.x, (int)hi.y);
      afr[mr] = __builtin_bit_cast(bf16x8, tmp);
    }
    const ushort* wpb = Wp + ((size_t)(kb * 4 + g) * 512) * 8;
#pragma unroll
    for (int nr = 0; nr < 8; ++nr) {
      int nc = w * 128 + nr * 16 + lc;
      bf16x8 bfr = *(const bf16x8*)&wpb[(size_t)nc * 8];
      acc[0][nr] = __builtin_amdgcn_mfma_f32_16x16x32_bf16(afr[0], bfr, acc[0][nr], 0, 0, 0);
      acc[1][nr] = __builtin_amdgcn_mfma_f32_16x16x32_bf16(afr[1], bfr, acc[1][nr], 0, 0, 0);
    }
  }

  __syncthreads();  // X-tile reads done; reuse lbuf as feat tile
#pragma unroll
  for (int mr = 0; mr < 2; ++mr) {
#pragma unroll
    for (int j = 0; j < 4; ++j) {
      int row = mr * 16 + g * 4 + j;
      ushort* orow = lbuf + row * OS + w * 128 + lc;
#pragma unroll
      for (int nr = 0; nr < 8; ++nr) orow[nr * 16] = f2b(acc[mr][nr][j]);
    }
  }
  __syncthreads();
  // coalesced global store: 32 rows x 64 uint4
#pragma unroll
  for (int it = 0; it < 8; ++it) {
    int idx = it * 256 + tid;
    int row = idx >> 6, ucol = idx & 63;
    int rr = n0 + row;
    if (rr < n)
      *(uint4*)&featb[(size_t)rr * 512 + ucol * 8] = *(const uint4*)&lbuf[row * OS + ucol * 8];
  }

  // el/er from the bf16 feat tile: thread t -> row r2=t>>3, head h2=t&7
  int r2 = tid >> 3, h2 = tid & 7;
  if (n0 + r2 < n) {
    const ushort* frow = lbuf + r2 * OS + h2 * 64;
    const float4* alp = (const float4*)(al + (size_t)h2 * 64);
    const float4* arp = (const float4*)(ar + (size_t)h2 * 64);
    float accl = 0.f, accr = 0.f;
#pragma unroll
    for (int fb = 0; fb < 8; ++fb) {
      uint4 u = *(const uint4*)&frow[fb * 8];
      float4 a0 = alp[fb * 2], a1 = alp[fb * 2 + 1];
      float4 c0 = arp[fb * 2], c1 = arp[fb * 2 + 1];
      float f0 = __uint_as_float(u.x << 16), f1 = __uint_as_float(u.x & 0xffff0000u);
      float f2 = __uint_as_float(u.y << 16), f3 = __uint_as_float(u.y & 0xffff0000u);
      float f4 = __uint_as_float(u.z << 16), f5 = __uint_as_float(u.z & 0xffff0000u);
      float f6 = __uint_as_float(u.w << 16), f7 = __uint_as_float(u.w & 0xffff0000u);
      accl += f0 * a0.x + f1 * a0.y + f2 * a0.z + f3 * a0.w +
              f4 * a1.x + f5 * a1.y + f6 * a1.z + f7 * a1.w;
      accr += f0 * c0.x + f1 * c0.y + f2 * c0.z + f3 * c0.w +
              f4 * c1.x + f5 * c1.y + f6 * c1.z + f7 * c1.w;
    }
    el[(size_t)(n0 + r2) * NH + h2] = accl;
    er[(size_t)(n0 + r2) * NH + h2] = accr;
  }
}

// ====== aggregate (round-8 exact): one node per block, 4 waves split edges ======
// lane l: head hl = l>>3, feats fbase=(l&7)*8 .. +7
__global__ __launch_bounds__(256) void aggKernel(const uint4* __restrict__ featb4,
                                                 const float* __restrict__ el,
                                                 const float* __restrict__ er,
                                                 const int* __restrict__ row_ptr,
                                                 const int* __restrict__ srcs,
                                                 const float* __restrict__ bsum,
                                                 float* __restrict__ xout, int n) {
  __shared__ float sd[3][64][11];  // waves 1..3 partials: acc(8) + sum
  int node = blockIdx.x;
  if (node >= n) return;
  int tid = threadIdx.x;
  int w = tid >> 6;
  int lane = tid & 63;
  int s0 = row_ptr[node], s1 = row_ptr[node + 1];
  int hl = lane >> 3;
  float erv = er[(size_t)node * NH + hl];
  float a0 = 0.f, a1 = 0.f, a2 = 0.f, a3 = 0.f, a4 = 0.f, a5 = 0.f, a6 = 0.f, a7 = 0.f;
  float sum = 0.f;

#define EDGE_BODY(SX, V)                                                  \
  {                                                                       \
    float t = el[(size_t)(SX)*NH + hl] + erv;                             \
    t = (t > 0.f) ? t : 0.2f * t;                                         \
    float av = __expf(t);                                                 \
    sum += av;                                                            \
    a0 += av * __uint_as_float((V).x << 16);                              \
    a1 += av * __uint_as_float((V).x & 0xffff0000u);                      \
    a2 += av * __uint_as_float((V).y << 16);                              \
    a3 += av * __uint_as_float((V).y & 0xffff0000u);                      \
    a4 += av * __uint_as_float((V).z << 16);                              \
    a5 += av * __uint_as_float((V).z & 0xffff0000u);                      \
    a6 += av * __uint_as_float((V).w << 16);                              \
    a7 += av * __uint_as_float((V).w & 0xffff0000u);                      \
  }

  for (int base = s0; base < s1; base += 64) {
    int nb = s1 - base;
    if (nb > 64) nb = 64;
    int li = base + lane;
    int sv = srcs[li < s1 ? li : s1 - 1];
    for (int e = w * 4; e + 4 <= nb; e += 16) {
      int sa = __shfl(sv, e);
      int sb = __shfl(sv, e + 1);
      int sc = __shfl(sv, e + 2);
      int se = __shfl(sv, e + 3);
      uint4 v0 = featb4[(size_t)sa * 64 + lane];
      uint4 v1 = featb4[(size_t)sb * 64 + lane];
      uint4 v2 = featb4[(size_t)sc * 64 + lane];
      uint4 v3 = featb4[(size_t)se * 64 + lane];
      EDGE_BODY(sa, v0)
      EDGE_BODY(sb, v1)
      EDGE_BODY(sc, v2)
      EDGE_BODY(se, v3)
    }
    if (w == 0) {
      for (int e = nb & ~3; e < nb; ++e) {
        int sx = __shfl(sv, e);
        uint4 v = featb4[(size_t)sx * 64 + lane];
        EDGE_BODY(sx, v)
      }
    }
  }
#undef EDGE_BODY

  if (w > 0) {
    float* q = sd[w - 1][lane];
    q[0] = a0; q[1] = a1; q[2] = a2; q[3] = a3;
    q[4] = a4; q[5] = a5; q[6] = a6; q[7] = a7;
    q[8] = sum;
  }
  __syncthreads();
  if (w == 0) {
#pragma unroll
    for (int j = 0; j < 3; ++j) {
      const float* q = sd[j][lane];
      a0 += q[0]; a1 += q[1]; a2 += q[2]; a3 += q[3];
      a4 += q[4]; a5 += q[5]; a6 += q[6]; a7 += q[7];
      sum += q[8];
    }
    float inv = (s1 > s0) ? 1.f / sum : 0.f;
    a0 *= inv; a1 *= inv; a2 *= inv; a3 *= inv;
    a4 *= inv; a5 *= inv; a6 *= inv; a7 *= inv;
#pragma unroll
    for (int k = 8; k <= 32; k <<= 1) {
      a0 += __shfl_xor(a0, k); a1 += __shfl_xor(a1, k);
      a2 += __shfl_xor(a2, k); a3 += __shfl_xor(a3, k);
      a4 += __shfl_xor(a4, k); a5 += __shfl_xor(a5, k);
      a6 += __shfl_xor(a6, k); a7 += __shfl_xor(a7, k);
    }
    if (lane < 8) {
      float4 b0 = ((const float4*)bsum)[lane * 2];
      float4 b1 = ((const float4*)bsum)[lane * 2 + 1];
      float4 o0, o1;
      o0.x = a0 + b0.x; o0.x = (o0.x > 0.f) ? o0.x : 0.01f * o0.x;
      o0.y = a1 + b0.y; o0.y = (o0.y > 0.f) ? o0.y : 0.01f * o0.y;
      o0.z = a2 + b0.z; o0.z = (o0.z > 0.f) ? o0.z : 0.01f * o0.z;
      o0.w = a3 + b0.w; o0.w = (o0.w > 0.f) ? o0.w : 0.01f * o0.w;
      o1.x = a4 + b1.x; o1.x = (o1.x > 0.f) ? o1.x : 0.01f * o1.x;
      o1.y = a5 + b1.y; o1.y = (o1.y > 0.f) ? o1.y : 0.01f * o1.y;
      o1.z = a6 + b1.z; o1.z = (o1.z > 0.f) ? o1.z : 0.01f * o1.z;
      o1.w = a7 + b1.w; o1.w = (o1.w > 0.f) ? o1.w : 0.01f * o1.w;
      float4* op = (float4*)(xout + (size_t)node * 64 + lane * 8);
      op[0] = o0;
      op[1] = o1;
    }
  }
}

// ============================ final dense: out = x @ Wm^T + bm ============================
__global__ __launch_bounds__(256) void finalKernel(const float* __restrict__ x,
                                                   const float* __restrict__ Wm,
                                                   const float* __restrict__ bm,
                                                   float* __restrict__ out, int n) {
  __shared__ float wt[64 * 65];
  int tid = threadIdx.x;
  for (int i = tid; i < 4096; i += 256) {
    int j = i >> 6, k = i & 63;
    wt[k * 65 + j] = Wm[i];
  }
  __syncthreads();
  int node = blockIdx.x * 4 + (tid >> 6);
  int lane = tid & 63;
  if (node >= n) return;
  const float* xr = x + (size_t)node * 64;
  float acc = bm[lane];
#pragma unroll 8
  for (int k = 0; k < 64; ++k) acc += xr[k] * wt[k * 65 + lane];
  out[(size_t)node * 64 + lane] = acc;
}

// ============================ launch ============================
extern "C" void kernel_launch(void* const* d_in, const int* in_sizes, int n_in,
                              void* d_out, int out_size, void* d_ws, size_t ws_size,
                              hipStream_t stream) {
  const float* inputs = (const float*)d_in[0];
  const int* src = (const int*)d_in[1];
  const int* dst = (const int*)d_in[2];
  const float* W1 = (const float*)d_in[3];
  const float* al1 = (const float*)d_in[4];
  const float* ar1 = (const float*)d_in[5];
  const float* b1 = (const float*)d_in[6];
  const float* W2 = (const float*)d_in[7];
  const float* al2 = (const float*)d_in[8];
  const float* ar2 = (const float*)d_in[9];
  const float* b2 = (const float*)d_in[10];
  const float* W3 = (const float*)d_in[11];
  const float* al3 = (const float*)d_in[12];
  const float* ar3 = (const float*)d_in[13];
  const float* b3 = (const float*)d_in[14];
  const float* Wm = (const float*)d_in[15];
  const float* bm = (const float*)d_in[16];
  float* out = (float*)d_out;

  char* p = (char*)d_ws;
  auto carve = [&](size_t bytes) {
    void* r = (void*)p;
    p += (bytes + 255) & ~(size_t)255;
    return r;
  };
  ushort* featb = (ushort*)carve((size_t)NN * HF * 2);   // 51.2 MB bf16
  float* el = (float*)carve((size_t)NN * NH * 4);
  float* er = (float*)carve((size_t)NN * NH * 4);
  float* xbuf = (float*)carve((size_t)NN * 64 * 4);      // 12.8 MB
  ushort* Wp = (ushort*)carve((size_t)IN_DIM * 512 * 2); // 128 KB
  float* bsum = (float*)carve(64 * 4);
  int* row_ptr = (int*)carve((size_t)(NN + 1) * 4);
  int* srcs = (int*)carve((size_t)NE * 4);
  int* deg = (int*)carve((size_t)NN * 4);
  int* cursor = (int*)carve((size_t)NN * 4);
  int* bsums = (int*)carve(256 * 4);

  const int edgeBlocks = (NE + 255) / 256;   // 3125
  const int nBlocks = (NN + 255) / 256;      // 196
  const int gemmBlocks = (NN + 31) / 32;     // 1563
  const int node4Blocks = (NN + 3) / 4;      // 12500 (finalKernel)

  // ---- CSR build ----
  zeroIntKernel<<<nBlocks, 256, 0, stream>>>(deg, NN);
  histKernel<<<edgeBlocks, 256, 0, stream>>>(dst, deg, NE);
  scanBlockKernel<<<nBlocks, 256, 0, stream>>>(deg, row_ptr, bsums, NN);
  scanTopKernel<<<1, 256, 0, stream>>>(bsums, nBlocks);
  scanAddKernel<<<nBlocks, 256, 0, stream>>>(row_ptr, bsums, cursor, NN);
  fillKernel<<<edgeBlocks, 256, 0, stream>>>(src, dst, cursor, srcs, NE);

  // ---- layer 1 ----
  packWKernel<IN_DIM><<<(512 * IN_DIM) / 256, 256, 0, stream>>>(W1, b1, Wp, bsum);
  gemmMfmaKernel<IN_DIM><<<gemmBlocks, 256, 0, stream>>>(inputs, Wp, al1, ar1, featb, el, er, NN);
  aggKernel<<<NN, 256, 0, stream>>>((const uint4*)featb, el, er, row_ptr, srcs, bsum, xbuf, NN);

  // ---- layer 2 ----
  packWKernel<HIDF><<<(512 * HIDF) / 256, 256, 0, stream>>>(W2, b2, Wp, bsum);
  gemmMfmaKernel<HIDF><<<gemmBlocks, 256, 0, stream>>>(xbuf, Wp, al2, ar2, featb, el, er, NN);
  aggKernel<<<NN, 256, 0, stream>>>((const uint4*)featb, el, er, row_ptr, srcs, bsum, xbuf, NN);

  // ---- layer 3 ----
  packWKernel<HIDF><<<(512 * HIDF) / 256, 256, 0, stream>>>(W3, b3, Wp, bsum);
  gemmMfmaKernel<HIDF><<<gemmBlocks, 256, 0, stream>>>(xbuf, Wp, al3, ar3, featb, el, er, NN);
  aggKernel<<<NN, 256, 0, stream>>>((const uint4*)featb, el, er, row_ptr, srcs, bsum, xbuf, NN);

  // ---- final dense ----
  finalKernel<<<node4Blocks, 256, 0, stream>>>(xbuf, Wm, bm, out, NN);
}

// Round 13
// 725.649 us; speedup vs baseline: 2.0149x; 1.0516x over previous
//
#include <hip/hip_runtime.h>
#include <hip/hip_bf16.h>
#include <math.h>

#define NN 50000
#define NE 800000
#define IN_DIM 128
#define HIDF 64
#define NH 8
#define HF 512   /* NH*HIDF */
#define OUT_DIM 64

typedef __attribute__((ext_vector_type(8))) short bf16x8;
typedef __attribute__((ext_vector_type(4))) float f32x4;

__device__ inline ushort f2b(float x) {
  union { __hip_bfloat16 b; ushort u; } c;
  c.b = __float2bfloat16(x);
  return c.u;
}

// ============================ utility ============================

__global__ __launch_bounds__(256) void zeroIntKernel(int* __restrict__ a, int n) {
  int i = blockIdx.x * 256 + threadIdx.x;
  if (i < n) a[i] = 0;
}

// ============================ CSR build ============================

__global__ __launch_bounds__(256) void histKernel(const int* __restrict__ dst,
                                                  int* __restrict__ deg, int e) {
  int i = blockIdx.x * 256 + threadIdx.x;
  if (i < e) atomicAdd(&deg[dst[i]], 1);
}

__global__ __launch_bounds__(256) void scanBlockKernel(const int* __restrict__ deg,
                                                       int* __restrict__ row_ptr,
                                                       int* __restrict__ bsums, int n) {
  __shared__ int sd[256];
  int i = blockIdx.x * 256 + threadIdx.x;
  int v = (i < n) ? deg[i] : 0;
  sd[threadIdx.x] = v;
  __syncthreads();
  for (int off = 1; off < 256; off <<= 1) {
    int t = (threadIdx.x >= off) ? sd[threadIdx.x - off] : 0;
    __syncthreads();
    sd[threadIdx.x] += t;
    __syncthreads();
  }
  if (i < n) row_ptr[i + 1] = sd[threadIdx.x];
  if (threadIdx.x == 255) bsums[blockIdx.x] = sd[255];
  if (i == 0) row_ptr[0] = 0;
}

__global__ __launch_bounds__(256) void scanTopKernel(int* __restrict__ bsums, int nb) {
  __shared__ int sd[256];
  int v = (threadIdx.x < nb) ? bsums[threadIdx.x] : 0;
  sd[threadIdx.x] = v;
  __syncthreads();
  for (int off = 1; off < 256; off <<= 1) {
    int t = (threadIdx.x >= off) ? sd[threadIdx.x - off] : 0;
    __syncthreads();
    sd[threadIdx.x] += t;
    __syncthreads();
  }
  if (threadIdx.x < nb) bsums[threadIdx.x] = sd[threadIdx.x] - v;  // exclusive
}

// row_ptr[i+1] += bsums[block]; cursor[i+1] = final row_ptr[i+1]; cursor[0] = 0
__global__ __launch_bounds__(256) void scanAddKernel(int* __restrict__ row_ptr,
                                                     const int* __restrict__ bsums,
                                                     int* __restrict__ cursor, int n) {
  int i = blockIdx.x * 256 + threadIdx.x;
  if (i < n) {
    int v = row_ptr[i + 1] + bsums[blockIdx.x];
    row_ptr[i + 1] = v;
    if (i + 1 < n) cursor[i + 1] = v;
  }
  if (i == 0) cursor[0] = 0;
}

__global__ __launch_bounds__(256) void fillKernel(const int* __restrict__ src,
                                                  const int* __restrict__ dst,
                                                  int* __restrict__ cursor,
                                                  int* __restrict__ srcs, int e) {
  int i = blockIdx.x * 256 + threadIdx.x;
  if (i < e) {
    int d = dst[i];
    int pos = atomicAdd(&cursor[d], 1);
    srcs[pos] = src[i];
  }
}

// ====== pack W [512][KIN] f32 -> bf16 B-fragments; block 0 also computes bsum ======
template <int KIN>
__global__ __launch_bounds__(256) void packWKernel(const float* __restrict__ W,
                                                   const float* __restrict__ b,
                                                   ushort* __restrict__ Wp,
                                                   float* __restrict__ bsum) {
  int idx = blockIdx.x * 256 + threadIdx.x;
  if (idx < 512 * KIN) {
    int j = idx & 7;
    int nn = (idx >> 3) & 511;
    int rest = idx >> 12;
    int g = rest & 3, kb = rest >> 2;
    int k = kb * 32 + (j >> 2) * 16 + g * 4 + (j & 3);
    Wp[idx] = f2b(W[(size_t)nn * KIN + k]);
  }
  if (blockIdx.x == 0 && threadIdx.x < 64) {
    float s = 0.f;
#pragma unroll
    for (int h = 0; h < NH; ++h) s += b[h * 64 + threadIdx.x];
    bsum[threadIdx.x] = s;
  }
}

// ====== MFMA GEMM: featb(bf16)[n][512] = X @ W^T; el/er from the feat LDS tile ======
template <int KIN>
__global__ __launch_bounds__(256) void gemmMfmaKernel(const float* __restrict__ X,
                                                      const ushort* __restrict__ Wp,
                                                      const float* __restrict__ al,
                                                      const float* __restrict__ ar,
                                                      ushort* __restrict__ featb,
                                                      float* __restrict__ el,
                                                      float* __restrict__ er, int n) {
  const int XS = KIN + 4;   // ushort stride for X tile
  const int OS = 520;       // ushort stride for out tile (rows 16B-aligned)
  __shared__ ushort lbuf[32 * 520];  // 33.3 KB; reused: X tile then feat tile
  ushort* xs = lbuf;
  int tid = threadIdx.x;
  int n0 = blockIdx.x * 32;
  const int PR = KIN / 2;
  for (int i = tid; i < 32 * PR; i += 256) {
    int r = i / PR, k = (i - r * PR) * 2;
    float2 v = (n0 + r < n) ? *(const float2*)&X[(size_t)(n0 + r) * KIN + k]
                            : make_float2(0.f, 0.f);
    uint packed = (uint)f2b(v.x) | ((uint)f2b(v.y) << 16);
    *(uint*)&xs[r * XS + k] = packed;
  }
  __syncthreads();

  int w = tid >> 6;
  int l = tid & 63;
  int lc = l & 15;   // fragment col / row lane index
  int g = l >> 4;    // k-group
  f32x4 acc[2][8];
#pragma unroll
  for (int mr = 0; mr < 2; ++mr)
#pragma unroll
    for (int nr = 0; nr < 8; ++nr) acc[mr][nr] = (f32x4){0.f, 0.f, 0.f, 0.f};

#pragma unroll
  for (int kb = 0; kb < KIN / 32; ++kb) {
    int kk = kb * 32;
    bf16x8 afr[2];
#pragma unroll
    for (int mr = 0; mr < 2; ++mr) {
      int row = mr * 16 + lc;
      uint2 lo = *(const uint2*)&xs[row * XS + kk + g * 4];
      uint2 hi = *(const uint2*)&xs[row * XS + kk + 16 + g * 4];
      int4 tmp = make_int4((int)lo.x, (int)lo.y, (int)hi.x, (int)hi.y);
      afr[mr] = __builtin_bit_cast(bf16x8, tmp);
    }
    const ushort* wpb = Wp + ((size_t)(kb * 4 + g) * 512) * 8;
#pragma unroll
    for (int nr = 0; nr < 8; ++nr) {
      int nc = w * 128 + nr * 16 + lc;
      bf16x8 bfr = *(const bf16x8*)&wpb[(size_t)nc * 8];
      acc[0][nr] = __builtin_amdgcn_mfma_f32_16x16x32_bf16(afr[0], bfr, acc[0][nr], 0, 0, 0);
      acc[1][nr] = __builtin_amdgcn_mfma_f32_16x16x32_bf16(afr[1], bfr, acc[1][nr], 0, 0, 0);
    }
  }

  __syncthreads();  // X-tile reads done; reuse lbuf as feat tile
#pragma unroll
  for (int mr = 0; mr < 2; ++mr) {
#pragma unroll
    for (int j = 0; j < 4; ++j) {
      int row = mr * 16 + g * 4 + j;
      ushort* orow = lbuf + row * OS + w * 128 + lc;
#pragma unroll
      for (int nr = 0; nr < 8; ++nr) orow[nr * 16] = f2b(acc[mr][nr][j]);
    }
  }
  __syncthreads();
  // coalesced global store: 32 rows x 64 uint4
#pragma unroll
  for (int it = 0; it < 8; ++it) {
    int idx = it * 256 + tid;
    int row = idx >> 6, ucol = idx & 63;
    int rr = n0 + row;
    if (rr < n)
      *(uint4*)&featb[(size_t)rr * 512 + ucol * 8] = *(const uint4*)&lbuf[row * OS + ucol * 8];
  }

  // el/er from the bf16 feat tile: thread t -> row r2=t>>3, head h2=t&7
  int r2 = tid >> 3, h2 = tid & 7;
  if (n0 + r2 < n) {
    const ushort* frow = lbuf + r2 * OS + h2 * 64;
    const float4* alp = (const float4*)(al + (size_t)h2 * 64);
    const float4* arp = (const float4*)(ar + (size_t)h2 * 64);
    float accl = 0.f, accr = 0.f;
#pragma unroll
    for (int fb = 0; fb < 8; ++fb) {
      uint4 u = *(const uint4*)&frow[fb * 8];
      float4 a0 = alp[fb * 2], a1 = alp[fb * 2 + 1];
      float4 c0 = arp[fb * 2], c1 = arp[fb * 2 + 1];
      float f0 = __uint_as_float(u.x << 16), f1 = __uint_as_float(u.x & 0xffff0000u);
      float f2 = __uint_as_float(u.y << 16), f3 = __uint_as_float(u.y & 0xffff0000u);
      float f4 = __uint_as_float(u.z << 16), f5 = __uint_as_float(u.z & 0xffff0000u);
      float f6 = __uint_as_float(u.w << 16), f7 = __uint_as_float(u.w & 0xffff0000u);
      accl += f0 * a0.x + f1 * a0.y + f2 * a0.z + f3 * a0.w +
              f4 * a1.x + f5 * a1.y + f6 * a1.z + f7 * a1.w;
      accr += f0 * c0.x + f1 * c0.y + f2 * c0.z + f3 * c0.w +
              f4 * c1.x + f5 * c1.y + f6 * c1.z + f7 * c1.w;
    }
    el[(size_t)(n0 + r2) * NH + h2] = accl;
    er[(size_t)(n0 + r2) * NH + h2] = accr;
  }
}

// ====== aggregate: ONE WAVE per node, 4 nodes per block (no LDS, no barriers) ======
// lane l: head hl = l>>3, feats fbase=(l&7)*8 .. +7
__global__ __launch_bounds__(256) void aggKernel(const uint4* __restrict__ featb4,
                                                 const float* __restrict__ el,
                                                 const float* __restrict__ er,
                                                 const int* __restrict__ row_ptr,
                                                 const int* __restrict__ srcs,
                                                 const float* __restrict__ bsum,
                                                 float* __restrict__ xout, int n) {
  int node = blockIdx.x * 4 + (threadIdx.x >> 6);
  int lane = threadIdx.x & 63;
  if (node >= n) return;
  int s0 = row_ptr[node], s1 = row_ptr[node + 1];
  int hl = lane >> 3;
  float erv = er[(size_t)node * NH + hl];
  float a0 = 0.f, a1 = 0.f, a2 = 0.f, a3 = 0.f, a4 = 0.f, a5 = 0.f, a6 = 0.f, a7 = 0.f;
  float sum = 0.f;

#define EDGE_BODY(SX, V)                                                  \
  {                                                                       \
    float t = el[(size_t)(SX)*NH + hl] + erv;                             \
    t = (t > 0.f) ? t : 0.2f * t;                                         \
    float av = __expf(t);                                                 \
    sum += av;                                                            \
    a0 += av * __uint_as_float((V).x << 16);                              \
    a1 += av * __uint_as_float((V).x & 0xffff0000u);                      \
    a2 += av * __uint_as_float((V).y << 16);                              \
    a3 += av * __uint_as_float((V).y & 0xffff0000u);                      \
    a4 += av * __uint_as_float((V).z << 16);                              \
    a5 += av * __uint_as_float((V).z & 0xffff0000u);                      \
    a6 += av * __uint_as_float((V).w << 16);                              \
    a7 += av * __uint_as_float((V).w & 0xffff0000u);                      \
  }

  for (int base = s0; base < s1; base += 64) {
    int nb = s1 - base;
    if (nb > 64) nb = 64;
    int li = base + lane;
    int sv = srcs[li < s1 ? li : s1 - 1];
    int e = 0;
    for (; e + 4 <= nb; e += 4) {
      int sa = __shfl(sv, e);
      int sb = __shfl(sv, e + 1);
      int sc = __shfl(sv, e + 2);
      int se = __shfl(sv, e + 3);
      uint4 v0 = featb4[(size_t)sa * 64 + lane];
      uint4 v1 = featb4[(size_t)sb * 64 + lane];
      uint4 v2 = featb4[(size_t)sc * 64 + lane];
      uint4 v3 = featb4[(size_t)se * 64 + lane];
      EDGE_BODY(sa, v0)
      EDGE_BODY(sb, v1)
      EDGE_BODY(sc, v2)
      EDGE_BODY(se, v3)
    }
    for (; e < nb; ++e) {
      int sx = __shfl(sv, e);
      uint4 v = featb4[(size_t)sx * 64 + lane];
      EDGE_BODY(sx, v)
    }
  }
#undef EDGE_BODY

  float inv = (s1 > s0) ? 1.f / sum : 0.f;
  a0 *= inv; a1 *= inv; a2 *= inv; a3 *= inv;
  a4 *= inv; a5 *= inv; a6 *= inv; a7 *= inv;
  // sum over heads: lanes with same (l&7)
#pragma unroll
  for (int k = 8; k <= 32; k <<= 1) {
    a0 += __shfl_xor(a0, k); a1 += __shfl_xor(a1, k);
    a2 += __shfl_xor(a2, k); a3 += __shfl_xor(a3, k);
    a4 += __shfl_xor(a4, k); a5 += __shfl_xor(a5, k);
    a6 += __shfl_xor(a6, k); a7 += __shfl_xor(a7, k);
  }
  if (lane < 8) {
    float4 b0 = ((const float4*)bsum)[lane * 2];
    float4 b1 = ((const float4*)bsum)[lane * 2 + 1];
    float4 o0, o1;
    o0.x = a0 + b0.x; o0.x = (o0.x > 0.f) ? o0.x : 0.01f * o0.x;
    o0.y = a1 + b0.y; o0.y = (o0.y > 0.f) ? o0.y : 0.01f * o0.y;
    o0.z = a2 + b0.z; o0.z = (o0.z > 0.f) ? o0.z : 0.01f * o0.z;
    o0.w = a3 + b0.w; o0.w = (o0.w > 0.f) ? o0.w : 0.01f * o0.w;
    o1.x = a4 + b1.x; o1.x = (o1.x > 0.f) ? o1.x : 0.01f * o1.x;
    o1.y = a5 + b1.y; o1.y = (o1.y > 0.f) ? o1.y : 0.01f * o1.y;
    o1.z = a6 + b1.z; o1.z = (o1.z > 0.f) ? o1.z : 0.01f * o1.z;
    o1.w = a7 + b1.w; o1.w = (o1.w > 0.f) ? o1.w : 0.01f * o1.w;
    float4* op = (float4*)(xout + (size_t)node * 64 + lane * 8);
    op[0] = o0;
    op[1] = o1;
  }
}

// ============================ final dense: out = x @ Wm^T + bm ============================
__global__ __launch_bounds__(256) void finalKernel(const float* __restrict__ x,
                                                   const float* __restrict__ Wm,
                                                   const float* __restrict__ bm,
                                                   float* __restrict__ out, int n) {
  __shared__ float wt[64 * 65];
  int tid = threadIdx.x;
  for (int i = tid; i < 4096; i += 256) {
    int j = i >> 6, k = i & 63;
    wt[k * 65 + j] = Wm[i];
  }
  __syncthreads();
  int node = blockIdx.x * 4 + (tid >> 6);
  int lane = tid & 63;
  if (node >= n) return;
  const float* xr = x + (size_t)node * 64;
  float acc = bm[lane];
#pragma unroll 8
  for (int k = 0; k < 64; ++k) acc += xr[k] * wt[k * 65 + lane];
  out[(size_t)node * 64 + lane] = acc;
}

// ============================ launch ============================
extern "C" void kernel_launch(void* const* d_in, const int* in_sizes, int n_in,
                              void* d_out, int out_size, void* d_ws, size_t ws_size,
                              hipStream_t stream) {
  const float* inputs = (const float*)d_in[0];
  const int* src = (const int*)d_in[1];
  const int* dst = (const int*)d_in[2];
  const float* W1 = (const float*)d_in[3];
  const float* al1 = (const float*)d_in[4];
  const float* ar1 = (const float*)d_in[5];
  const float* b1 = (const float*)d_in[6];
  const float* W2 = (const float*)d_in[7];
  const float* al2 = (const float*)d_in[8];
  const float* ar2 = (const float*)d_in[9];
  const float* b2 = (const float*)d_in[10];
  const float* W3 = (const float*)d_in[11];
  const float* al3 = (const float*)d_in[12];
  const float* ar3 = (const float*)d_in[13];
  const float* b3 = (const float*)d_in[14];
  const float* Wm = (const float*)d_in[15];
  const float* bm = (const float*)d_in[16];
  float* out = (float*)d_out;

  char* p = (char*)d_ws;
  auto carve = [&](size_t bytes) {
    void* r = (void*)p;
    p += (bytes + 255) & ~(size_t)255;
    return r;
  };
  ushort* featb = (ushort*)carve((size_t)NN * HF * 2);   // 51.2 MB bf16
  float* el = (float*)carve((size_t)NN * NH * 4);
  float* er = (float*)carve((size_t)NN * NH * 4);
  float* xbuf = (float*)carve((size_t)NN * 64 * 4);      // 12.8 MB
  ushort* Wp = (ushort*)carve((size_t)IN_DIM * 512 * 2); // 128 KB
  float* bsum = (float*)carve(64 * 4);
  int* row_ptr = (int*)carve((size_t)(NN + 1) * 4);
  int* srcs = (int*)carve((size_t)NE * 4);
  int* deg = (int*)carve((size_t)NN * 4);
  int* cursor = (int*)carve((size_t)NN * 4);
  int* bsums = (int*)carve(256 * 4);

  const int edgeBlocks = (NE + 255) / 256;   // 3125
  const int nBlocks = (NN + 255) / 256;      // 196
  const int gemmBlocks = (NN + 31) / 32;     // 1563
  const int node4Blocks = (NN + 3) / 4;      // 12500 (agg + final)

  // ---- CSR build ----
  zeroIntKernel<<<nBlocks, 256, 0, stream>>>(deg, NN);
  histKernel<<<edgeBlocks, 256, 0, stream>>>(dst, deg, NE);
  scanBlockKernel<<<nBlocks, 256, 0, stream>>>(deg, row_ptr, bsums, NN);
  scanTopKernel<<<1, 256, 0, stream>>>(bsums, nBlocks);
  scanAddKernel<<<nBlocks, 256, 0, stream>>>(row_ptr, bsums, cursor, NN);
  fillKernel<<<edgeBlocks, 256, 0, stream>>>(src, dst, cursor, srcs, NE);

  // ---- layer 1 ----
  packWKernel<IN_DIM><<<(512 * IN_DIM) / 256, 256, 0, stream>>>(W1, b1, Wp, bsum);
  gemmMfmaKernel<IN_DIM><<<gemmBlocks, 256, 0, stream>>>(inputs, Wp, al1, ar1, featb, el, er, NN);
  aggKernel<<<node4Blocks, 256, 0, stream>>>((const uint4*)featb, el, er, row_ptr, srcs, bsum, xbuf, NN);

  // ---- layer 2 ----
  packWKernel<HIDF><<<(512 * HIDF) / 256, 256, 0, stream>>>(W2, b2, Wp, bsum);
  gemmMfmaKernel<HIDF><<<gemmBlocks, 256, 0, stream>>>(xbuf, Wp, al2, ar2, featb, el, er, NN);
  aggKernel<<<node4Blocks, 256, 0, stream>>>((const uint4*)featb, el, er, row_ptr, srcs, bsum, xbuf, NN);

  // ---- layer 3 ----
  packWKernel<HIDF><<<(512 * HIDF) / 256, 256, 0, stream>>>(W3, b3, Wp, bsum);
  gemmMfmaKernel<HIDF><<<gemmBlocks, 256, 0, stream>>>(xbuf, Wp, al3, ar3, featb, el, er, NN);
  aggKernel<<<node4Blocks, 256, 0, stream>>>((const uint4*)featb, el, er, row_ptr, srcs, bsum, xbuf, NN);

  // ---- final dense ----
  finalKernel<<<node4Blocks, 256, 0, stream>>>(xbuf, Wm, bm, out, NN);
}